// Round 6
// baseline (593.374 us; speedup 1.0000x reference)
//
#include <hip/hip_runtime.h>
#include <math.h>

// Scattering net: four-step register FFT, WAVE-LOCAL line groups (round-17).
// r16 analysis: VALU ~55%, DS ~41%, ~45% lockstep stall from 5 block barriers
// (line groups spanned waves: g was tid>>7). Remap g = tid&7, q = tid>>3:
// each 128-line's 8 threads are consecutive lanes of ONE wave; wave W owns
// lines [8W, 8W+8). Line-redistribute exchanges become intra-wave (LDS is
// in-order per wave; s_waitcnt lgkmcnt(0) fences, no s_barrier). Transpose
// layout keeps each wave's read cells inside its own 1088-elem region ->
// inv_fft2: 2 barriers, fwd_fft2: 1 (was 3-4 each). Twiddles: g now per-lane
// -> 16 VGPR constants (w128^{gk}, k=1..8; k>=9 composed via V=w128^{8g}),
// +56 VALU/fft2. __launch_bounds__(1024,8) pins VGPR<=64 for 2 blocks/CU
// (r10 lesson: residency binds). Granule global layouts (r16) kept.
//
// Conventions:
//  CONV-S: slot j=8c+k2 <-> F[kr=q, kc=g+8c+16k2]   (c=j>>3, k2=j&7)
//  CONV-X: slot s       <-> x[nr=g+8s, nc=q]
//  Strips: line q, cell(k1,r) at q*136 + k1 + 17r   (fits [0,135])
//  Transp: cell(kr,nc) at (kr&7) + 8(nc&7) + 64(kr>>3) + 1088(nc>>3)
// All LDS phases <=2-way banked; strip phases pair as ds_read2/write2.

#define SDIM 128
#define PLANE 16384
#define NT 1024
#define SSTR 136
#define TBLK 1088
#define TWO_PI 6.28318530717958647692f

constexpr float W16R[8] = {1.f, 0.9238795325f, 0.7071067812f, 0.3826834324f,
                           0.f, -0.3826834324f, -0.7071067812f, -0.9238795325f};
constexpr float W16I[8] = {0.f, -0.3826834324f, -0.7071067812f, -0.9238795325f,
                           -1.f, -0.9238795325f, -0.7071067812f, -0.3826834324f};

__device__ __forceinline__ float fast_sqrtf(float x) {
  return __builtin_amdgcn_sqrtf(x);
}

__device__ __forceinline__ void ldsfence() {
  asm volatile("s_waitcnt lgkmcnt(0)" ::: "memory");
}

// ---- packed bf16 complex <-> fp32 pair ----
__device__ __forceinline__ unsigned packbf(float re, float im) {
  const unsigned r = __float_as_uint(re) + 0x8000u;
  const unsigned i = __float_as_uint(im) + 0x8000u;
  return __builtin_amdgcn_perm(r, i, 0x07060302u);
}
__device__ __forceinline__ void unpackbf(unsigned u, float& re, float& im) {
  re = __uint_as_float(u & 0xFFFF0000u);
  im = __uint_as_float(u << 16);
}

// storage-polymorphic LDS access
__device__ __forceinline__ void stC(float2* s, int idx, float re, float im) { s[idx] = make_float2(re, im); }
__device__ __forceinline__ void ldC(const float2* s, int idx, float& re, float& im) { const float2 v = s[idx]; re = v.x; im = v.y; }
__device__ __forceinline__ void stC(unsigned* s, int idx, float re, float im) { s[idx] = packbf(re, im); }
__device__ __forceinline__ void ldC(const unsigned* s, int idx, float& re, float& im) { unpackbf(s[idx], re, im); }

// per-lane twiddles tw[k] = w128^{-g k} = twg[16g+k], entries 1..8 in VGPRs.
__device__ __forceinline__ void load_tw8(const float2* __restrict__ twg, int g,
                                         float* twr, float* twi) {
  const float4* t4 = (const float4*)(twg + 16 * g);
  const float4 a = t4[0];                  // e0, e1
  const float4 b = t4[1];                  // e2, e3
  const float4 c = t4[2];                  // e4, e5
  const float4 d = t4[3];                  // e6, e7
  const float2 e8 = twg[16 * g + 8];
  twr[1] = a.z; twi[1] = a.w;
  twr[2] = b.x; twi[2] = b.y;
  twr[3] = b.z; twi[3] = b.w;
  twr[4] = c.x; twi[4] = c.y;
  twr[5] = c.z; twi[5] = c.w;
  twr[6] = d.x; twi[6] = d.y;
  twr[7] = d.z; twi[7] = d.w;
  twr[8] = e8.x; twi[8] = e8.y;
}

template<bool INV>
__device__ __forceinline__ void bfly(float& ar, float& ai, float& br, float& bi, const int idx) {
  float tr, ti;
  if (idx == 0) {
    tr = br; ti = bi;
  } else if (idx == 4) {
    if (INV) { tr = -bi; ti = br; } else { tr = bi; ti = -br; }
  } else {
    const float wr = W16R[idx];
    const float wi = INV ? -W16I[idx] : W16I[idx];
    tr = br * wr - bi * wi;
    ti = br * wi + bi * wr;
  }
  br = ar - tr; bi = ai - ti;
  ar = ar + tr; ai = ai + ti;
}

#define CSWAP(re, im, a, b) { float _t = re[a]; re[a]=re[b]; re[b]=_t; _t = im[a]; im[a]=im[b]; im[b]=_t; }

template<bool INV>
__device__ __forceinline__ void dft16(float* re, float* im) {
  CSWAP(re, im, 1, 8) CSWAP(re, im, 2, 4) CSWAP(re, im, 3, 12)
  CSWAP(re, im, 5, 10) CSWAP(re, im, 7, 14) CSWAP(re, im, 11, 13)
#pragma unroll
  for (int ls = 1; ls <= 4; ++ls) {
    const int len = 1 << ls, half = len >> 1, tstep = 16 >> ls;
#pragma unroll
    for (int blk = 0; blk < 16; blk += len)
#pragma unroll
      for (int j = 0; j < half; ++j)
        bfly<INV>(re[blk + j], im[blk + j], re[blk + j + half], im[blk + j + half], j * tstep);
  }
}

template<bool INV>
__device__ __forceinline__ void dft8(float* re, float* im) {
  CSWAP(re, im, 1, 4) CSWAP(re, im, 3, 6)
#pragma unroll
  for (int ls = 1; ls <= 3; ++ls) {
    const int len = 1 << ls, half = len >> 1, tstep = 8 >> ls;
#pragma unroll
    for (int blk = 0; blk < 8; blk += len)
#pragma unroll
      for (int j = 0; j < half; ++j)
        bfly<INV>(re[blk + j], im[blk + j], re[blk + j + half], im[blk + j + half], j * tstep * 2);
  }
}

// tw application: k=1..8 direct; k=9..15 via tw[k-8] * tw[8].
__device__ __forceinline__ void twmul_fwd(float* R, float* I, const float* twr, const float* twi) {
#pragma unroll
  for (int k = 1; k <= 8; ++k) {
    const float r = R[k] * twr[k] - I[k] * twi[k];
    I[k] = R[k] * twi[k] + I[k] * twr[k]; R[k] = r;
  }
#pragma unroll
  for (int k = 9; k < 16; ++k) {
    const float r = R[k] * twr[k - 8] - I[k] * twi[k - 8];
    const float i = R[k] * twi[k - 8] + I[k] * twr[k - 8];
    R[k] = r * twr[8] - i * twi[8];
    I[k] = r * twi[8] + i * twr[8];
  }
}
__device__ __forceinline__ void twmul_inv(float* R, float* I, const float* twr, const float* twi) {
#pragma unroll
  for (int k = 1; k <= 8; ++k) {
    const float r = R[k] * twr[k] + I[k] * twi[k];
    I[k] = I[k] * twr[k] - R[k] * twi[k]; R[k] = r;
  }
#pragma unroll
  for (int k = 9; k < 16; ++k) {
    const float r = R[k] * twr[k - 8] + I[k] * twi[k - 8];
    const float i = I[k] * twr[k - 8] - R[k] * twi[k - 8];
    R[k] = r * twr[8] + i * twi[8];
    I[k] = i * twr[8] - r * twi[8];
  }
}

// Inverse 2D FFT. In: CONV-S regs. Out: CONV-X regs. 2 block barriers.
template<typename S>
__device__ __forceinline__ void inv_fft2(float* R, float* I, S* sC,
                                         const float* twr, const float* twi,
                                         int g, int q) {
  const int sb = q * SSTR;
  const int qh = q & 7, W = q >> 3;
  // pass over kc (line = row kr=q): dft8 over k2 per c
  dft8<true>(R, I); dft8<true>(R + 8, I + 8);
  ldsfence();
#pragma unroll
  for (int r = 0; r < 8; ++r) {                     // cell(g+8c, r); write2 D8
    stC(sC, sb + g + 17 * r,     R[r],     I[r]);
    stC(sC, sb + g + 8 + 17 * r, R[8 + r], I[8 + r]);
  }
  ldsfence();
#pragma unroll
  for (int k = 0; k < 16; ++k) ldC(sC, sb + 17 * g + k, R[k], I[k]);  // read2 D1
  twmul_inv(R, I, twr, twi);
  dft16<true>(R, I);                                // slot s = H[kr=q, nc=g+8s]
  __syncthreads();                                  // all strip reads done
  {
    const int tb = qh + 8 * g + 64 * W;             // T-write spans all blocks
#pragma unroll
    for (int s = 0; s < 16; ++s) stC(sC, tb + TBLK * s, R[s], I[s]);
  }
  __syncthreads();                                  // transpose ready
  {
    const int tb = g + 8 * qh + TBLK * W;           // T-read: own block only
#pragma unroll
    for (int k2 = 0; k2 < 8; ++k2) {
      ldC(sC, tb + 128 * k2,      R[k2],     I[k2]);
      ldC(sC, tb + 128 * k2 + 64, R[8 + k2], I[8 + k2]);
    }
  }
  // pass over kr (line = col nc=q)
  dft8<true>(R, I); dft8<true>(R + 8, I + 8);
  ldsfence();                                       // own T-reads drained
#pragma unroll
  for (int r = 0; r < 8; ++r) {
    stC(sC, sb + g + 17 * r,     R[r],     I[r]);
    stC(sC, sb + g + 8 + 17 * r, R[8 + r], I[8 + r]);
  }
  ldsfence();
#pragma unroll
  for (int k = 0; k < 16; ++k) ldC(sC, sb + 17 * g + k, R[k], I[k]);
  twmul_inv(R, I, twr, twi);
  dft16<true>(R, I);                                // slot s = x[nr=g+8s, nc=q]
}

// Forward 2D FFT. In: CONV-X regs. Out: CONV-S regs. 1 block barrier.
template<typename S>
__device__ __forceinline__ void fwd_fft2(float* R, float* I, S* sC,
                                         const float* twr, const float* twi,
                                         int g, int q) {
  const int sb = q * SSTR;
  const int qh = q & 7, W = q >> 3;
  // pass over nr (line = col nc=q): dft16 over s
  dft16<false>(R, I);
  twmul_fwd(R, I, twr, twi);
  ldsfence();
#pragma unroll
  for (int k = 0; k < 16; ++k) stC(sC, sb + 17 * g + k, R[k], I[k]);  // write2 D1
  ldsfence();
#pragma unroll
  for (int r = 0; r < 8; ++r) {                     // read2 D8
    ldC(sC, sb + g + 17 * r,     R[r],     I[r]);
    ldC(sC, sb + g + 8 + 17 * r, R[8 + r], I[8 + r]);
  }
  dft8<false>(R, I); dft8<false>(R + 8, I + 8);     // slot 8c+k2 = P[kr=g+8c+16k2, nc=q]
  ldsfence();
  {
    const int tb = g + 8 * qh + TBLK * W;           // T-write: own block only
#pragma unroll
    for (int k2 = 0; k2 < 8; ++k2) {
      stC(sC, tb + 128 * k2,      R[k2],     I[k2]);
      stC(sC, tb + 128 * k2 + 64, R[8 + k2], I[8 + k2]);
    }
  }
  __syncthreads();                                  // transpose ready
  {
    const int tb = qh + 8 * g + 64 * W;             // T-read spans all blocks
#pragma unroll
    for (int s = 0; s < 16; ++s) ldC(sC, tb + TBLK * s, R[s], I[s]);
  }
  // pass over nc (line = row kr=q)
  dft16<false>(R, I);
  twmul_fwd(R, I, twr, twi);
  ldsfence();                                       // own T-reads drained
#pragma unroll
  for (int k = 0; k < 16; ++k) stC(sC, sb + 17 * g + k, R[k], I[k]);
  ldsfence();
#pragma unroll
  for (int r = 0; r < 8; ++r) {
    ldC(sC, sb + g + 17 * r,     R[r],     I[r]);
    ldC(sC, sb + g + 8 + 17 * r, R[8 + r], I[8 + r]);
  }
  dft8<false>(R, I); dft8<false>(R + 8, I + 8);     // CONV-S
}

__device__ __forceinline__ float block_reduce_sum(float v, float* red, int tid) {
#pragma unroll
  for (int o = 32; o > 0; o >>= 1) v += __shfl_down(v, o);
  __syncthreads();
  if ((tid & 63) == 0) red[tid >> 6] = v;
  __syncthreads();
  float t = 0.0f;
  if (tid == 0) {
#pragma unroll
    for (int w = 0; w < 16; ++w) t += red[w];
  }
  return t;
}

// psi granule layout: float4 granule (plane, i, tid) = slots {2i, 2i+1} of
// consumer thread tid. Slot j at thread (g=tid&7, q=tid>>3) holds spectral
// (kr=q, kc=g+8(j>>3)+16(j&7)), 1/16384 folded in. Block 0 fills twg.
__global__ __launch_bounds__(256) void k_psi(const float* __restrict__ mags,
                                             const float* __restrict__ phases,
                                             float2* __restrict__ psi,
                                             float2* __restrict__ twg) {
  if (blockIdx.x == 0 && threadIdx.x < 128) {
    const int gg = threadIdx.x >> 4, k = threadIdx.x & 15;
    float sn, cs;
    __sincosf(-TWO_PI * (float)(gg * k) * (1.0f / 128.0f), &sn, &cs);
    twg[threadIdx.x] = make_float2(cs, sn);
  }
  const int gid = blockIdx.x * 256 + threadIdx.x;      // < 24*16384
  const int p = gid >> 14;
  const int rem = gid & (PLANE - 1);
  const int e = rem & 1;
  const int tt = (rem >> 1) & 1023;
  const int i = rem >> 11;
  const int j = 2 * i + e;
  const int g = tt & 7, q = tt >> 3;
  const int kr = q;
  const int kc = g + 8 * (j >> 3) + 16 * (j & 7);
  const int src = (p << 14) + kr * SDIM + kc;
  const float m = mags[src] * (1.0f / 16384.0f);
  float sn, cs;
  __sincosf(phases[src], &sn, &cs);
  psi[gid] = make_float2(m * cs, m * sn);
}

// fp32 LDS; stages image into transpose layout, fwd -> Xf granules. ~64 blocks.
__global__ __launch_bounds__(NT) void k_img_fft(const float* __restrict__ img,
                                                float2* __restrict__ Xf,
                                                float* __restrict__ s0,
                                                const float2* __restrict__ twg) {
  __shared__ float2 sC[128 * SSTR];
  __shared__ float red[16];
  const int tid = threadIdx.x, b = blockIdx.x;
  const int g = tid & 7, q = tid >> 3;
  float twr[9], twi[9];
  load_tw8(twg, g, twr, twi);
  const float* ip = img + b * PLANE;
  float sum = 0.0f;
#pragma unroll
  for (int kk = 0; kk < 16; ++kk) {
    const int e = tid + kk * NT;
    const float v = ip[e];
    const int nr = e >> 7, nc = e & 127;
    sC[(nr & 7) + 8 * (nc & 7) + 64 * (nr >> 3) + TBLK * (nc >> 3)] = make_float2(v, 0.0f);
    sum += v;
  }
  const float tot = block_reduce_sum(sum, red, tid);   // syncs publish sC
  if (tid == 0) s0[b] = tot * (1.0f / 16384.0f);
  __syncthreads();
  float R[16], I[16];
  {
    const int tb = g + 8 * (q & 7) + TBLK * (q >> 3);  // Tcell(g+8s, q)
#pragma unroll
    for (int s = 0; s < 16; ++s) { R[s] = sC[tb + 64 * s].x; I[s] = 0.0f; }
  }
  __syncthreads();                                     // staging reads done
  fwd_fft2(R, I, sC, twr, twi, g, q);
  float4* x4 = (float4*)Xf + (size_t)b * 8192 + tid;
#pragma unroll
  for (int i = 0; i < 8; ++i)
    x4[i * 1024] = make_float4(R[2 * i], I[2 * i], R[2 * i + 1], I[2 * i + 1]);
}

// Phase A: bid<1280: u1=|ifft2(Xf.psi1)|, U=fft2(u1) -> Ubuf + s1. bid>=1280: s1 j=5.
__global__ __launch_bounds__(NT, 8) void k_scat_a(const float2* __restrict__ Xf,
                                                  const float2* __restrict__ psi,
                                                  float* __restrict__ s1num,
                                                  unsigned* __restrict__ Ubuf,
                                                  const float2* __restrict__ twg) {
  __shared__ unsigned sU[128 * SSTR];          // 69.6 KB -> 2 blocks/CU
  __shared__ float red[16];
  const int tid = threadIdx.x;
  const int g = tid & 7, q = tid >> 3;
  float twr[9], twi[9];
  load_tw8(twg, g, twr, twi);
  const int bid = blockIdx.x;
  float R[16], I[16];

  if (bid < 1280) {
    const int j1 = bid >> 8;
    const int b = (bid & 255) >> 2;
    const int l1 = bid & 3;
    const float4* x4 = (const float4*)Xf + (size_t)b * 8192 + tid;
    const float4* p4 = (const float4*)psi + (size_t)(j1 * 4 + l1) * 8192 + tid;
#pragma unroll
    for (int i = 0; i < 8; ++i) {
      const float4 x = x4[i * 1024], v = p4[i * 1024];
      R[2 * i]     = x.x * v.x - x.y * v.y;  I[2 * i]     = x.x * v.y + x.y * v.x;
      R[2 * i + 1] = x.z * v.z - x.w * v.w;  I[2 * i + 1] = x.z * v.w + x.w * v.z;
    }
    inv_fft2(R, I, sU, twr, twi, g, q);
    float s1sum = 0.0f;
#pragma unroll
    for (int m = 0; m < 16; ++m) {
      const float a = fast_sqrtf(R[m] * R[m] + I[m] * I[m]);
      s1sum += a; R[m] = a; I[m] = 0.0f;
    }
    fwd_fft2(R, I, sU, twr, twi, g, q);
    uint4 ob[4];
    unsigned* obs = (unsigned*)ob;
#pragma unroll
    for (int j = 0; j < 16; ++j) obs[j] = packbf(R[j], I[j]);
    uint4* o4 = (uint4*)Ubuf + (size_t)((b * 5 + j1) * 4 + l1) * 4096 + tid;
#pragma unroll
    for (int i = 0; i < 4; ++i) o4[i * 1024] = ob[i];
    const float tot = block_reduce_sum(s1sum, red, tid);
    if (tid == 0) atomicAdd(&s1num[b * 6 + j1], tot);
  } else {
    const int idx = bid - 1280;
    const int b = idx >> 2, l = idx & 3;
    const float4* x4 = (const float4*)Xf + (size_t)b * 8192 + tid;
    const float4* p4 = (const float4*)psi + (size_t)(20 + l) * 8192 + tid;
#pragma unroll
    for (int i = 0; i < 8; ++i) {
      const float4 x = x4[i * 1024], v = p4[i * 1024];
      R[2 * i]     = x.x * v.x - x.y * v.y;  I[2 * i]     = x.x * v.y + x.y * v.x;
      R[2 * i + 1] = x.z * v.z - x.w * v.w;  I[2 * i + 1] = x.z * v.w + x.w * v.z;
    }
    inv_fft2(R, I, sU, twr, twi, g, q);
    float s = 0.0f;
#pragma unroll
    for (int m = 0; m < 16; ++m) s += fast_sqrtf(R[m] * R[m] + I[m] * I[m]);
    const float tot = block_reduce_sum(s, red, tid);
    if (tid == 0) atomicAdd(&s1num[b * 6 + 5], tot);
  }
}

// Phase B: one inner ifft per block. 15360 blocks; 2 blocks/CU residency binds.
__global__ __launch_bounds__(NT, 8) void k_scat_b(const float2* __restrict__ psi,
                                                  const unsigned* __restrict__ Ubuf,
                                                  float* __restrict__ s2num,
                                                  const float2* __restrict__ twg) {
  __shared__ unsigned sU[128 * SSTR];          // 69.6 KB -> 2 blocks/CU
  __shared__ float red[16];
  const int tid = threadIdx.x;
  const int g = tid & 7, q = tid >> 3;
  float twr[9], twi[9];
  load_tw8(twg, g, twr, twi);
  int t = blockIdx.x;
  const int l2 = t & 3; t >>= 2;
  const int pair = t % 15; t /= 15;
  const int l1 = t & 3;
  const int b = t >> 2;
  int j1 = 0, base = 0;
  if (pair >= 14)      { j1 = 4; base = 14; }
  else if (pair >= 12) { j1 = 3; base = 12; }
  else if (pair >= 9)  { j1 = 2; base = 9; }
  else if (pair >= 5)  { j1 = 1; base = 5; }
  const int j2 = j1 + 1 + (pair - base);
  float R[16], I[16];
  {
    const uint4* u4 = (const uint4*)Ubuf + (size_t)((b * 5 + j1) * 4 + l1) * 4096 + tid;
    uint4 ub[4];
#pragma unroll
    for (int i = 0; i < 4; ++i) ub[i] = u4[i * 1024];
    const unsigned* ubs = (const unsigned*)ub;
    const float4* p4 = (const float4*)psi + (size_t)(j2 * 4 + l2) * 8192 + tid;
#pragma unroll
    for (int i = 0; i < 8; ++i) {
      const float4 v = p4[i * 1024];
      float ur, ui;
      unpackbf(ubs[2 * i], ur, ui);
      R[2 * i] = ur * v.x - ui * v.y;      I[2 * i] = ur * v.y + ui * v.x;
      unpackbf(ubs[2 * i + 1], ur, ui);
      R[2 * i + 1] = ur * v.z - ui * v.w;  I[2 * i + 1] = ur * v.w + ui * v.z;
    }
  }
  inv_fft2(R, I, sU, twr, twi, g, q);
  float vsum = 0.0f;
#pragma unroll
  for (int m = 0; m < 16; ++m) vsum += fast_sqrtf(R[m] * R[m] + I[m] * I[m]);
  const float tot = block_reduce_sum(vsum, red, tid);
  if (tid == 0) atomicAdd(&s2num[b * 15 + pair], tot);
}

// Fallback (ws too small): monolithic; correctness only.
__global__ __launch_bounds__(NT) void k_scat_mono(const float2* __restrict__ Xf,
                                                  const float2* __restrict__ psi,
                                                  float* __restrict__ s1num,
                                                  float* __restrict__ s2num,
                                                  const float2* __restrict__ twg) {
  __shared__ unsigned sU[128 * SSTR];
  __shared__ float red[16];
  const int tid = threadIdx.x;
  const int g = tid & 7, q = tid >> 3;
  float twr[9], twi[9];
  load_tw8(twg, g, twr, twi);
  const int bid = blockIdx.x;
  float R[16], I[16];
  if (bid < 1280) {
    const int j1 = bid >> 8;
    const int b = (bid & 255) >> 2;
    const int l1 = bid & 3;
    const float4* x4 = (const float4*)Xf + (size_t)b * 8192 + tid;
    const float4* p4 = (const float4*)psi + (size_t)(j1 * 4 + l1) * 8192 + tid;
#pragma unroll
    for (int i = 0; i < 8; ++i) {
      const float4 x = x4[i * 1024], v = p4[i * 1024];
      R[2 * i]     = x.x * v.x - x.y * v.y;  I[2 * i]     = x.x * v.y + x.y * v.x;
      R[2 * i + 1] = x.z * v.z - x.w * v.w;  I[2 * i + 1] = x.z * v.w + x.w * v.z;
    }
    inv_fft2(R, I, sU, twr, twi, g, q);
    float s1sum = 0.0f;
#pragma unroll
    for (int m = 0; m < 16; ++m) {
      const float a = fast_sqrtf(R[m] * R[m] + I[m] * I[m]);
      s1sum += a; R[m] = a; I[m] = 0.0f;
    }
    fwd_fft2(R, I, sU, twr, twi, g, q);
    float Ur[16], Ui[16];
#pragma unroll
    for (int k = 0; k < 16; ++k) { Ur[k] = R[k]; Ui[k] = I[k]; }
    {
      const float tot = block_reduce_sum(s1sum, red, tid);
      if (tid == 0) atomicAdd(&s1num[b * 6 + j1], tot);
    }
    const int pb = (j1 * (11 - j1)) >> 1;
    int plane = (j1 + 1) * 4;
#pragma unroll 1
    for (int j2 = j1 + 1; j2 <= 5; ++j2) {
      float vsum = 0.0f;
#pragma unroll 1
      for (int l2 = 0; l2 < 4; ++l2) {
        const float4* q4 = (const float4*)psi + (size_t)plane * 8192 + tid;
#pragma unroll
        for (int i = 0; i < 8; ++i) {
          const float4 v = q4[i * 1024];
          R[2 * i]     = Ur[2 * i] * v.x - Ui[2 * i] * v.y;
          I[2 * i]     = Ur[2 * i] * v.y + Ui[2 * i] * v.x;
          R[2 * i + 1] = Ur[2 * i + 1] * v.z - Ui[2 * i + 1] * v.w;
          I[2 * i + 1] = Ur[2 * i + 1] * v.w + Ui[2 * i + 1] * v.z;
        }
        inv_fft2(R, I, sU, twr, twi, g, q);
#pragma unroll
        for (int m = 0; m < 16; ++m) vsum += fast_sqrtf(R[m] * R[m] + I[m] * I[m]);
        ++plane;
      }
      const float tot = block_reduce_sum(vsum, red, tid);
      if (tid == 0) atomicAdd(&s2num[b * 15 + pb + (j2 - j1 - 1)], tot);
    }
  } else {
    const int idx = bid - 1280;
    const int b = idx >> 2, l = idx & 3;
    const float4* x4 = (const float4*)Xf + (size_t)b * 8192 + tid;
    const float4* p4 = (const float4*)psi + (size_t)(20 + l) * 8192 + tid;
#pragma unroll
    for (int i = 0; i < 8; ++i) {
      const float4 x = x4[i * 1024], v = p4[i * 1024];
      R[2 * i]     = x.x * v.x - x.y * v.y;  I[2 * i]     = x.x * v.y + x.y * v.x;
      R[2 * i + 1] = x.z * v.z - x.w * v.w;  I[2 * i + 1] = x.z * v.w + x.w * v.z;
    }
    inv_fft2(R, I, sU, twr, twi, g, q);
    float s = 0.0f;
#pragma unroll
    for (int m = 0; m < 16; ++m) s += fast_sqrtf(R[m] * R[m] + I[m] * I[m]);
    const float tot = block_reduce_sum(s, red, tid);
    if (tid == 0) atomicAdd(&s1num[b * 6 + 5], tot);
  }
}

__global__ __launch_bounds__(64) void k_final(const float* __restrict__ s0,
                                              const float* __restrict__ s1num,
                                              const float* __restrict__ s2num,
                                              const float* __restrict__ w1,
                                              const float* __restrict__ b1,
                                              const float* __restrict__ w2,
                                              const float* __restrict__ b2,
                                              const float* __restrict__ w3,
                                              const float* __restrict__ b3,
                                              float* __restrict__ out) {
  const int b = threadIdx.x;
  if (b >= 64) return;
  float x[22];
  x[0] = s0[b];
#pragma unroll
  for (int j = 0; j < 6; ++j) x[1 + j] = s1num[b * 6 + j] * (1.0f / (4.0f * 16384.0f));
#pragma unroll
  for (int p = 0; p < 15; ++p) x[7 + p] = s2num[b * 15 + p] * (1.0f / (16.0f * 16384.0f));
  float h1[16];
#pragma unroll
  for (int o = 0; o < 16; ++o) {
    float t = b1[o];
    for (int i = 0; i < 22; ++i) t += x[i] * w1[i * 16 + o];
    h1[o] = fmaxf(t, 0.0f);
  }
  float h2[16];
#pragma unroll
  for (int o = 0; o < 16; ++o) {
    float t = b2[o];
    for (int i = 0; i < 16; ++i) t += h1[i] * w2[i * 16 + o];
    h2[o] = fmaxf(t, 0.0f);
  }
  float t = b3[0];
#pragma unroll
  for (int i = 0; i < 16; ++i) t += h2[i] * w3[i];
  out[b] = 1.0f / (1.0f + expf(-t));
}

extern "C" void kernel_launch(void* const* d_in, const int* in_sizes, int n_in,
                              void* d_out, int out_size, void* d_ws, size_t ws_size,
                              hipStream_t stream) {
  (void)in_sizes; (void)n_in; (void)out_size;
  const float* image  = (const float*)d_in[0];
  const float* mags   = (const float*)d_in[1];
  const float* phases = (const float*)d_in[2];
  const float* w1 = (const float*)d_in[3];
  const float* b1 = (const float*)d_in[4];
  const float* w2 = (const float*)d_in[5];
  const float* b2 = (const float*)d_in[6];
  const float* w3 = (const float*)d_in[7];
  const float* b3 = (const float*)d_in[8];
  float* out = (float*)d_out;

  char* ws = (char*)d_ws;
  float2* psi = (float2*)ws;                       // 3,145,728 B
  float2* Xf  = (float2*)(ws + 3145728);           // 8,388,608 B
  float*  s0  = (float*)(ws + 11534336);           // 64
  float*  s1n = s0 + 64;                           // 384
  float*  s2n = s1n + 384;                         // 960
  float2* twg = (float2*)(s2n + 960);              // 128 float2
  unsigned* Ubuf = (unsigned*)(ws + 11542528);     // 83,886,080 B
  const size_t need = 11542528ull + 83886080ull;   // ~95.4 MB

  hipMemsetAsync(s1n, 0, (384 + 960) * sizeof(float), stream);
  k_psi<<<dim3(1536), dim3(256), 0, stream>>>(mags, phases, psi, twg);
  k_img_fft<<<dim3(64), dim3(NT), 0, stream>>>(image, Xf, s0, twg);
  if (ws_size >= need) {
    k_scat_a<<<dim3(1536), dim3(NT), 0, stream>>>(Xf, psi, s1n, Ubuf, twg);
    k_scat_b<<<dim3(15360), dim3(NT), 0, stream>>>(psi, Ubuf, s2n, twg);
  } else {
    k_scat_mono<<<dim3(1536), dim3(NT), 0, stream>>>(Xf, psi, s1n, s2n, twg);
  }
  k_final<<<dim3(1), dim3(64), 0, stream>>>(s0, s1n, s2n, w1, b1, w2, b2, w3, b3, out);
}

// Round 7
// 482.321 us; speedup vs baseline: 1.2302x; 1.2302x over previous
//
#include <hip/hip_runtime.h>
#include <math.h>

// Scattering net: four-step register FFT (r5 structure: g=tid>>7 wave-uniform,
// q=tid&127; granule global layouts; SGPR twiddles; LDS pairing; fast sqrt).
//
// Round-18: DUAL-PLANE f16x2 k_scat_b. r17 (wave-local) reverted: +7.8M bank
// conflicts, lgkmcnt(0) fences serialized phases, absmax crept up. New lever:
// CDNA packed f16 is a TRUE 2x-rate pipe (unlike pk_f32, r12): pack two l2
// planes into the f16 halves of each register -> one inv_fft2 instruction
// stream computes TWO iffts (s2 sums over l2, both halves fold into one
// reduction). LDS cell = (re2,im2) 8B ds_*_b64: DS instr per ifft ~halved.
// LDS 128*129*8 = 132KB -> 1 block/CU (4 waves/SIMD) -- per-round pipe work
// halves, so net win predicted. psi for j2>=1 additionally packed as f16x2
// pairs (x16 scale, folded out in k_final). U stays bf16 (fits f16 range,
// |U| <~ 12k << 65504); mag^2+sqrt in f32 for range safety.
// Tiers: ws >= need_h2 -> dual path; >= need_r5 -> r5 f32 path; else mono.

#define SDIM 128
#define PLANE 16384
#define PITCH 129
#define NT 1024
#define TWO_PI 6.28318530717958647692f
#define PSIH_SCALE 16.0f

typedef _Float16 h2 __attribute__((ext_vector_type(2)));

constexpr float W16R[8] = {1.f, 0.9238795325f, 0.7071067812f, 0.3826834324f,
                           0.f, -0.3826834324f, -0.7071067812f, -0.9238795325f};
constexpr float W16I[8] = {0.f, -0.3826834324f, -0.7071067812f, -0.9238795325f,
                           -1.f, -0.9238795325f, -0.7071067812f, -0.3826834324f};

__device__ __forceinline__ float fast_sqrtf(float x) { return __builtin_amdgcn_sqrtf(x); }

// ---- packed bf16 complex <-> fp32 pair ----
__device__ __forceinline__ unsigned packbf(float re, float im) {
  const unsigned r = __float_as_uint(re) + 0x8000u;
  const unsigned i = __float_as_uint(im) + 0x8000u;
  return __builtin_amdgcn_perm(r, i, 0x07060302u);
}
__device__ __forceinline__ void unpackbf(unsigned u, float& re, float& im) {
  re = __uint_as_float(u & 0xFFFF0000u);
  im = __uint_as_float(u << 16);
}

// ---- h2 helpers ----
union UHU { unsigned u; h2 h; };
__device__ __forceinline__ h2 u2h(unsigned u) { UHU x; x.u = u; return x.h; }
__device__ __forceinline__ unsigned h2u(h2 h) { UHU x; x.h = h; return x.u; }
__device__ __forceinline__ h2 bch2(float f) { const _Float16 h = (_Float16)f; h2 v = {h, h}; return v; }

// storage-polymorphic LDS access (f32 core)
__device__ __forceinline__ void stC(float2* s, int idx, float re, float im) { s[idx] = make_float2(re, im); }
__device__ __forceinline__ void ldC(const float2* s, int idx, float& re, float& im) { const float2 v = s[idx]; re = v.x; im = v.y; }
__device__ __forceinline__ void stC(unsigned* s, int idx, float re, float im) { s[idx] = packbf(re, im); }
__device__ __forceinline__ void ldC(const unsigned* s, int idx, float& re, float& im) { unpackbf(s[idx], re, im); }

// wave-uniform twiddle tables -> SGPRs (g = tid>>7 is wave-uniform).
__device__ __forceinline__ void load_tw(const float2* __restrict__ twg, int g,
                                        float* twr, float* twi) {
#pragma unroll
  for (int k = 1; k < 16; ++k) {
    const float2 w = twg[16 * g + k];
    twr[k] = __uint_as_float(__builtin_amdgcn_readfirstlane(__float_as_uint(w.x)));
    twi[k] = __uint_as_float(__builtin_amdgcn_readfirstlane(__float_as_uint(w.y)));
  }
}
__device__ __forceinline__ void load_twh(const uint2* __restrict__ twgh, int g,
                                         unsigned* twru, unsigned* twiu) {
#pragma unroll
  for (int k = 1; k < 16; ++k) {
    const uint2 w = twgh[16 * g + k];
    twru[k] = (unsigned)__builtin_amdgcn_readfirstlane((int)w.x);
    twiu[k] = (unsigned)__builtin_amdgcn_readfirstlane((int)w.y);
  }
}

// ---------------- f32 FFT core (r5, known-good) ----------------
template<bool INV>
__device__ __forceinline__ void bfly(float& ar, float& ai, float& br, float& bi, const int idx) {
  float tr, ti;
  if (idx == 0) { tr = br; ti = bi; }
  else if (idx == 4) {
    if (INV) { tr = -bi; ti = br; } else { tr = bi; ti = -br; }
  } else {
    const float wr = W16R[idx];
    const float wi = INV ? -W16I[idx] : W16I[idx];
    tr = br * wr - bi * wi;
    ti = br * wi + bi * wr;
  }
  br = ar - tr; bi = ai - ti;
  ar = ar + tr; ai = ai + ti;
}

#define CSWAP(re, im, a, b) { float _t = re[a]; re[a]=re[b]; re[b]=_t; _t = im[a]; im[a]=im[b]; im[b]=_t; }

template<bool INV>
__device__ __forceinline__ void dft16(float* re, float* im) {
  CSWAP(re, im, 1, 8) CSWAP(re, im, 2, 4) CSWAP(re, im, 3, 12)
  CSWAP(re, im, 5, 10) CSWAP(re, im, 7, 14) CSWAP(re, im, 11, 13)
#pragma unroll
  for (int ls = 1; ls <= 4; ++ls) {
    const int len = 1 << ls, half = len >> 1, tstep = 16 >> ls;
#pragma unroll
    for (int blk = 0; blk < 16; blk += len)
#pragma unroll
      for (int j = 0; j < half; ++j)
        bfly<INV>(re[blk + j], im[blk + j], re[blk + j + half], im[blk + j + half], j * tstep);
  }
}

template<bool INV>
__device__ __forceinline__ void dft8(float* re, float* im) {
  CSWAP(re, im, 1, 4) CSWAP(re, im, 3, 6)
#pragma unroll
  for (int ls = 1; ls <= 3; ++ls) {
    const int len = 1 << ls, half = len >> 1, tstep = 8 >> ls;
#pragma unroll
    for (int blk = 0; blk < 8; blk += len)
#pragma unroll
      for (int j = 0; j < half; ++j)
        bfly<INV>(re[blk + j], im[blk + j], re[blk + j + half], im[blk + j + half], j * tstep * 2);
  }
}

__device__ __forceinline__ void twmul_fwd(float* R, float* I, const float* twr, const float* twi) {
#pragma unroll
  for (int k = 1; k < 16; ++k) {
    const float r = R[k] * twr[k] - I[k] * twi[k];
    I[k] = R[k] * twi[k] + I[k] * twr[k]; R[k] = r;
  }
}
__device__ __forceinline__ void twmul_inv(float* R, float* I, const float* twr, const float* twi) {
#pragma unroll
  for (int k = 1; k < 16; ++k) {
    const float r = R[k] * twr[k] + I[k] * twi[k];
    I[k] = I[k] * twr[k] - R[k] * twi[k]; R[k] = r;
  }
}

template<typename S>
__device__ __forceinline__ void fwd_fft2(float* R, float* I, S* sC,
                                         int g, int q, const float* twr, const float* twi) {
  const int rb = q * PITCH;
  dft16<false>(R, I);
  twmul_fwd(R, I, twr, twi);
  __syncthreads();                             // B0
#pragma unroll
  for (int k = 0; k < 16; ++k) stC(sC, rb + 8 * k + g, R[k], I[k]);
  __syncthreads();                             // B1
#pragma unroll
  for (int t = 0; t < 8; ++t) {
    ldC(sC, rb + 16 * g + t, R[t], I[t]);
    ldC(sC, rb + 16 * g + 8 + t, R[8 + t], I[8 + t]);
  }
  dft8<false>(R, I); dft8<false>(R + 8, I + 8);
#pragma unroll
  for (int k2 = 0; k2 < 8; ++k2) {
    stC(sC, rb + 16 * g + k2, R[k2], I[k2]);
    stC(sC, rb + 16 * g + 8 + k2, R[8 + k2], I[8 + k2]);
  }
  __syncthreads();                             // B2
#pragma unroll
  for (int m = 0; m < 16; ++m) ldC(sC, (g + 8 * m) * PITCH + q, R[m], I[m]);
  dft16<false>(R, I);
  twmul_fwd(R, I, twr, twi);
#pragma unroll
  for (int k = 0; k < 16; ++k) stC(sC, (8 * k + g) * PITCH + q, R[k], I[k]);
  __syncthreads();                             // B3
#pragma unroll
  for (int u = 0; u < 8; ++u) {
    const int bp = (16 * g + 2 * u) * PITCH + q;
    ldC(sC, bp, R[2 * u], I[2 * u]);
    ldC(sC, bp + PITCH, R[2 * u + 1], I[2 * u + 1]);
  }
  dft8<false>(R, I); dft8<false>(R + 8, I + 8);
}

template<bool FIRST, typename S>
__device__ __forceinline__ void inv_fft2(float* R, float* I, S* sC,
                                         int g, int q, const float* twr, const float* twi) {
  const int rb = q * PITCH;
  dft8<true>(R, I); dft8<true>(R + 8, I + 8);
  if constexpr (!FIRST) __syncthreads();       // B0
#pragma unroll
  for (int t = 0; t < 16; ++t) stC(sC, rb + 16 * g + t, R[t], I[t]);
  __syncthreads();                             // B1
#pragma unroll
  for (int k = 0; k < 16; ++k) ldC(sC, rb + 8 * k + g, R[k], I[k]);
  twmul_inv(R, I, twr, twi);
  dft16<true>(R, I);
#pragma unroll
  for (int m = 0; m < 16; ++m) stC(sC, rb + g + 8 * m, R[m], I[m]);
  __syncthreads();                             // B2
#pragma unroll
  for (int u = 0; u < 8; ++u) {
    const int bp = (16 * g + 2 * u) * PITCH + q;
    ldC(sC, bp, R[2 * u], I[2 * u]);
    ldC(sC, bp + PITCH, R[2 * u + 1], I[2 * u + 1]);
  }
  dft8<true>(R, I); dft8<true>(R + 8, I + 8);
#pragma unroll
  for (int u = 0; u < 8; ++u) {
    const int bp = (16 * g + 2 * u) * PITCH + q;
    stC(sC, bp, R[2 * u], I[2 * u]);
    stC(sC, bp + PITCH, R[2 * u + 1], I[2 * u + 1]);
  }
  __syncthreads();                             // B3
#pragma unroll
  for (int k = 0; k < 16; ++k) ldC(sC, (8 * k + g) * PITCH + q, R[k], I[k]);
  twmul_inv(R, I, twr, twi);
  dft16<true>(R, I);
}

// ---------------- h2 FFT core (inverse only, dual-plane) ----------------
__device__ __forceinline__ void bfly_h_inv(h2& ar, h2& ai, h2& br, h2& bi, const int idx) {
  h2 tr, ti;
  if (idx == 0) { tr = br; ti = bi; }
  else if (idx == 4) { tr = -bi; ti = br; }   // w = +i (inverse)
  else {
    const h2 wr = bch2(W16R[idx]);
    const h2 wi = bch2(-W16I[idx]);
    tr = br * wr - bi * wi;
    ti = br * wi + bi * wr;
  }
  br = ar - tr; bi = ai - ti;
  ar = ar + tr; ai = ai + ti;
}

#define HSWAP(re, im, a, b) { h2 _t = re[a]; re[a]=re[b]; re[b]=_t; _t = im[a]; im[a]=im[b]; im[b]=_t; }

__device__ __forceinline__ void dft16h(h2* re, h2* im) {
  HSWAP(re, im, 1, 8) HSWAP(re, im, 2, 4) HSWAP(re, im, 3, 12)
  HSWAP(re, im, 5, 10) HSWAP(re, im, 7, 14) HSWAP(re, im, 11, 13)
#pragma unroll
  for (int ls = 1; ls <= 4; ++ls) {
    const int len = 1 << ls, half = len >> 1, tstep = 16 >> ls;
#pragma unroll
    for (int blk = 0; blk < 16; blk += len)
#pragma unroll
      for (int j = 0; j < half; ++j)
        bfly_h_inv(re[blk + j], im[blk + j], re[blk + j + half], im[blk + j + half], j * tstep);
  }
}

__device__ __forceinline__ void dft8h(h2* re, h2* im) {
  HSWAP(re, im, 1, 4) HSWAP(re, im, 3, 6)
#pragma unroll
  for (int ls = 1; ls <= 3; ++ls) {
    const int len = 1 << ls, half = len >> 1, tstep = 8 >> ls;
#pragma unroll
    for (int blk = 0; blk < 8; blk += len)
#pragma unroll
      for (int j = 0; j < half; ++j)
        bfly_h_inv(re[blk + j], im[blk + j], re[blk + j + half], im[blk + j + half], j * tstep * 2);
  }
}

__device__ __forceinline__ void twmul_inv_h(h2* R, h2* I, const unsigned* twru, const unsigned* twiu) {
#pragma unroll
  for (int k = 1; k < 16; ++k) {
    const h2 wr = u2h(twru[k]), wi = u2h(twiu[k]);
    const h2 r = R[k] * wr + I[k] * wi;
    I[k] = I[k] * wr - R[k] * wi;
    R[k] = r;
  }
}

// dual-plane inverse fft2, uint2 LDS cells (re2, im2), r5 barrier structure.
__device__ __forceinline__ void inv_fft2_h(h2* R, h2* I, uint2* sC,
                                           int g, int q,
                                           const unsigned* twru, const unsigned* twiu) {
  const int rb = q * PITCH;
  dft8h(R, I); dft8h(R + 8, I + 8);
#pragma unroll
  for (int t = 0; t < 16; ++t) sC[rb + 16 * g + t] = make_uint2(h2u(R[t]), h2u(I[t]));
  __syncthreads();                             // B1
#pragma unroll
  for (int k = 0; k < 16; ++k) { const uint2 v = sC[rb + 8 * k + g]; R[k] = u2h(v.x); I[k] = u2h(v.y); }
  twmul_inv_h(R, I, twru, twiu);
  dft16h(R, I);
#pragma unroll
  for (int m = 0; m < 16; ++m) sC[rb + g + 8 * m] = make_uint2(h2u(R[m]), h2u(I[m]));
  __syncthreads();                             // B2
#pragma unroll
  for (int u = 0; u < 8; ++u) {
    const int bp = (16 * g + 2 * u) * PITCH + q;
    const uint2 v0 = sC[bp];         R[2 * u] = u2h(v0.x);     I[2 * u] = u2h(v0.y);
    const uint2 v1 = sC[bp + PITCH]; R[2 * u + 1] = u2h(v1.x); I[2 * u + 1] = u2h(v1.y);
  }
  dft8h(R, I); dft8h(R + 8, I + 8);
#pragma unroll
  for (int u = 0; u < 8; ++u) {
    const int bp = (16 * g + 2 * u) * PITCH + q;
    sC[bp]         = make_uint2(h2u(R[2 * u]),     h2u(I[2 * u]));
    sC[bp + PITCH] = make_uint2(h2u(R[2 * u + 1]), h2u(I[2 * u + 1]));
  }
  __syncthreads();                             // B3
#pragma unroll
  for (int k = 0; k < 16; ++k) { const uint2 v = sC[(8 * k + g) * PITCH + q]; R[k] = u2h(v.x); I[k] = u2h(v.y); }
  twmul_inv_h(R, I, twru, twiu);
  dft16h(R, I);
}

__device__ __forceinline__ float block_reduce_sum(float v, float* red, int tid) {
#pragma unroll
  for (int o = 32; o > 0; o >>= 1) v += __shfl_down(v, o);
  __syncthreads();
  if ((tid & 63) == 0) red[tid >> 6] = v;
  __syncthreads();
  float t = 0.0f;
  if (tid == 0) {
#pragma unroll
    for (int w = 0; w < 16; ++w) t += red[w];
  }
  return t;
}

// psi f32 granules (r5) + psih dual f16 cells for j2 in [1,6).
// psih uint2 cell idx: (jp<<14) + (i*1024 + tid)*2 + e2; slot j = 2i+e2;
// halves = (l2=2*epair, 2*epair+1), jp = (j2-1)*2 + epair; value = psi * 16.
__global__ __launch_bounds__(256) void k_psi(const float* __restrict__ mags,
                                             const float* __restrict__ phases,
                                             float2* __restrict__ psi,
                                             float2* __restrict__ twg,
                                             uint2* __restrict__ psih2,
                                             uint2* __restrict__ twgh) {
  if (blockIdx.x == 0 && threadIdx.x < 128) {
    const int gg = threadIdx.x >> 4, k = threadIdx.x & 15;
    float sn, cs;
    __sincosf(-TWO_PI * (float)(gg * k) * (1.0f / 128.0f), &sn, &cs);
    twg[threadIdx.x] = make_float2(cs, sn);
    twgh[threadIdx.x] = make_uint2(h2u(bch2(cs)), h2u(bch2(sn)));
  }
  const int gid = blockIdx.x * 256 + threadIdx.x;
  if (gid < 24 * PLANE) {                              // f32 psi (r5 granules)
    const int p = gid >> 14;
    const int rem = gid & (PLANE - 1);
    const int e = rem & 1;
    const int tt = (rem >> 1) & 1023;
    const int i = rem >> 11;
    const int j = 2 * i + e;
    const int g = tt >> 7, q = tt & 127;
    const int pr = 16 * g + j, pc = q;
    const int kr = (pr >> 3) + 16 * (pr & 7);
    const int kc = (pc >> 3) + 16 * (pc & 7);
    const int src = (p << 14) + kr * SDIM + kc;
    const float m = mags[src] * (1.0f / 16384.0f);
    float sn, cs;
    __sincosf(phases[src], &sn, &cs);
    psi[gid] = make_float2(m * cs, m * sn);
  } else if (gid < 24 * PLANE + 10 * PLANE) {          // dual f16 psih
    const int c = gid - 24 * PLANE;
    const int jp = c >> 14;
    const int c14 = c & (PLANE - 1);
    const int e2 = c14 & 1;
    const int tmp = c14 >> 1;
    const int tt = tmp & 1023;
    const int i = tmp >> 10;
    const int j = 2 * i + e2;
    const int g = tt >> 7, q = tt & 127;
    const int pr = 16 * g + j, pc = q;
    const int kr = (pr >> 3) + 16 * (pr & 7);
    const int kc = (pc >> 3) + 16 * (pc & 7);
    const int j2 = 1 + (jp >> 1);
    const int epair = jp & 1;
    const int plane_lo = j2 * 4 + 2 * epair;
    const int src_lo = (plane_lo << 14) + kr * SDIM + kc;
    const int src_hi = src_lo + PLANE;
    const float scl = PSIH_SCALE / 16384.0f;
    const float m0 = mags[src_lo] * scl;
    const float m1 = mags[src_hi] * scl;
    float sn0, cs0, sn1, cs1;
    __sincosf(phases[src_lo], &sn0, &cs0);
    __sincosf(phases[src_hi], &sn1, &cs1);
    h2 re2 = { (_Float16)(m0 * cs0), (_Float16)(m1 * cs1) };
    h2 im2 = { (_Float16)(m0 * sn0), (_Float16)(m1 * sn1) };
    psih2[(jp << 14) + c14] = make_uint2(h2u(re2), h2u(im2));
  }
}

// fp32 LDS; Xf granule layout; ~5 us.
__global__ __launch_bounds__(NT) void k_img_fft(const float* __restrict__ img,
                                                float2* __restrict__ Xf,
                                                float* __restrict__ s0,
                                                const float2* __restrict__ twg) {
  __shared__ float2 sC[SDIM * PITCH];
  __shared__ float red[16];
  const int tid = threadIdx.x, b = blockIdx.x;
  const int g = __builtin_amdgcn_readfirstlane(tid >> 7);
  const int q = tid & 127;
  float twr[16], twi[16];
  load_tw(twg, g, twr, twi);
  const float* ip = img + b * PLANE;
  float sum = 0.0f;
#pragma unroll
  for (int kk = 0; kk < 16; ++kk) {
    const int e = tid + kk * NT;
    const float v = ip[e];
    sC[(e >> 7) * PITCH + (e & 127)] = make_float2(v, 0.0f);
    sum += v;
  }
  const float tot = block_reduce_sum(sum, red, tid);
  if (tid == 0) s0[b] = tot * (1.0f / 16384.0f);
  __syncthreads();
  float R[16], I[16];
#pragma unroll
  for (int m = 0; m < 16; ++m) { R[m] = sC[q * PITCH + g + 8 * m].x; I[m] = 0.0f; }
  fwd_fft2(R, I, sC, g, q, twr, twi);
  float4* x4 = (float4*)Xf + (size_t)b * 8192 + tid;
#pragma unroll
  for (int i = 0; i < 8; ++i)
    x4[i * 1024] = make_float4(R[2 * i], I[2 * i], R[2 * i + 1], I[2 * i + 1]);
}

// Phase A (r5): u1=|ifft2(Xf.psi1)|, U=fft2(u1) -> Ubuf + s1.
__global__ __launch_bounds__(NT) void k_scat_a(const float2* __restrict__ Xf,
                                               const float2* __restrict__ psi,
                                               float* __restrict__ s1num,
                                               unsigned* __restrict__ Ubuf,
                                               const float2* __restrict__ twg) {
  __shared__ unsigned sU[SDIM * PITCH];
  __shared__ float red[16];
  const int tid = threadIdx.x;
  const int g = __builtin_amdgcn_readfirstlane(tid >> 7);
  const int q = tid & 127;
  float twr[16], twi[16];
  load_tw(twg, g, twr, twi);
  const int bid = blockIdx.x;
  float R[16], I[16];

  if (bid < 1280) {
    const int j1 = bid >> 8;
    const int b = (bid & 255) >> 2;
    const int l1 = bid & 3;
    const float4* x4 = (const float4*)Xf + (size_t)b * 8192 + tid;
    const float4* p4 = (const float4*)psi + (size_t)(j1 * 4 + l1) * 8192 + tid;
#pragma unroll
    for (int i = 0; i < 8; ++i) {
      const float4 x = x4[i * 1024], v = p4[i * 1024];
      R[2 * i]     = x.x * v.x - x.y * v.y;  I[2 * i]     = x.x * v.y + x.y * v.x;
      R[2 * i + 1] = x.z * v.z - x.w * v.w;  I[2 * i + 1] = x.z * v.w + x.w * v.z;
    }
    inv_fft2<true>(R, I, sU, g, q, twr, twi);
    float s1sum = 0.0f;
#pragma unroll
    for (int m = 0; m < 16; ++m) {
      const float a = fast_sqrtf(R[m] * R[m] + I[m] * I[m]);
      s1sum += a; R[m] = a; I[m] = 0.0f;
    }
    fwd_fft2(R, I, sU, g, q, twr, twi);
    uint4 ob[4];
    unsigned* obs = (unsigned*)ob;
#pragma unroll
    for (int j = 0; j < 16; ++j) obs[j] = packbf(R[j], I[j]);
    uint4* o4 = (uint4*)Ubuf + (size_t)((b * 5 + j1) * 4 + l1) * 4096 + tid;
#pragma unroll
    for (int i = 0; i < 4; ++i) o4[i * 1024] = ob[i];
    const float tot = block_reduce_sum(s1sum, red, tid);
    if (tid == 0) atomicAdd(&s1num[b * 6 + j1], tot);
  } else {
    const int idx = bid - 1280;
    const int b = idx >> 2, l = idx & 3;
    const float4* x4 = (const float4*)Xf + (size_t)b * 8192 + tid;
    const float4* p4 = (const float4*)psi + (size_t)(20 + l) * 8192 + tid;
#pragma unroll
    for (int i = 0; i < 8; ++i) {
      const float4 x = x4[i * 1024], v = p4[i * 1024];
      R[2 * i]     = x.x * v.x - x.y * v.y;  I[2 * i]     = x.x * v.y + x.y * v.x;
      R[2 * i + 1] = x.z * v.z - x.w * v.w;  I[2 * i + 1] = x.z * v.w + x.w * v.z;
    }
    inv_fft2<true>(R, I, sU, g, q, twr, twi);
    float s = 0.0f;
#pragma unroll
    for (int m = 0; m < 16; ++m) s += fast_sqrtf(R[m] * R[m] + I[m] * I[m]);
    const float tot = block_reduce_sum(s, red, tid);
    if (tid == 0) atomicAdd(&s1num[b * 6 + 5], tot);
  }
}

// Phase B dual (h2): 7680 blocks = (b,pair,l1,e); two l2 in f16 halves.
// LDS 132KB -> 1 block/CU (16 waves).
__global__ __launch_bounds__(NT) void k_scat_b_h2(const uint4* __restrict__ psih4,
                                                  const unsigned* __restrict__ Ubuf,
                                                  float* __restrict__ s2num,
                                                  const uint2* __restrict__ twgh) {
  __shared__ uint2 sU[SDIM * PITCH];           // 132,096 B
  __shared__ float red[16];
  const int tid = threadIdx.x;
  const int g = __builtin_amdgcn_readfirstlane(tid >> 7);
  const int q = tid & 127;
  unsigned twru[16], twiu[16];
  load_twh(twgh, g, twru, twiu);
  int t = blockIdx.x;
  const int e = t & 1; t >>= 1;
  const int l1 = t & 3; t >>= 2;
  const int pair = t % 15;
  const int b = t / 15;
  int j1 = 0, base = 0;
  if (pair >= 14)      { j1 = 4; base = 14; }
  else if (pair >= 12) { j1 = 3; base = 12; }
  else if (pair >= 9)  { j1 = 2; base = 9; }
  else if (pair >= 5)  { j1 = 1; base = 5; }
  const int j2 = j1 + 1 + (pair - base);
  const int jp = (j2 - 1) * 2 + e;

  h2 R2[16], I2[16];
  {
    const uint4* u4 = (const uint4*)Ubuf + (size_t)((b * 5 + j1) * 4 + l1) * 4096 + tid;
    uint4 ub[4];
#pragma unroll
    for (int i = 0; i < 4; ++i) ub[i] = u4[i * 1024];
    const unsigned* ubs = (const unsigned*)ub;
    const uint4* p4 = psih4 + (size_t)jp * 8192 + tid;
#pragma unroll
    for (int i = 0; i < 8; ++i) {
      const uint4 pv = p4[i * 1024];
      float ur, ui;
      unpackbf(ubs[2 * i], ur, ui);
      {
        const h2 UR = bch2(ur), UI = bch2(ui);
        const h2 pr = u2h(pv.x), pi = u2h(pv.y);
        R2[2 * i] = UR * pr - UI * pi;
        I2[2 * i] = UR * pi + UI * pr;
      }
      unpackbf(ubs[2 * i + 1], ur, ui);
      {
        const h2 UR = bch2(ur), UI = bch2(ui);
        const h2 pr = u2h(pv.z), pi = u2h(pv.w);
        R2[2 * i + 1] = UR * pr - UI * pi;
        I2[2 * i + 1] = UR * pi + UI * pr;
      }
    }
  }
  inv_fft2_h(R2, I2, sU, g, q, twru, twiu);
  float vsum = 0.0f;
#pragma unroll
  for (int m = 0; m < 16; ++m) {
    const float rl = (float)R2[m].x, il = (float)I2[m].x;
    const float rh = (float)R2[m].y, ih = (float)I2[m].y;
    vsum += fast_sqrtf(rl * rl + il * il) + fast_sqrtf(rh * rh + ih * ih);
  }
  const float tot = block_reduce_sum(vsum, red, tid);
  if (tid == 0) atomicAdd(&s2num[b * 15 + pair], tot);
}

// Phase B f32 fallback (r5, tier-2).
__global__ __launch_bounds__(NT) void k_scat_b(const float2* __restrict__ psi,
                                               const unsigned* __restrict__ Ubuf,
                                               float* __restrict__ s2num,
                                               const float2* __restrict__ twg) {
  __shared__ unsigned sU[SDIM * PITCH];
  __shared__ float red[16];
  const int tid = threadIdx.x;
  const int g = __builtin_amdgcn_readfirstlane(tid >> 7);
  const int q = tid & 127;
  float twr[16], twi[16];
  load_tw(twg, g, twr, twi);
  int t = blockIdx.x;
  const int l2 = t & 3; t >>= 2;
  const int pair = t % 15; t /= 15;
  const int l1 = t & 3;
  const int b = t >> 2;
  int j1 = 0, base = 0;
  if (pair >= 14)      { j1 = 4; base = 14; }
  else if (pair >= 12) { j1 = 3; base = 12; }
  else if (pair >= 9)  { j1 = 2; base = 9; }
  else if (pair >= 5)  { j1 = 1; base = 5; }
  const int j2 = j1 + 1 + (pair - base);
  float R[16], I[16];
  {
    const uint4* u4 = (const uint4*)Ubuf + (size_t)((b * 5 + j1) * 4 + l1) * 4096 + tid;
    uint4 ub[4];
#pragma unroll
    for (int i = 0; i < 4; ++i) ub[i] = u4[i * 1024];
    const unsigned* ubs = (const unsigned*)ub;
    const float4* p4 = (const float4*)psi + (size_t)(j2 * 4 + l2) * 8192 + tid;
#pragma unroll
    for (int i = 0; i < 8; ++i) {
      const float4 v = p4[i * 1024];
      float ur, ui;
      unpackbf(ubs[2 * i], ur, ui);
      R[2 * i] = ur * v.x - ui * v.y;      I[2 * i] = ur * v.y + ui * v.x;
      unpackbf(ubs[2 * i + 1], ur, ui);
      R[2 * i + 1] = ur * v.z - ui * v.w;  I[2 * i + 1] = ur * v.w + ui * v.z;
    }
  }
  inv_fft2<true>(R, I, sU, g, q, twr, twi);
  float vsum = 0.0f;
#pragma unroll
  for (int m = 0; m < 16; ++m) vsum += fast_sqrtf(R[m] * R[m] + I[m] * I[m]);
  const float tot = block_reduce_sum(vsum, red, tid);
  if (tid == 0) atomicAdd(&s2num[b * 15 + pair], tot);
}

// Fallback (ws tiny): monolithic; correctness only.
__global__ __launch_bounds__(NT) void k_scat_mono(const float2* __restrict__ Xf,
                                                  const float2* __restrict__ psi,
                                                  float* __restrict__ s1num,
                                                  float* __restrict__ s2num,
                                                  const float2* __restrict__ twg) {
  __shared__ unsigned sU[SDIM * PITCH];
  __shared__ float red[16];
  const int tid = threadIdx.x;
  const int g = __builtin_amdgcn_readfirstlane(tid >> 7);
  const int q = tid & 127;
  float twr[16], twi[16];
  load_tw(twg, g, twr, twi);
  const int bid = blockIdx.x;
  float R[16], I[16];
  if (bid < 1280) {
    const int j1 = bid >> 8;
    const int b = (bid & 255) >> 2;
    const int l1 = bid & 3;
    const float4* x4 = (const float4*)Xf + (size_t)b * 8192 + tid;
    const float4* p4 = (const float4*)psi + (size_t)(j1 * 4 + l1) * 8192 + tid;
#pragma unroll
    for (int i = 0; i < 8; ++i) {
      const float4 x = x4[i * 1024], v = p4[i * 1024];
      R[2 * i]     = x.x * v.x - x.y * v.y;  I[2 * i]     = x.x * v.y + x.y * v.x;
      R[2 * i + 1] = x.z * v.z - x.w * v.w;  I[2 * i + 1] = x.z * v.w + x.w * v.z;
    }
    inv_fft2<true>(R, I, sU, g, q, twr, twi);
    float s1sum = 0.0f;
#pragma unroll
    for (int m = 0; m < 16; ++m) {
      const float a = fast_sqrtf(R[m] * R[m] + I[m] * I[m]);
      s1sum += a; R[m] = a; I[m] = 0.0f;
    }
    fwd_fft2(R, I, sU, g, q, twr, twi);
    float Ur[16], Ui[16];
#pragma unroll
    for (int k = 0; k < 16; ++k) { Ur[k] = R[k]; Ui[k] = I[k]; }
    {
      const float tot = block_reduce_sum(s1sum, red, tid);
      if (tid == 0) atomicAdd(&s1num[b * 6 + j1], tot);
    }
    const int pb = (j1 * (11 - j1)) >> 1;
    int plane = (j1 + 1) * 4;
#pragma unroll 1
    for (int j2 = j1 + 1; j2 <= 5; ++j2) {
      float vsum = 0.0f;
#pragma unroll 1
      for (int l2 = 0; l2 < 4; ++l2) {
        const float4* q4 = (const float4*)psi + (size_t)plane * 8192 + tid;
#pragma unroll
        for (int i = 0; i < 8; ++i) {
          const float4 v = q4[i * 1024];
          R[2 * i]     = Ur[2 * i] * v.x - Ui[2 * i] * v.y;
          I[2 * i]     = Ur[2 * i] * v.y + Ui[2 * i] * v.x;
          R[2 * i + 1] = Ur[2 * i + 1] * v.z - Ui[2 * i + 1] * v.w;
          I[2 * i + 1] = Ur[2 * i + 1] * v.w + Ui[2 * i + 1] * v.z;
        }
        inv_fft2<false>(R, I, sU, g, q, twr, twi);
#pragma unroll
        for (int m = 0; m < 16; ++m) vsum += fast_sqrtf(R[m] * R[m] + I[m] * I[m]);
        ++plane;
      }
      const float tot = block_reduce_sum(vsum, red, tid);
      if (tid == 0) atomicAdd(&s2num[b * 15 + pb + (j2 - j1 - 1)], tot);
    }
  } else {
    const int idx = bid - 1280;
    const int b = idx >> 2, l = idx & 3;
    const float4* x4 = (const float4*)Xf + (size_t)b * 8192 + tid;
    const float4* p4 = (const float4*)psi + (size_t)(20 + l) * 8192 + tid;
#pragma unroll
    for (int i = 0; i < 8; ++i) {
      const float4 x = x4[i * 1024], v = p4[i * 1024];
      R[2 * i]     = x.x * v.x - x.y * v.y;  I[2 * i]     = x.x * v.y + x.y * v.x;
      R[2 * i + 1] = x.z * v.z - x.w * v.w;  I[2 * i + 1] = x.z * v.w + x.w * v.z;
    }
    inv_fft2<true>(R, I, sU, g, q, twr, twi);
    float s = 0.0f;
#pragma unroll
    for (int m = 0; m < 16; ++m) s += fast_sqrtf(R[m] * R[m] + I[m] * I[m]);
    const float tot = block_reduce_sum(s, red, tid);
    if (tid == 0) atomicAdd(&s1num[b * 6 + 5], tot);
  }
}

__global__ __launch_bounds__(64) void k_final(const float* __restrict__ s0,
                                              const float* __restrict__ s1num,
                                              const float* __restrict__ s2num,
                                              const float* __restrict__ w1,
                                              const float* __restrict__ b1,
                                              const float* __restrict__ w2,
                                              const float* __restrict__ b2,
                                              const float* __restrict__ w3,
                                              const float* __restrict__ b3,
                                              float* __restrict__ out,
                                              float s2scale) {
  const int b = threadIdx.x;
  if (b >= 64) return;
  float x[22];
  x[0] = s0[b];
#pragma unroll
  for (int j = 0; j < 6; ++j) x[1 + j] = s1num[b * 6 + j] * (1.0f / (4.0f * 16384.0f));
#pragma unroll
  for (int p = 0; p < 15; ++p) x[7 + p] = s2num[b * 15 + p] * s2scale;
  float h1[16];
#pragma unroll
  for (int o = 0; o < 16; ++o) {
    float t = b1[o];
    for (int i = 0; i < 22; ++i) t += x[i] * w1[i * 16 + o];
    h1[o] = fmaxf(t, 0.0f);
  }
  float h2a[16];
#pragma unroll
  for (int o = 0; o < 16; ++o) {
    float t = b2[o];
    for (int i = 0; i < 16; ++i) t += h1[i] * w2[i * 16 + o];
    h2a[o] = fmaxf(t, 0.0f);
  }
  float t = b3[0];
#pragma unroll
  for (int i = 0; i < 16; ++i) t += h2a[i] * w3[i];
  out[b] = 1.0f / (1.0f + expf(-t));
}

extern "C" void kernel_launch(void* const* d_in, const int* in_sizes, int n_in,
                              void* d_out, int out_size, void* d_ws, size_t ws_size,
                              hipStream_t stream) {
  (void)in_sizes; (void)n_in; (void)out_size;
  const float* image  = (const float*)d_in[0];
  const float* mags   = (const float*)d_in[1];
  const float* phases = (const float*)d_in[2];
  const float* w1 = (const float*)d_in[3];
  const float* b1 = (const float*)d_in[4];
  const float* w2 = (const float*)d_in[5];
  const float* b2 = (const float*)d_in[6];
  const float* w3 = (const float*)d_in[7];
  const float* b3 = (const float*)d_in[8];
  float* out = (float*)d_out;

  char* ws = (char*)d_ws;
  float2* psi = (float2*)ws;                       // 3,145,728 B
  float2* Xf  = (float2*)(ws + 3145728);           // 8,388,608 B
  float*  s0  = (float*)(ws + 11534336);           // 64
  float*  s1n = s0 + 64;                           // 384
  float*  s2n = s1n + 384;                         // 960
  float2* twg = (float2*)(s2n + 960);              // 128 float2 (1024 B)
  uint2*  twgh = (uint2*)((char*)twg + 1024);      // 128 uint2 (1024 B)
  unsigned* Ubuf = (unsigned*)(ws + 11542528);     // 83,886,080 B
  uint2*  psih2 = (uint2*)(ws + 95428608);         // 1,310,720 B (10 dual planes)
  const size_t need_r5 = 11542528ull + 83886080ull;          // 95,428,608
  const size_t need_h2 = need_r5 + 1310720ull;               // 96,739,328

  hipMemsetAsync(s1n, 0, (384 + 960) * sizeof(float), stream);
  if (ws_size >= need_h2) {
    k_psi<<<dim3(2176), dim3(256), 0, stream>>>(mags, phases, psi, twg, psih2, twgh);
    k_img_fft<<<dim3(64), dim3(NT), 0, stream>>>(image, Xf, s0, twg);
    k_scat_a<<<dim3(1536), dim3(NT), 0, stream>>>(Xf, psi, s1n, Ubuf, twg);
    k_scat_b_h2<<<dim3(7680), dim3(NT), 0, stream>>>((const uint4*)psih2, Ubuf, s2n, twgh);
    k_final<<<dim3(1), dim3(64), 0, stream>>>(s0, s1n, s2n, w1, b1, w2, b2, w3, b3, out,
                                              1.0f / (16.0f * 16384.0f * PSIH_SCALE));
  } else if (ws_size >= need_r5) {
    k_psi<<<dim3(1536), dim3(256), 0, stream>>>(mags, phases, psi, twg, psih2, twgh);
    k_img_fft<<<dim3(64), dim3(NT), 0, stream>>>(image, Xf, s0, twg);
    k_scat_a<<<dim3(1536), dim3(NT), 0, stream>>>(Xf, psi, s1n, Ubuf, twg);
    k_scat_b<<<dim3(15360), dim3(NT), 0, stream>>>(psi, Ubuf, s2n, twg);
    k_final<<<dim3(1), dim3(64), 0, stream>>>(s0, s1n, s2n, w1, b1, w2, b2, w3, b3, out,
                                              1.0f / (16.0f * 16384.0f));
  } else {
    k_psi<<<dim3(1536), dim3(256), 0, stream>>>(mags, phases, psi, twg, psih2, twgh);
    k_img_fft<<<dim3(64), dim3(NT), 0, stream>>>(image, Xf, s0, twg);
    k_scat_mono<<<dim3(1536), dim3(NT), 0, stream>>>(Xf, psi, s1n, s2n, twg);
    k_final<<<dim3(1), dim3(64), 0, stream>>>(s0, s1n, s2n, w1, b1, w2, b2, w3, b3, out,
                                              1.0f / (16.0f * 16384.0f));
  }
}

// Round 8
// 463.738 us; speedup vs baseline: 1.2795x; 1.0401x over previous
//
#include <hip/hip_runtime.h>
#include <math.h>

// Scattering net: four-step register FFT (r5 structure for f32 kernels).
//
// Round-19: ROW-PAIR f16 k_scat_b. r18 (dual-l2 f16, 132KB LDS) halved VALU
// (VALUBusy 145->69) but gained only 9%: 1 block/CU exposed every barrier as
// a full-CU stall. Fix: pack the two f16 halves as LINE-PAIRS (q, q+64) of
// ONE plane -> LDS = 64 strips x 129 x 8B = 66KB -> 2 blocks/CU of 512 thr
// (16 waves in 2 barrier-independent blocks). Same VALU/DS halving; grid
// back to 15360. New: transpose re-pairs halves (col-pairs -> row-pairs) via
// 2x ds_read_b64 + 2x v_perm per slot + one guard barrier (4 total).
// g = tid>>6 stays wave-uniform -> SGPR twiddles. psih: per-plane h2 layout
// [pidx][j][t512] pairing cols (q, q+64), x16 scale (folded in k_final).
// Ubuf unchanged (rp thread loads two r5-granule virtual tids, coalesced).

#define SDIM 128
#define PLANE 16384
#define PITCH 129
#define NT 1024
#define TWO_PI 6.28318530717958647692f
#define PSIH_SCALE 16.0f

typedef _Float16 h2 __attribute__((ext_vector_type(2)));

constexpr float W16R[8] = {1.f, 0.9238795325f, 0.7071067812f, 0.3826834324f,
                           0.f, -0.3826834324f, -0.7071067812f, -0.9238795325f};
constexpr float W16I[8] = {0.f, -0.3826834324f, -0.7071067812f, -0.9238795325f,
                           -1.f, -0.9238795325f, -0.7071067812f, -0.3826834324f};

__device__ __forceinline__ float fast_sqrtf(float x) { return __builtin_amdgcn_sqrtf(x); }

// ---- packed bf16 complex <-> fp32 pair ----
__device__ __forceinline__ unsigned packbf(float re, float im) {
  const unsigned r = __float_as_uint(re) + 0x8000u;
  const unsigned i = __float_as_uint(im) + 0x8000u;
  return __builtin_amdgcn_perm(r, i, 0x07060302u);
}
__device__ __forceinline__ void unpackbf(unsigned u, float& re, float& im) {
  re = __uint_as_float(u & 0xFFFF0000u);
  im = __uint_as_float(u << 16);
}

// ---- h2 helpers ----
union UHU { unsigned u; h2 h; };
__device__ __forceinline__ h2 u2h(unsigned u) { UHU x; x.u = u; return x.h; }
__device__ __forceinline__ unsigned h2u(h2 h) { UHU x; x.h = h; return x.u; }
__device__ __forceinline__ h2 bch2(float f) { const _Float16 h = (_Float16)f; h2 v = {h, h}; return v; }
__device__ __forceinline__ h2 mkh2(float a, float b) { h2 v = {(_Float16)a, (_Float16)b}; return v; }

// storage-polymorphic LDS access (f32 cores)
__device__ __forceinline__ void stC(float2* s, int idx, float re, float im) { s[idx] = make_float2(re, im); }
__device__ __forceinline__ void ldC(const float2* s, int idx, float& re, float& im) { const float2 v = s[idx]; re = v.x; im = v.y; }
__device__ __forceinline__ void stC(unsigned* s, int idx, float re, float im) { s[idx] = packbf(re, im); }
__device__ __forceinline__ void ldC(const unsigned* s, int idx, float& re, float& im) { unpackbf(s[idx], re, im); }

// wave-uniform twiddle tables -> SGPRs.
__device__ __forceinline__ void load_tw(const float2* __restrict__ twg, int g,
                                        float* twr, float* twi) {
#pragma unroll
  for (int k = 1; k < 16; ++k) {
    const float2 w = twg[16 * g + k];
    twr[k] = __uint_as_float(__builtin_amdgcn_readfirstlane(__float_as_uint(w.x)));
    twi[k] = __uint_as_float(__builtin_amdgcn_readfirstlane(__float_as_uint(w.y)));
  }
}
__device__ __forceinline__ void load_twh(const uint2* __restrict__ twgh, int g,
                                         unsigned* twru, unsigned* twiu) {
#pragma unroll
  for (int k = 1; k < 16; ++k) {
    const uint2 w = twgh[16 * g + k];
    twru[k] = (unsigned)__builtin_amdgcn_readfirstlane((int)w.x);
    twiu[k] = (unsigned)__builtin_amdgcn_readfirstlane((int)w.y);
  }
}

// ---------------- f32 FFT core (r5, known-good) ----------------
template<bool INV>
__device__ __forceinline__ void bfly(float& ar, float& ai, float& br, float& bi, const int idx) {
  float tr, ti;
  if (idx == 0) { tr = br; ti = bi; }
  else if (idx == 4) {
    if (INV) { tr = -bi; ti = br; } else { tr = bi; ti = -br; }
  } else {
    const float wr = W16R[idx];
    const float wi = INV ? -W16I[idx] : W16I[idx];
    tr = br * wr - bi * wi;
    ti = br * wi + bi * wr;
  }
  br = ar - tr; bi = ai - ti;
  ar = ar + tr; ai = ai + ti;
}

#define CSWAP(re, im, a, b) { float _t = re[a]; re[a]=re[b]; re[b]=_t; _t = im[a]; im[a]=im[b]; im[b]=_t; }

template<bool INV>
__device__ __forceinline__ void dft16(float* re, float* im) {
  CSWAP(re, im, 1, 8) CSWAP(re, im, 2, 4) CSWAP(re, im, 3, 12)
  CSWAP(re, im, 5, 10) CSWAP(re, im, 7, 14) CSWAP(re, im, 11, 13)
#pragma unroll
  for (int ls = 1; ls <= 4; ++ls) {
    const int len = 1 << ls, half = len >> 1, tstep = 16 >> ls;
#pragma unroll
    for (int blk = 0; blk < 16; blk += len)
#pragma unroll
      for (int j = 0; j < half; ++j)
        bfly<INV>(re[blk + j], im[blk + j], re[blk + j + half], im[blk + j + half], j * tstep);
  }
}

template<bool INV>
__device__ __forceinline__ void dft8(float* re, float* im) {
  CSWAP(re, im, 1, 4) CSWAP(re, im, 3, 6)
#pragma unroll
  for (int ls = 1; ls <= 3; ++ls) {
    const int len = 1 << ls, half = len >> 1, tstep = 8 >> ls;
#pragma unroll
    for (int blk = 0; blk < 8; blk += len)
#pragma unroll
      for (int j = 0; j < half; ++j)
        bfly<INV>(re[blk + j], im[blk + j], re[blk + j + half], im[blk + j + half], j * tstep * 2);
  }
}

__device__ __forceinline__ void twmul_fwd(float* R, float* I, const float* twr, const float* twi) {
#pragma unroll
  for (int k = 1; k < 16; ++k) {
    const float r = R[k] * twr[k] - I[k] * twi[k];
    I[k] = R[k] * twi[k] + I[k] * twr[k]; R[k] = r;
  }
}
__device__ __forceinline__ void twmul_inv(float* R, float* I, const float* twr, const float* twi) {
#pragma unroll
  for (int k = 1; k < 16; ++k) {
    const float r = R[k] * twr[k] + I[k] * twi[k];
    I[k] = I[k] * twr[k] - R[k] * twi[k]; R[k] = r;
  }
}

template<typename S>
__device__ __forceinline__ void fwd_fft2(float* R, float* I, S* sC,
                                         int g, int q, const float* twr, const float* twi) {
  const int rb = q * PITCH;
  dft16<false>(R, I);
  twmul_fwd(R, I, twr, twi);
  __syncthreads();                             // B0
#pragma unroll
  for (int k = 0; k < 16; ++k) stC(sC, rb + 8 * k + g, R[k], I[k]);
  __syncthreads();                             // B1
#pragma unroll
  for (int t = 0; t < 8; ++t) {
    ldC(sC, rb + 16 * g + t, R[t], I[t]);
    ldC(sC, rb + 16 * g + 8 + t, R[8 + t], I[8 + t]);
  }
  dft8<false>(R, I); dft8<false>(R + 8, I + 8);
#pragma unroll
  for (int k2 = 0; k2 < 8; ++k2) {
    stC(sC, rb + 16 * g + k2, R[k2], I[k2]);
    stC(sC, rb + 16 * g + 8 + k2, R[8 + k2], I[8 + k2]);
  }
  __syncthreads();                             // B2
#pragma unroll
  for (int m = 0; m < 16; ++m) ldC(sC, (g + 8 * m) * PITCH + q, R[m], I[m]);
  dft16<false>(R, I);
  twmul_fwd(R, I, twr, twi);
#pragma unroll
  for (int k = 0; k < 16; ++k) stC(sC, (8 * k + g) * PITCH + q, R[k], I[k]);
  __syncthreads();                             // B3
#pragma unroll
  for (int u = 0; u < 8; ++u) {
    const int bp = (16 * g + 2 * u) * PITCH + q;
    ldC(sC, bp, R[2 * u], I[2 * u]);
    ldC(sC, bp + PITCH, R[2 * u + 1], I[2 * u + 1]);
  }
  dft8<false>(R, I); dft8<false>(R + 8, I + 8);
}

template<bool FIRST, typename S>
__device__ __forceinline__ void inv_fft2(float* R, float* I, S* sC,
                                         int g, int q, const float* twr, const float* twi) {
  const int rb = q * PITCH;
  dft8<true>(R, I); dft8<true>(R + 8, I + 8);
  if constexpr (!FIRST) __syncthreads();       // B0
#pragma unroll
  for (int t = 0; t < 16; ++t) stC(sC, rb + 16 * g + t, R[t], I[t]);
  __syncthreads();                             // B1
#pragma unroll
  for (int k = 0; k < 16; ++k) ldC(sC, rb + 8 * k + g, R[k], I[k]);
  twmul_inv(R, I, twr, twi);
  dft16<true>(R, I);
#pragma unroll
  for (int m = 0; m < 16; ++m) stC(sC, rb + g + 8 * m, R[m], I[m]);
  __syncthreads();                             // B2
#pragma unroll
  for (int u = 0; u < 8; ++u) {
    const int bp = (16 * g + 2 * u) * PITCH + q;
    ldC(sC, bp, R[2 * u], I[2 * u]);
    ldC(sC, bp + PITCH, R[2 * u + 1], I[2 * u + 1]);
  }
  dft8<true>(R, I); dft8<true>(R + 8, I + 8);
#pragma unroll
  for (int u = 0; u < 8; ++u) {
    const int bp = (16 * g + 2 * u) * PITCH + q;
    stC(sC, bp, R[2 * u], I[2 * u]);
    stC(sC, bp + PITCH, R[2 * u + 1], I[2 * u + 1]);
  }
  __syncthreads();                             // B3
#pragma unroll
  for (int k = 0; k < 16; ++k) ldC(sC, (8 * k + g) * PITCH + q, R[k], I[k]);
  twmul_inv(R, I, twr, twi);
  dft16<true>(R, I);
}

// ---------------- h2 FFT core (inverse only) ----------------
__device__ __forceinline__ void bfly_h_inv(h2& ar, h2& ai, h2& br, h2& bi, const int idx) {
  h2 tr, ti;
  if (idx == 0) { tr = br; ti = bi; }
  else if (idx == 4) { tr = -bi; ti = br; }   // w = +i (inverse)
  else {
    const h2 wr = bch2(W16R[idx]);
    const h2 wi = bch2(-W16I[idx]);
    tr = br * wr - bi * wi;
    ti = br * wi + bi * wr;
  }
  br = ar - tr; bi = ai - ti;
  ar = ar + tr; ai = ai + ti;
}

#define HSWAP(re, im, a, b) { h2 _t = re[a]; re[a]=re[b]; re[b]=_t; _t = im[a]; im[a]=im[b]; im[b]=_t; }

__device__ __forceinline__ void dft16h(h2* re, h2* im) {
  HSWAP(re, im, 1, 8) HSWAP(re, im, 2, 4) HSWAP(re, im, 3, 12)
  HSWAP(re, im, 5, 10) HSWAP(re, im, 7, 14) HSWAP(re, im, 11, 13)
#pragma unroll
  for (int ls = 1; ls <= 4; ++ls) {
    const int len = 1 << ls, half = len >> 1, tstep = 16 >> ls;
#pragma unroll
    for (int blk = 0; blk < 16; blk += len)
#pragma unroll
      for (int j = 0; j < half; ++j)
        bfly_h_inv(re[blk + j], im[blk + j], re[blk + j + half], im[blk + j + half], j * tstep);
  }
}

__device__ __forceinline__ void dft8h(h2* re, h2* im) {
  HSWAP(re, im, 1, 4) HSWAP(re, im, 3, 6)
#pragma unroll
  for (int ls = 1; ls <= 3; ++ls) {
    const int len = 1 << ls, half = len >> 1, tstep = 8 >> ls;
#pragma unroll
    for (int blk = 0; blk < 8; blk += len)
#pragma unroll
      for (int j = 0; j < half; ++j)
        bfly_h_inv(re[blk + j], im[blk + j], re[blk + j + half], im[blk + j + half], j * tstep * 2);
  }
}

__device__ __forceinline__ void twmul_inv_h(h2* R, h2* I, const unsigned* twru, const unsigned* twiu) {
#pragma unroll
  for (int k = 1; k < 16; ++k) {
    const h2 wr = u2h(twru[k]), wi = u2h(twiu[k]);
    const h2 r = R[k] * wr + I[k] * wi;
    I[k] = I[k] * wr - R[k] * wi;
    R[k] = r;
  }
}

template<int NW>
__device__ __forceinline__ float block_reduce_sum(float v, float* red, int tid) {
#pragma unroll
  for (int o = 32; o > 0; o >>= 1) v += __shfl_down(v, o);
  __syncthreads();
  if ((tid & 63) == 0) red[tid >> 6] = v;
  __syncthreads();
  float t = 0.0f;
  if (tid == 0) {
#pragma unroll
    for (int w = 0; w < NW; ++w) t += red[w];
  }
  return t;
}

// psi f32 granules (r5) + psih row-pair h2 cells for planes 4..23:
// psih[pidx*8192 + j*512 + t512] = uint2{re2, im2}, halves = cols (q, q+64)
// of spectral row 16g+j (sigma-mapped), value = psi * PSIH_SCALE.
__global__ __launch_bounds__(256) void k_psi(const float* __restrict__ mags,
                                             const float* __restrict__ phases,
                                             float2* __restrict__ psi,
                                             float2* __restrict__ twg,
                                             uint2* __restrict__ psih,
                                             uint2* __restrict__ twgh) {
  if (blockIdx.x == 0 && threadIdx.x < 128) {
    const int gg = threadIdx.x >> 4, k = threadIdx.x & 15;
    float sn, cs;
    __sincosf(-TWO_PI * (float)(gg * k) * (1.0f / 128.0f), &sn, &cs);
    twg[threadIdx.x] = make_float2(cs, sn);
    twgh[threadIdx.x] = make_uint2(h2u(bch2(cs)), h2u(bch2(sn)));
  }
  const int gid = blockIdx.x * 256 + threadIdx.x;
  if (gid < 24 * PLANE) {                              // f32 psi (r5 granules)
    const int p = gid >> 14;
    const int rem = gid & (PLANE - 1);
    const int e = rem & 1;
    const int tt = (rem >> 1) & 1023;
    const int i = rem >> 11;
    const int j = 2 * i + e;
    const int g = tt >> 7, q = tt & 127;
    const int pr = 16 * g + j, pc = q;
    const int kr = (pr >> 3) + 16 * (pr & 7);
    const int kc = (pc >> 3) + 16 * (pc & 7);
    const int src = (p << 14) + kr * SDIM + kc;
    const float m = mags[src] * (1.0f / 16384.0f);
    float sn, cs;
    __sincosf(phases[src], &sn, &cs);
    psi[gid] = make_float2(m * cs, m * sn);
  } else if (gid < 24 * PLANE + 20 * 8192) {           // row-pair h2 psih
    const int c = gid - 24 * PLANE;
    const int pidx = c >> 13;
    const int rem = c & 8191;
    const int j = rem >> 9;
    const int t512 = rem & 511;
    const int g = t512 >> 6, q = t512 & 63;
    const int row = 16 * g + j;
    const int plane = pidx + 4;
    const int kr = (row >> 3) + 16 * (row & 7);
    const int kc0 = (q >> 3) + 16 * (q & 7);
    const int q1 = q + 64;
    const int kc1 = (q1 >> 3) + 16 * (q1 & 7);
    const int src0 = (plane << 14) + kr * SDIM + kc0;
    const int src1 = (plane << 14) + kr * SDIM + kc1;
    const float scl = PSIH_SCALE / 16384.0f;
    const float m0 = mags[src0] * scl;
    const float m1 = mags[src1] * scl;
    float sn0, cs0, sn1, cs1;
    __sincosf(phases[src0], &sn0, &cs0);
    __sincosf(phases[src1], &sn1, &cs1);
    psih[c] = make_uint2(h2u(mkh2(m0 * cs0, m1 * cs1)), h2u(mkh2(m0 * sn0, m1 * sn1)));
  }
}

// fp32 LDS; Xf granule layout; ~5 us.
__global__ __launch_bounds__(NT) void k_img_fft(const float* __restrict__ img,
                                                float2* __restrict__ Xf,
                                                float* __restrict__ s0,
                                                const float2* __restrict__ twg) {
  __shared__ float2 sC[SDIM * PITCH];
  __shared__ float red[16];
  const int tid = threadIdx.x, b = blockIdx.x;
  const int g = __builtin_amdgcn_readfirstlane(tid >> 7);
  const int q = tid & 127;
  float twr[16], twi[16];
  load_tw(twg, g, twr, twi);
  const float* ip = img + b * PLANE;
  float sum = 0.0f;
#pragma unroll
  for (int kk = 0; kk < 16; ++kk) {
    const int e = tid + kk * NT;
    const float v = ip[e];
    sC[(e >> 7) * PITCH + (e & 127)] = make_float2(v, 0.0f);
    sum += v;
  }
  const float tot = block_reduce_sum<16>(sum, red, tid);
  if (tid == 0) s0[b] = tot * (1.0f / 16384.0f);
  __syncthreads();
  float R[16], I[16];
#pragma unroll
  for (int m = 0; m < 16; ++m) { R[m] = sC[q * PITCH + g + 8 * m].x; I[m] = 0.0f; }
  fwd_fft2(R, I, sC, g, q, twr, twi);
  float4* x4 = (float4*)Xf + (size_t)b * 8192 + tid;
#pragma unroll
  for (int i = 0; i < 8; ++i)
    x4[i * 1024] = make_float4(R[2 * i], I[2 * i], R[2 * i + 1], I[2 * i + 1]);
}

// Phase A (r5): u1=|ifft2(Xf.psi1)|, U=fft2(u1) -> Ubuf + s1.
__global__ __launch_bounds__(NT) void k_scat_a(const float2* __restrict__ Xf,
                                               const float2* __restrict__ psi,
                                               float* __restrict__ s1num,
                                               unsigned* __restrict__ Ubuf,
                                               const float2* __restrict__ twg) {
  __shared__ unsigned sU[SDIM * PITCH];
  __shared__ float red[16];
  const int tid = threadIdx.x;
  const int g = __builtin_amdgcn_readfirstlane(tid >> 7);
  const int q = tid & 127;
  float twr[16], twi[16];
  load_tw(twg, g, twr, twi);
  const int bid = blockIdx.x;
  float R[16], I[16];

  if (bid < 1280) {
    const int j1 = bid >> 8;
    const int b = (bid & 255) >> 2;
    const int l1 = bid & 3;
    const float4* x4 = (const float4*)Xf + (size_t)b * 8192 + tid;
    const float4* p4 = (const float4*)psi + (size_t)(j1 * 4 + l1) * 8192 + tid;
#pragma unroll
    for (int i = 0; i < 8; ++i) {
      const float4 x = x4[i * 1024], v = p4[i * 1024];
      R[2 * i]     = x.x * v.x - x.y * v.y;  I[2 * i]     = x.x * v.y + x.y * v.x;
      R[2 * i + 1] = x.z * v.z - x.w * v.w;  I[2 * i + 1] = x.z * v.w + x.w * v.z;
    }
    inv_fft2<true>(R, I, sU, g, q, twr, twi);
    float s1sum = 0.0f;
#pragma unroll
    for (int m = 0; m < 16; ++m) {
      const float a = fast_sqrtf(R[m] * R[m] + I[m] * I[m]);
      s1sum += a; R[m] = a; I[m] = 0.0f;
    }
    fwd_fft2(R, I, sU, g, q, twr, twi);
    uint4 ob[4];
    unsigned* obs = (unsigned*)ob;
#pragma unroll
    for (int j = 0; j < 16; ++j) obs[j] = packbf(R[j], I[j]);
    uint4* o4 = (uint4*)Ubuf + (size_t)((b * 5 + j1) * 4 + l1) * 4096 + tid;
#pragma unroll
    for (int i = 0; i < 4; ++i) o4[i * 1024] = ob[i];
    const float tot = block_reduce_sum<16>(s1sum, red, tid);
    if (tid == 0) atomicAdd(&s1num[b * 6 + j1], tot);
  } else {
    const int idx = bid - 1280;
    const int b = idx >> 2, l = idx & 3;
    const float4* x4 = (const float4*)Xf + (size_t)b * 8192 + tid;
    const float4* p4 = (const float4*)psi + (size_t)(20 + l) * 8192 + tid;
#pragma unroll
    for (int i = 0; i < 8; ++i) {
      const float4 x = x4[i * 1024], v = p4[i * 1024];
      R[2 * i]     = x.x * v.x - x.y * v.y;  I[2 * i]     = x.x * v.y + x.y * v.x;
      R[2 * i + 1] = x.z * v.z - x.w * v.w;  I[2 * i + 1] = x.z * v.w + x.w * v.z;
    }
    inv_fft2<true>(R, I, sU, g, q, twr, twi);
    float s = 0.0f;
#pragma unroll
    for (int m = 0; m < 16; ++m) s += fast_sqrtf(R[m] * R[m] + I[m] * I[m]);
    const float tot = block_reduce_sum<16>(s, red, tid);
    if (tid == 0) atomicAdd(&s1num[b * 6 + 5], tot);
  }
}

// Phase B row-pair h2: 15360 blocks x 512 threads; 66KB -> 2 blocks/CU.
// Thread (g=tid>>6 wave-uniform, q=tid&63) owns line-pair (q, q+64) in the
// two f16 halves. Pass 1: column-pairs; transpose re-pairs to row-pairs.
__global__ __launch_bounds__(512, 4) void k_scat_b_rp(const uint2* __restrict__ psih,
                                                      const unsigned* __restrict__ Ubuf,
                                                      float* __restrict__ s2num,
                                                      const uint2* __restrict__ twgh) {
  __shared__ uint2 sU[64 * PITCH];             // 66,048 B
  __shared__ float red[8];
  const int tid = threadIdx.x;
  const int g = __builtin_amdgcn_readfirstlane(tid >> 6);
  const int q = tid & 63;
  unsigned twru[16], twiu[16];
  load_twh(twgh, g, twru, twiu);
  int t = blockIdx.x;
  const int l2 = t & 3; t >>= 2;
  const int pair = t % 15; t /= 15;
  const int l1 = t & 3;
  const int b = t >> 2;
  int j1 = 0, base = 0;
  if (pair >= 14)      { j1 = 4; base = 14; }
  else if (pair >= 12) { j1 = 3; base = 12; }
  else if (pair >= 9)  { j1 = 2; base = 9; }
  else if (pair >= 5)  { j1 = 1; base = 5; }
  const int j2 = j1 + 1 + (pair - base);
  const int pidx = j2 * 4 + l2 - 4;            // 0..19

  h2 R2[16], I2[16];
  {
    // U: two r5-granule virtual tids (cols q and q+64 of each row slot).
    const uint4* u4 = (const uint4*)Ubuf + (size_t)((b * 5 + j1) * 4 + l1) * 4096;
    const int t0 = g * 128 + q;
    uint4 ua[4], ub[4];
#pragma unroll
    for (int i = 0; i < 4; ++i) { ua[i] = u4[i * 1024 + t0]; ub[i] = u4[i * 1024 + t0 + 64]; }
    const unsigned* uas = (const unsigned*)ua;
    const unsigned* ubs = (const unsigned*)ub;
    const uint2* ph = psih + (size_t)pidx * 8192 + tid;
#pragma unroll
    for (int j = 0; j < 16; ++j) {
      float urL, uiL, urH, uiH;
      unpackbf(uas[j], urL, uiL);
      unpackbf(ubs[j], urH, uiH);
      const h2 UR = mkh2(urL, urH), UI = mkh2(uiL, uiH);
      const uint2 pv = ph[j * 512];
      const h2 pr = u2h(pv.x), pi = u2h(pv.y);
      R2[j] = UR * pr - UI * pi;
      I2[j] = UR * pi + UI * pr;
    }
  }

  const int sb = q * PITCH;
  // ---- pass 1: column-pair lines (elements = spectral rows) ----
  dft8h(R2, I2); dft8h(R2 + 8, I2 + 8);
#pragma unroll
  for (int s = 0; s < 16; ++s) sU[sb + 16 * g + s] = make_uint2(h2u(R2[s]), h2u(I2[s]));
  __syncthreads();                             // B1
#pragma unroll
  for (int k = 0; k < 16; ++k) { const uint2 v = sU[sb + 8 * k + g]; R2[k] = u2h(v.x); I2[k] = u2h(v.y); }
  twmul_inv_h(R2, I2, twru, twiu);
  dft16h(R2, I2);
#pragma unroll
  for (int m = 0; m < 16; ++m) sU[sb + g + 8 * m] = make_uint2(h2u(R2[m]), h2u(I2[m]));  // same cells
  __syncthreads();                             // B2
  // ---- transpose + re-pair: col-pair halves -> row-pair halves ----
  {
    const int s_base = (16 * g) & 63;          // strip of col (16g+j); halves sel by g
    const unsigned sel = (g < 4) ? 0x05040100u : 0x07060302u;
#pragma unroll
    for (int j = 0; j < 16; ++j) {
      const int cb = (s_base + j) * PITCH;
      const uint2 vA = sU[cb + q];             // rows q   (both col halves)
      const uint2 vB = sU[cb + q + 64];        // rows q+64
      R2[j] = u2h(__builtin_amdgcn_perm(vB.x, vA.x, sel));
      I2[j] = u2h(__builtin_amdgcn_perm(vB.y, vA.y, sel));
    }
  }
  // ---- pass 2: row-pair lines (elements = spectral cols) ----
  dft8h(R2, I2); dft8h(R2 + 8, I2 + 8);
  __syncthreads();                             // B3: transpose reads drained before re-key
#pragma unroll
  for (int s = 0; s < 16; ++s) sU[sb + 16 * g + s] = make_uint2(h2u(R2[s]), h2u(I2[s]));
  __syncthreads();                             // B4
#pragma unroll
  for (int k = 0; k < 16; ++k) { const uint2 v = sU[sb + 8 * k + g]; R2[k] = u2h(v.x); I2[k] = u2h(v.y); }
  twmul_inv_h(R2, I2, twru, twiu);
  dft16h(R2, I2);

  float vsum = 0.0f;
#pragma unroll
  for (int m = 0; m < 16; ++m) {
    const float rl = (float)R2[m].x, il = (float)I2[m].x;
    const float rh = (float)R2[m].y, ih = (float)I2[m].y;
    vsum += fast_sqrtf(rl * rl + il * il) + fast_sqrtf(rh * rh + ih * ih);
  }
  const float tot = block_reduce_sum<8>(vsum, red, tid);
  if (tid == 0) atomicAdd(&s2num[b * 15 + pair], tot);
}

// Phase B f32 fallback (r5, tier-2).
__global__ __launch_bounds__(NT) void k_scat_b(const float2* __restrict__ psi,
                                               const unsigned* __restrict__ Ubuf,
                                               float* __restrict__ s2num,
                                               const float2* __restrict__ twg) {
  __shared__ unsigned sU[SDIM * PITCH];
  __shared__ float red[16];
  const int tid = threadIdx.x;
  const int g = __builtin_amdgcn_readfirstlane(tid >> 7);
  const int q = tid & 127;
  float twr[16], twi[16];
  load_tw(twg, g, twr, twi);
  int t = blockIdx.x;
  const int l2 = t & 3; t >>= 2;
  const int pair = t % 15; t /= 15;
  const int l1 = t & 3;
  const int b = t >> 2;
  int j1 = 0, base = 0;
  if (pair >= 14)      { j1 = 4; base = 14; }
  else if (pair >= 12) { j1 = 3; base = 12; }
  else if (pair >= 9)  { j1 = 2; base = 9; }
  else if (pair >= 5)  { j1 = 1; base = 5; }
  const int j2 = j1 + 1 + (pair - base);
  float R[16], I[16];
  {
    const uint4* u4 = (const uint4*)Ubuf + (size_t)((b * 5 + j1) * 4 + l1) * 4096 + tid;
    uint4 ub[4];
#pragma unroll
    for (int i = 0; i < 4; ++i) ub[i] = u4[i * 1024];
    const unsigned* ubs = (const unsigned*)ub;
    const float4* p4 = (const float4*)psi + (size_t)(j2 * 4 + l2) * 8192 + tid;
#pragma unroll
    for (int i = 0; i < 8; ++i) {
      const float4 v = p4[i * 1024];
      float ur, ui;
      unpackbf(ubs[2 * i], ur, ui);
      R[2 * i] = ur * v.x - ui * v.y;      I[2 * i] = ur * v.y + ui * v.x;
      unpackbf(ubs[2 * i + 1], ur, ui);
      R[2 * i + 1] = ur * v.z - ui * v.w;  I[2 * i + 1] = ur * v.w + ui * v.z;
    }
  }
  inv_fft2<true>(R, I, sU, g, q, twr, twi);
  float vsum = 0.0f;
#pragma unroll
  for (int m = 0; m < 16; ++m) vsum += fast_sqrtf(R[m] * R[m] + I[m] * I[m]);
  const float tot = block_reduce_sum<16>(vsum, red, tid);
  if (tid == 0) atomicAdd(&s2num[b * 15 + pair], tot);
}

// Fallback (ws tiny): monolithic; correctness only.
__global__ __launch_bounds__(NT) void k_scat_mono(const float2* __restrict__ Xf,
                                                  const float2* __restrict__ psi,
                                                  float* __restrict__ s1num,
                                                  float* __restrict__ s2num,
                                                  const float2* __restrict__ twg) {
  __shared__ unsigned sU[SDIM * PITCH];
  __shared__ float red[16];
  const int tid = threadIdx.x;
  const int g = __builtin_amdgcn_readfirstlane(tid >> 7);
  const int q = tid & 127;
  float twr[16], twi[16];
  load_tw(twg, g, twr, twi);
  const int bid = blockIdx.x;
  float R[16], I[16];
  if (bid < 1280) {
    const int j1 = bid >> 8;
    const int b = (bid & 255) >> 2;
    const int l1 = bid & 3;
    const float4* x4 = (const float4*)Xf + (size_t)b * 8192 + tid;
    const float4* p4 = (const float4*)psi + (size_t)(j1 * 4 + l1) * 8192 + tid;
#pragma unroll
    for (int i = 0; i < 8; ++i) {
      const float4 x = x4[i * 1024], v = p4[i * 1024];
      R[2 * i]     = x.x * v.x - x.y * v.y;  I[2 * i]     = x.x * v.y + x.y * v.x;
      R[2 * i + 1] = x.z * v.z - x.w * v.w;  I[2 * i + 1] = x.z * v.w + x.w * v.z;
    }
    inv_fft2<true>(R, I, sU, g, q, twr, twi);
    float s1sum = 0.0f;
#pragma unroll
    for (int m = 0; m < 16; ++m) {
      const float a = fast_sqrtf(R[m] * R[m] + I[m] * I[m]);
      s1sum += a; R[m] = a; I[m] = 0.0f;
    }
    fwd_fft2(R, I, sU, g, q, twr, twi);
    float Ur[16], Ui[16];
#pragma unroll
    for (int k = 0; k < 16; ++k) { Ur[k] = R[k]; Ui[k] = I[k]; }
    {
      const float tot = block_reduce_sum<16>(s1sum, red, tid);
      if (tid == 0) atomicAdd(&s1num[b * 6 + j1], tot);
    }
    const int pb = (j1 * (11 - j1)) >> 1;
    int plane = (j1 + 1) * 4;
#pragma unroll 1
    for (int j2 = j1 + 1; j2 <= 5; ++j2) {
      float vsum = 0.0f;
#pragma unroll 1
      for (int l2 = 0; l2 < 4; ++l2) {
        const float4* q4 = (const float4*)psi + (size_t)plane * 8192 + tid;
#pragma unroll
        for (int i = 0; i < 8; ++i) {
          const float4 v = q4[i * 1024];
          R[2 * i]     = Ur[2 * i] * v.x - Ui[2 * i] * v.y;
          I[2 * i]     = Ur[2 * i] * v.y + Ui[2 * i] * v.x;
          R[2 * i + 1] = Ur[2 * i + 1] * v.z - Ui[2 * i + 1] * v.w;
          I[2 * i + 1] = Ur[2 * i + 1] * v.w + Ui[2 * i + 1] * v.z;
        }
        inv_fft2<false>(R, I, sU, g, q, twr, twi);
#pragma unroll
        for (int m = 0; m < 16; ++m) vsum += fast_sqrtf(R[m] * R[m] + I[m] * I[m]);
        ++plane;
      }
      const float tot = block_reduce_sum<16>(vsum, red, tid);
      if (tid == 0) atomicAdd(&s2num[b * 15 + pb + (j2 - j1 - 1)], tot);
    }
  } else {
    const int idx = bid - 1280;
    const int b = idx >> 2, l = idx & 3;
    const float4* x4 = (const float4*)Xf + (size_t)b * 8192 + tid;
    const float4* p4 = (const float4*)psi + (size_t)(20 + l) * 8192 + tid;
#pragma unroll
    for (int i = 0; i < 8; ++i) {
      const float4 x = x4[i * 1024], v = p4[i * 1024];
      R[2 * i]     = x.x * v.x - x.y * v.y;  I[2 * i]     = x.x * v.y + x.y * v.x;
      R[2 * i + 1] = x.z * v.z - x.w * v.w;  I[2 * i + 1] = x.z * v.w + x.w * v.z;
    }
    inv_fft2<true>(R, I, sU, g, q, twr, twi);
    float s = 0.0f;
#pragma unroll
    for (int m = 0; m < 16; ++m) s += fast_sqrtf(R[m] * R[m] + I[m] * I[m]);
    const float tot = block_reduce_sum<16>(s, red, tid);
    if (tid == 0) atomicAdd(&s1num[b * 6 + 5], tot);
  }
}

__global__ __launch_bounds__(64) void k_final(const float* __restrict__ s0,
                                              const float* __restrict__ s1num,
                                              const float* __restrict__ s2num,
                                              const float* __restrict__ w1,
                                              const float* __restrict__ b1,
                                              const float* __restrict__ w2,
                                              const float* __restrict__ b2,
                                              const float* __restrict__ w3,
                                              const float* __restrict__ b3,
                                              float* __restrict__ out,
                                              float s2scale) {
  const int b = threadIdx.x;
  if (b >= 64) return;
  float x[22];
  x[0] = s0[b];
#pragma unroll
  for (int j = 0; j < 6; ++j) x[1 + j] = s1num[b * 6 + j] * (1.0f / (4.0f * 16384.0f));
#pragma unroll
  for (int p = 0; p < 15; ++p) x[7 + p] = s2num[b * 15 + p] * s2scale;
  float h1[16];
#pragma unroll
  for (int o = 0; o < 16; ++o) {
    float t = b1[o];
    for (int i = 0; i < 22; ++i) t += x[i] * w1[i * 16 + o];
    h1[o] = fmaxf(t, 0.0f);
  }
  float h2a[16];
#pragma unroll
  for (int o = 0; o < 16; ++o) {
    float t = b2[o];
    for (int i = 0; i < 16; ++i) t += h1[i] * w2[i * 16 + o];
    h2a[o] = fmaxf(t, 0.0f);
  }
  float t = b3[0];
#pragma unroll
  for (int i = 0; i < 16; ++i) t += h2a[i] * w3[i];
  out[b] = 1.0f / (1.0f + expf(-t));
}

extern "C" void kernel_launch(void* const* d_in, const int* in_sizes, int n_in,
                              void* d_out, int out_size, void* d_ws, size_t ws_size,
                              hipStream_t stream) {
  (void)in_sizes; (void)n_in; (void)out_size;
  const float* image  = (const float*)d_in[0];
  const float* mags   = (const float*)d_in[1];
  const float* phases = (const float*)d_in[2];
  const float* w1 = (const float*)d_in[3];
  const float* b1 = (const float*)d_in[4];
  const float* w2 = (const float*)d_in[5];
  const float* b2 = (const float*)d_in[6];
  const float* w3 = (const float*)d_in[7];
  const float* b3 = (const float*)d_in[8];
  float* out = (float*)d_out;

  char* ws = (char*)d_ws;
  float2* psi = (float2*)ws;                       // 3,145,728 B
  float2* Xf  = (float2*)(ws + 3145728);           // 8,388,608 B
  float*  s0  = (float*)(ws + 11534336);           // 64
  float*  s1n = s0 + 64;                           // 384
  float*  s2n = s1n + 384;                         // 960
  float2* twg = (float2*)(s2n + 960);              // 128 float2 (1024 B)
  uint2*  twgh = (uint2*)((char*)twg + 1024);      // 128 uint2 (1024 B)
  unsigned* Ubuf = (unsigned*)(ws + 11542528);     // 83,886,080 B
  uint2*  psih = (uint2*)(ws + 95428608);          // 1,310,720 B (20 planes)
  const size_t need_r5 = 11542528ull + 83886080ull;          // 95,428,608
  const size_t need_h2 = need_r5 + 1310720ull;               // 96,739,328

  hipMemsetAsync(s1n, 0, (384 + 960) * sizeof(float), stream);
  if (ws_size >= need_h2) {
    k_psi<<<dim3(2176), dim3(256), 0, stream>>>(mags, phases, psi, twg, psih, twgh);
    k_img_fft<<<dim3(64), dim3(NT), 0, stream>>>(image, Xf, s0, twg);
    k_scat_a<<<dim3(1536), dim3(NT), 0, stream>>>(Xf, psi, s1n, Ubuf, twg);
    k_scat_b_rp<<<dim3(15360), dim3(512), 0, stream>>>(psih, Ubuf, s2n, twgh);
    k_final<<<dim3(1), dim3(64), 0, stream>>>(s0, s1n, s2n, w1, b1, w2, b2, w3, b3, out,
                                              1.0f / (16.0f * 16384.0f * PSIH_SCALE));
  } else if (ws_size >= need_r5) {
    k_psi<<<dim3(1536), dim3(256), 0, stream>>>(mags, phases, psi, twg, psih, twgh);
    k_img_fft<<<dim3(64), dim3(NT), 0, stream>>>(image, Xf, s0, twg);
    k_scat_a<<<dim3(1536), dim3(NT), 0, stream>>>(Xf, psi, s1n, Ubuf, twg);
    k_scat_b<<<dim3(15360), dim3(NT), 0, stream>>>(psi, Ubuf, s2n, twg);
    k_final<<<dim3(1), dim3(64), 0, stream>>>(s0, s1n, s2n, w1, b1, w2, b2, w3, b3, out,
                                              1.0f / (16.0f * 16384.0f));
  } else {
    k_psi<<<dim3(1536), dim3(256), 0, stream>>>(mags, phases, psi, twg, psih, twgh);
    k_img_fft<<<dim3(64), dim3(NT), 0, stream>>>(image, Xf, s0, twg);
    k_scat_mono<<<dim3(1536), dim3(NT), 0, stream>>>(Xf, psi, s1n, s2n, twg);
    k_final<<<dim3(1), dim3(64), 0, stream>>>(s0, s1n, s2n, w1, b1, w2, b2, w3, b3, out,
                                              1.0f / (16.0f * 16384.0f));
  }
}

// Round 9
// 446.758 us; speedup vs baseline: 1.3282x; 1.0380x over previous
//
#include <hip/hip_runtime.h>
#include <math.h>

// Scattering net: four-step register FFT (r5 structure for f32 kernels).
//
// Round-20: MULTI-IFFT BLOCKS for k_scat_b. r19 (row-pair f16, 2 blocks/CU)
// halved VALU-cycles but was ~60% stalled: per-ifft 24-load prologue (same U
// slice re-fetched by up to 20 sibling blocks -> FETCH 296MB vs 82MB unique)
// + barrier lockstep with nothing in flight. Fix: block = (b,j1,l1) group
// (1280 blocks x 512 thr), U-slice loaded ONCE into 32 h2 regs, loop over
// nit=(5-j1)*4 iffts with psih prefetch issued right after consumption ->
// loads hide under the whole ~10k-cyc ifft. One reduce per j2 (4 iffts).
// Heavy j1=0 blocks dispatch first (bid = j1*256 + ...) for balance.
// FFT core (inv_rp_core) = r19's verified code, unchanged. launch_bounds
// (512,4) caps VGPR at 128 (budget ~115).

#define SDIM 128
#define PLANE 16384
#define PITCH 129
#define NT 1024
#define TWO_PI 6.28318530717958647692f
#define PSIH_SCALE 16.0f

typedef _Float16 h2 __attribute__((ext_vector_type(2)));

constexpr float W16R[8] = {1.f, 0.9238795325f, 0.7071067812f, 0.3826834324f,
                           0.f, -0.3826834324f, -0.7071067812f, -0.9238795325f};
constexpr float W16I[8] = {0.f, -0.3826834324f, -0.7071067812f, -0.9238795325f,
                           -1.f, -0.9238795325f, -0.7071067812f, -0.3826834324f};

__device__ __forceinline__ float fast_sqrtf(float x) { return __builtin_amdgcn_sqrtf(x); }

// ---- packed bf16 complex <-> fp32 pair ----
__device__ __forceinline__ unsigned packbf(float re, float im) {
  const unsigned r = __float_as_uint(re) + 0x8000u;
  const unsigned i = __float_as_uint(im) + 0x8000u;
  return __builtin_amdgcn_perm(r, i, 0x07060302u);
}
__device__ __forceinline__ void unpackbf(unsigned u, float& re, float& im) {
  re = __uint_as_float(u & 0xFFFF0000u);
  im = __uint_as_float(u << 16);
}

// ---- h2 helpers ----
union UHU { unsigned u; h2 h; };
__device__ __forceinline__ h2 u2h(unsigned u) { UHU x; x.u = u; return x.h; }
__device__ __forceinline__ unsigned h2u(h2 h) { UHU x; x.h = h; return x.u; }
__device__ __forceinline__ h2 bch2(float f) { const _Float16 h = (_Float16)f; h2 v = {h, h}; return v; }
__device__ __forceinline__ h2 mkh2(float a, float b) { h2 v = {(_Float16)a, (_Float16)b}; return v; }

// storage-polymorphic LDS access (f32 cores)
__device__ __forceinline__ void stC(float2* s, int idx, float re, float im) { s[idx] = make_float2(re, im); }
__device__ __forceinline__ void ldC(const float2* s, int idx, float& re, float& im) { const float2 v = s[idx]; re = v.x; im = v.y; }
__device__ __forceinline__ void stC(unsigned* s, int idx, float re, float im) { s[idx] = packbf(re, im); }
__device__ __forceinline__ void ldC(const unsigned* s, int idx, float& re, float& im) { unpackbf(s[idx], re, im); }

// wave-uniform twiddle tables -> SGPRs.
__device__ __forceinline__ void load_tw(const float2* __restrict__ twg, int g,
                                        float* twr, float* twi) {
#pragma unroll
  for (int k = 1; k < 16; ++k) {
    const float2 w = twg[16 * g + k];
    twr[k] = __uint_as_float(__builtin_amdgcn_readfirstlane(__float_as_uint(w.x)));
    twi[k] = __uint_as_float(__builtin_amdgcn_readfirstlane(__float_as_uint(w.y)));
  }
}
__device__ __forceinline__ void load_twh(const uint2* __restrict__ twgh, int g,
                                         unsigned* twru, unsigned* twiu) {
#pragma unroll
  for (int k = 1; k < 16; ++k) {
    const uint2 w = twgh[16 * g + k];
    twru[k] = (unsigned)__builtin_amdgcn_readfirstlane((int)w.x);
    twiu[k] = (unsigned)__builtin_amdgcn_readfirstlane((int)w.y);
  }
}

// ---------------- f32 FFT core (r5, known-good) ----------------
template<bool INV>
__device__ __forceinline__ void bfly(float& ar, float& ai, float& br, float& bi, const int idx) {
  float tr, ti;
  if (idx == 0) { tr = br; ti = bi; }
  else if (idx == 4) {
    if (INV) { tr = -bi; ti = br; } else { tr = bi; ti = -br; }
  } else {
    const float wr = W16R[idx];
    const float wi = INV ? -W16I[idx] : W16I[idx];
    tr = br * wr - bi * wi;
    ti = br * wi + bi * wr;
  }
  br = ar - tr; bi = ai - ti;
  ar = ar + tr; ai = ai + ti;
}

#define CSWAP(re, im, a, b) { float _t = re[a]; re[a]=re[b]; re[b]=_t; _t = im[a]; im[a]=im[b]; im[b]=_t; }

template<bool INV>
__device__ __forceinline__ void dft16(float* re, float* im) {
  CSWAP(re, im, 1, 8) CSWAP(re, im, 2, 4) CSWAP(re, im, 3, 12)
  CSWAP(re, im, 5, 10) CSWAP(re, im, 7, 14) CSWAP(re, im, 11, 13)
#pragma unroll
  for (int ls = 1; ls <= 4; ++ls) {
    const int len = 1 << ls, half = len >> 1, tstep = 16 >> ls;
#pragma unroll
    for (int blk = 0; blk < 16; blk += len)
#pragma unroll
      for (int j = 0; j < half; ++j)
        bfly<INV>(re[blk + j], im[blk + j], re[blk + j + half], im[blk + j + half], j * tstep);
  }
}

template<bool INV>
__device__ __forceinline__ void dft8(float* re, float* im) {
  CSWAP(re, im, 1, 4) CSWAP(re, im, 3, 6)
#pragma unroll
  for (int ls = 1; ls <= 3; ++ls) {
    const int len = 1 << ls, half = len >> 1, tstep = 8 >> ls;
#pragma unroll
    for (int blk = 0; blk < 8; blk += len)
#pragma unroll
      for (int j = 0; j < half; ++j)
        bfly<INV>(re[blk + j], im[blk + j], re[blk + j + half], im[blk + j + half], j * tstep * 2);
  }
}

__device__ __forceinline__ void twmul_fwd(float* R, float* I, const float* twr, const float* twi) {
#pragma unroll
  for (int k = 1; k < 16; ++k) {
    const float r = R[k] * twr[k] - I[k] * twi[k];
    I[k] = R[k] * twi[k] + I[k] * twr[k]; R[k] = r;
  }
}
__device__ __forceinline__ void twmul_inv(float* R, float* I, const float* twr, const float* twi) {
#pragma unroll
  for (int k = 1; k < 16; ++k) {
    const float r = R[k] * twr[k] + I[k] * twi[k];
    I[k] = I[k] * twr[k] - R[k] * twi[k]; R[k] = r;
  }
}

template<typename S>
__device__ __forceinline__ void fwd_fft2(float* R, float* I, S* sC,
                                         int g, int q, const float* twr, const float* twi) {
  const int rb = q * PITCH;
  dft16<false>(R, I);
  twmul_fwd(R, I, twr, twi);
  __syncthreads();                             // B0
#pragma unroll
  for (int k = 0; k < 16; ++k) stC(sC, rb + 8 * k + g, R[k], I[k]);
  __syncthreads();                             // B1
#pragma unroll
  for (int t = 0; t < 8; ++t) {
    ldC(sC, rb + 16 * g + t, R[t], I[t]);
    ldC(sC, rb + 16 * g + 8 + t, R[8 + t], I[8 + t]);
  }
  dft8<false>(R, I); dft8<false>(R + 8, I + 8);
#pragma unroll
  for (int k2 = 0; k2 < 8; ++k2) {
    stC(sC, rb + 16 * g + k2, R[k2], I[k2]);
    stC(sC, rb + 16 * g + 8 + k2, R[8 + k2], I[8 + k2]);
  }
  __syncthreads();                             // B2
#pragma unroll
  for (int m = 0; m < 16; ++m) ldC(sC, (g + 8 * m) * PITCH + q, R[m], I[m]);
  dft16<false>(R, I);
  twmul_fwd(R, I, twr, twi);
#pragma unroll
  for (int k = 0; k < 16; ++k) stC(sC, (8 * k + g) * PITCH + q, R[k], I[k]);
  __syncthreads();                             // B3
#pragma unroll
  for (int u = 0; u < 8; ++u) {
    const int bp = (16 * g + 2 * u) * PITCH + q;
    ldC(sC, bp, R[2 * u], I[2 * u]);
    ldC(sC, bp + PITCH, R[2 * u + 1], I[2 * u + 1]);
  }
  dft8<false>(R, I); dft8<false>(R + 8, I + 8);
}

template<bool FIRST, typename S>
__device__ __forceinline__ void inv_fft2(float* R, float* I, S* sC,
                                         int g, int q, const float* twr, const float* twi) {
  const int rb = q * PITCH;
  dft8<true>(R, I); dft8<true>(R + 8, I + 8);
  if constexpr (!FIRST) __syncthreads();       // B0
#pragma unroll
  for (int t = 0; t < 16; ++t) stC(sC, rb + 16 * g + t, R[t], I[t]);
  __syncthreads();                             // B1
#pragma unroll
  for (int k = 0; k < 16; ++k) ldC(sC, rb + 8 * k + g, R[k], I[k]);
  twmul_inv(R, I, twr, twi);
  dft16<true>(R, I);
#pragma unroll
  for (int m = 0; m < 16; ++m) stC(sC, rb + g + 8 * m, R[m], I[m]);
  __syncthreads();                             // B2
#pragma unroll
  for (int u = 0; u < 8; ++u) {
    const int bp = (16 * g + 2 * u) * PITCH + q;
    ldC(sC, bp, R[2 * u], I[2 * u]);
    ldC(sC, bp + PITCH, R[2 * u + 1], I[2 * u + 1]);
  }
  dft8<true>(R, I); dft8<true>(R + 8, I + 8);
#pragma unroll
  for (int u = 0; u < 8; ++u) {
    const int bp = (16 * g + 2 * u) * PITCH + q;
    stC(sC, bp, R[2 * u], I[2 * u]);
    stC(sC, bp + PITCH, R[2 * u + 1], I[2 * u + 1]);
  }
  __syncthreads();                             // B3
#pragma unroll
  for (int k = 0; k < 16; ++k) ldC(sC, (8 * k + g) * PITCH + q, R[k], I[k]);
  twmul_inv(R, I, twr, twi);
  dft16<true>(R, I);
}

// ---------------- h2 FFT core (inverse only) ----------------
__device__ __forceinline__ void bfly_h_inv(h2& ar, h2& ai, h2& br, h2& bi, const int idx) {
  h2 tr, ti;
  if (idx == 0) { tr = br; ti = bi; }
  else if (idx == 4) { tr = -bi; ti = br; }   // w = +i (inverse)
  else {
    const h2 wr = bch2(W16R[idx]);
    const h2 wi = bch2(-W16I[idx]);
    tr = br * wr - bi * wi;
    ti = br * wi + bi * wr;
  }
  br = ar - tr; bi = ai - ti;
  ar = ar + tr; ai = ai + ti;
}

#define HSWAP(re, im, a, b) { h2 _t = re[a]; re[a]=re[b]; re[b]=_t; _t = im[a]; im[a]=im[b]; im[b]=_t; }

__device__ __forceinline__ void dft16h(h2* re, h2* im) {
  HSWAP(re, im, 1, 8) HSWAP(re, im, 2, 4) HSWAP(re, im, 3, 12)
  HSWAP(re, im, 5, 10) HSWAP(re, im, 7, 14) HSWAP(re, im, 11, 13)
#pragma unroll
  for (int ls = 1; ls <= 4; ++ls) {
    const int len = 1 << ls, half = len >> 1, tstep = 16 >> ls;
#pragma unroll
    for (int blk = 0; blk < 16; blk += len)
#pragma unroll
      for (int j = 0; j < half; ++j)
        bfly_h_inv(re[blk + j], im[blk + j], re[blk + j + half], im[blk + j + half], j * tstep);
  }
}

__device__ __forceinline__ void dft8h(h2* re, h2* im) {
  HSWAP(re, im, 1, 4) HSWAP(re, im, 3, 6)
#pragma unroll
  for (int ls = 1; ls <= 3; ++ls) {
    const int len = 1 << ls, half = len >> 1, tstep = 8 >> ls;
#pragma unroll
    for (int blk = 0; blk < 8; blk += len)
#pragma unroll
      for (int j = 0; j < half; ++j)
        bfly_h_inv(re[blk + j], im[blk + j], re[blk + j + half], im[blk + j + half], j * tstep * 2);
  }
}

__device__ __forceinline__ void twmul_inv_h(h2* R, h2* I, const unsigned* twru, const unsigned* twiu) {
#pragma unroll
  for (int k = 1; k < 16; ++k) {
    const h2 wr = u2h(twru[k]), wi = u2h(twiu[k]);
    const h2 r = R[k] * wr + I[k] * wi;
    I[k] = I[k] * wr - R[k] * wi;
    R[k] = r;
  }
}

// Row-pair dual-line inverse fft2 plane core (r19, verified). 4 barriers.
__device__ __forceinline__ void inv_rp_core(h2* R2, h2* I2, uint2* sU,
                                            int g, int q,
                                            const unsigned* twru, const unsigned* twiu) {
  const int sb = q * PITCH;
  // ---- pass 1: column-pair lines ----
  dft8h(R2, I2); dft8h(R2 + 8, I2 + 8);
#pragma unroll
  for (int s = 0; s < 16; ++s) sU[sb + 16 * g + s] = make_uint2(h2u(R2[s]), h2u(I2[s]));
  __syncthreads();                             // B1
#pragma unroll
  for (int k = 0; k < 16; ++k) { const uint2 v = sU[sb + 8 * k + g]; R2[k] = u2h(v.x); I2[k] = u2h(v.y); }
  twmul_inv_h(R2, I2, twru, twiu);
  dft16h(R2, I2);
#pragma unroll
  for (int m = 0; m < 16; ++m) sU[sb + g + 8 * m] = make_uint2(h2u(R2[m]), h2u(I2[m]));  // same cells
  __syncthreads();                             // B2
  // ---- transpose + re-pair: col-pair halves -> row-pair halves ----
  {
    const int s_base = (16 * g) & 63;
    const unsigned sel = (g < 4) ? 0x05040100u : 0x07060302u;
#pragma unroll
    for (int j = 0; j < 16; ++j) {
      const int cb = (s_base + j) * PITCH;
      const uint2 vA = sU[cb + q];
      const uint2 vB = sU[cb + q + 64];
      R2[j] = u2h(__builtin_amdgcn_perm(vB.x, vA.x, sel));
      I2[j] = u2h(__builtin_amdgcn_perm(vB.y, vA.y, sel));
    }
  }
  // ---- pass 2: row-pair lines ----
  dft8h(R2, I2); dft8h(R2 + 8, I2 + 8);
  __syncthreads();                             // B3: transpose reads drained
#pragma unroll
  for (int s = 0; s < 16; ++s) sU[sb + 16 * g + s] = make_uint2(h2u(R2[s]), h2u(I2[s]));
  __syncthreads();                             // B4
#pragma unroll
  for (int k = 0; k < 16; ++k) { const uint2 v = sU[sb + 8 * k + g]; R2[k] = u2h(v.x); I2[k] = u2h(v.y); }
  twmul_inv_h(R2, I2, twru, twiu);
  dft16h(R2, I2);
}

template<int NW>
__device__ __forceinline__ float block_reduce_sum(float v, float* red, int tid) {
#pragma unroll
  for (int o = 32; o > 0; o >>= 1) v += __shfl_down(v, o);
  __syncthreads();
  if ((tid & 63) == 0) red[tid >> 6] = v;
  __syncthreads();
  float t = 0.0f;
  if (tid == 0) {
#pragma unroll
    for (int w = 0; w < NW; ++w) t += red[w];
  }
  return t;
}

// psi f32 granules (r5) + psih row-pair h2 cells for planes 4..23:
// psih[pidx*8192 + j*512 + t512] = uint2{re2, im2}, halves = cols (q, q+64)
// of spectral row 16g+j (sigma-mapped), value = psi * PSIH_SCALE.
__global__ __launch_bounds__(256) void k_psi(const float* __restrict__ mags,
                                             const float* __restrict__ phases,
                                             float2* __restrict__ psi,
                                             float2* __restrict__ twg,
                                             uint2* __restrict__ psih,
                                             uint2* __restrict__ twgh) {
  if (blockIdx.x == 0 && threadIdx.x < 128) {
    const int gg = threadIdx.x >> 4, k = threadIdx.x & 15;
    float sn, cs;
    __sincosf(-TWO_PI * (float)(gg * k) * (1.0f / 128.0f), &sn, &cs);
    twg[threadIdx.x] = make_float2(cs, sn);
    twgh[threadIdx.x] = make_uint2(h2u(bch2(cs)), h2u(bch2(sn)));
  }
  const int gid = blockIdx.x * 256 + threadIdx.x;
  if (gid < 24 * PLANE) {                              // f32 psi (r5 granules)
    const int p = gid >> 14;
    const int rem = gid & (PLANE - 1);
    const int e = rem & 1;
    const int tt = (rem >> 1) & 1023;
    const int i = rem >> 11;
    const int j = 2 * i + e;
    const int g = tt >> 7, q = tt & 127;
    const int pr = 16 * g + j, pc = q;
    const int kr = (pr >> 3) + 16 * (pr & 7);
    const int kc = (pc >> 3) + 16 * (pc & 7);
    const int src = (p << 14) + kr * SDIM + kc;
    const float m = mags[src] * (1.0f / 16384.0f);
    float sn, cs;
    __sincosf(phases[src], &sn, &cs);
    psi[gid] = make_float2(m * cs, m * sn);
  } else if (gid < 24 * PLANE + 20 * 8192) {           // row-pair h2 psih
    const int c = gid - 24 * PLANE;
    const int pidx = c >> 13;
    const int rem = c & 8191;
    const int j = rem >> 9;
    const int t512 = rem & 511;
    const int g = t512 >> 6, q = t512 & 63;
    const int row = 16 * g + j;
    const int plane = pidx + 4;
    const int kr = (row >> 3) + 16 * (row & 7);
    const int kc0 = (q >> 3) + 16 * (q & 7);
    const int q1 = q + 64;
    const int kc1 = (q1 >> 3) + 16 * (q1 & 7);
    const int src0 = (plane << 14) + kr * SDIM + kc0;
    const int src1 = (plane << 14) + kr * SDIM + kc1;
    const float scl = PSIH_SCALE / 16384.0f;
    const float m0 = mags[src0] * scl;
    const float m1 = mags[src1] * scl;
    float sn0, cs0, sn1, cs1;
    __sincosf(phases[src0], &sn0, &cs0);
    __sincosf(phases[src1], &sn1, &cs1);
    psih[c] = make_uint2(h2u(mkh2(m0 * cs0, m1 * cs1)), h2u(mkh2(m0 * sn0, m1 * sn1)));
  }
}

// fp32 LDS; Xf granule layout; ~5 us.
__global__ __launch_bounds__(NT) void k_img_fft(const float* __restrict__ img,
                                                float2* __restrict__ Xf,
                                                float* __restrict__ s0,
                                                const float2* __restrict__ twg) {
  __shared__ float2 sC[SDIM * PITCH];
  __shared__ float red[16];
  const int tid = threadIdx.x, b = blockIdx.x;
  const int g = __builtin_amdgcn_readfirstlane(tid >> 7);
  const int q = tid & 127;
  float twr[16], twi[16];
  load_tw(twg, g, twr, twi);
  const float* ip = img + b * PLANE;
  float sum = 0.0f;
#pragma unroll
  for (int kk = 0; kk < 16; ++kk) {
    const int e = tid + kk * NT;
    const float v = ip[e];
    sC[(e >> 7) * PITCH + (e & 127)] = make_float2(v, 0.0f);
    sum += v;
  }
  const float tot = block_reduce_sum<16>(sum, red, tid);
  if (tid == 0) s0[b] = tot * (1.0f / 16384.0f);
  __syncthreads();
  float R[16], I[16];
#pragma unroll
  for (int m = 0; m < 16; ++m) { R[m] = sC[q * PITCH + g + 8 * m].x; I[m] = 0.0f; }
  fwd_fft2(R, I, sC, g, q, twr, twi);
  float4* x4 = (float4*)Xf + (size_t)b * 8192 + tid;
#pragma unroll
  for (int i = 0; i < 8; ++i)
    x4[i * 1024] = make_float4(R[2 * i], I[2 * i], R[2 * i + 1], I[2 * i + 1]);
}

// Phase A (r5): u1=|ifft2(Xf.psi1)|, U=fft2(u1) -> Ubuf + s1.
__global__ __launch_bounds__(NT) void k_scat_a(const float2* __restrict__ Xf,
                                               const float2* __restrict__ psi,
                                               float* __restrict__ s1num,
                                               unsigned* __restrict__ Ubuf,
                                               const float2* __restrict__ twg) {
  __shared__ unsigned sU[SDIM * PITCH];
  __shared__ float red[16];
  const int tid = threadIdx.x;
  const int g = __builtin_amdgcn_readfirstlane(tid >> 7);
  const int q = tid & 127;
  float twr[16], twi[16];
  load_tw(twg, g, twr, twi);
  const int bid = blockIdx.x;
  float R[16], I[16];

  if (bid < 1280) {
    const int j1 = bid >> 8;
    const int b = (bid & 255) >> 2;
    const int l1 = bid & 3;
    const float4* x4 = (const float4*)Xf + (size_t)b * 8192 + tid;
    const float4* p4 = (const float4*)psi + (size_t)(j1 * 4 + l1) * 8192 + tid;
#pragma unroll
    for (int i = 0; i < 8; ++i) {
      const float4 x = x4[i * 1024], v = p4[i * 1024];
      R[2 * i]     = x.x * v.x - x.y * v.y;  I[2 * i]     = x.x * v.y + x.y * v.x;
      R[2 * i + 1] = x.z * v.z - x.w * v.w;  I[2 * i + 1] = x.z * v.w + x.w * v.z;
    }
    inv_fft2<true>(R, I, sU, g, q, twr, twi);
    float s1sum = 0.0f;
#pragma unroll
    for (int m = 0; m < 16; ++m) {
      const float a = fast_sqrtf(R[m] * R[m] + I[m] * I[m]);
      s1sum += a; R[m] = a; I[m] = 0.0f;
    }
    fwd_fft2(R, I, sU, g, q, twr, twi);
    uint4 ob[4];
    unsigned* obs = (unsigned*)ob;
#pragma unroll
    for (int j = 0; j < 16; ++j) obs[j] = packbf(R[j], I[j]);
    uint4* o4 = (uint4*)Ubuf + (size_t)((b * 5 + j1) * 4 + l1) * 4096 + tid;
#pragma unroll
    for (int i = 0; i < 4; ++i) o4[i * 1024] = ob[i];
    const float tot = block_reduce_sum<16>(s1sum, red, tid);
    if (tid == 0) atomicAdd(&s1num[b * 6 + j1], tot);
  } else {
    const int idx = bid - 1280;
    const int b = idx >> 2, l = idx & 3;
    const float4* x4 = (const float4*)Xf + (size_t)b * 8192 + tid;
    const float4* p4 = (const float4*)psi + (size_t)(20 + l) * 8192 + tid;
#pragma unroll
    for (int i = 0; i < 8; ++i) {
      const float4 x = x4[i * 1024], v = p4[i * 1024];
      R[2 * i]     = x.x * v.x - x.y * v.y;  I[2 * i]     = x.x * v.y + x.y * v.x;
      R[2 * i + 1] = x.z * v.z - x.w * v.w;  I[2 * i + 1] = x.z * v.w + x.w * v.z;
    }
    inv_fft2<true>(R, I, sU, g, q, twr, twi);
    float s = 0.0f;
#pragma unroll
    for (int m = 0; m < 16; ++m) s += fast_sqrtf(R[m] * R[m] + I[m] * I[m]);
    const float tot = block_reduce_sum<16>(s, red, tid);
    if (tid == 0) atomicAdd(&s1num[b * 6 + 5], tot);
  }
}

// Phase B multi-ifft row-pair h2: 1280 blocks x 512 threads, 2 blocks/CU.
// Block (b,j1,l1): U-slice in regs (32 h2), loop nit=(5-j1)*4 iffts over
// pidx = 4*j1 + it (it = (j2-j1-1)*4 + l2), psih prefetched one ifft ahead.
// Reduce+atomic once per j2 group. Heavy j1=0 blocks first.
__global__ __launch_bounds__(512, 4) void k_scat_b_rpm(const uint2* __restrict__ psih,
                                                       const unsigned* __restrict__ Ubuf,
                                                       float* __restrict__ s2num,
                                                       const uint2* __restrict__ twgh) {
  __shared__ uint2 sU[64 * PITCH];             // 66,048 B
  __shared__ float red[8];
  const int tid = threadIdx.x;
  const int g = __builtin_amdgcn_readfirstlane(tid >> 6);
  const int q = tid & 63;
  unsigned twru[16], twiu[16];
  load_twh(twgh, g, twru, twiu);
  const int bid = blockIdx.x;
  const int j1 = bid >> 8;                     // j1 ascending -> heavy first
  const int b = (bid & 255) >> 2;
  const int l1 = bid & 3;
  const int pb = (j1 * (11 - j1)) >> 1;
  const int nit = (5 - j1) * 4;

  // U-slice once: two r5-granule virtual tids (cols q, q+64), -> h2 pairs.
  h2 UR2[16], UI2[16];
  {
    const uint4* u4 = (const uint4*)Ubuf + (size_t)((b * 5 + j1) * 4 + l1) * 4096;
    const int t0 = g * 128 + q;
    uint4 ua[4], ub[4];
#pragma unroll
    for (int i = 0; i < 4; ++i) { ua[i] = u4[i * 1024 + t0]; ub[i] = u4[i * 1024 + t0 + 64]; }
    const unsigned* uas = (const unsigned*)ua;
    const unsigned* ubs = (const unsigned*)ub;
#pragma unroll
    for (int j = 0; j < 16; ++j) {
      float urL, uiL, urH, uiH;
      unpackbf(uas[j], urL, uiL);
      unpackbf(ubs[j], urH, uiH);
      UR2[j] = mkh2(urL, urH);
      UI2[j] = mkh2(uiL, uiH);
    }
  }

  // prefetch psih plane for it=0 (pidx = 4*j1)
  uint2 buf[16];
  {
    const uint2* ph = psih + (size_t)(4 * j1) * 8192 + tid;
#pragma unroll
    for (int j = 0; j < 16; ++j) buf[j] = ph[j * 512];
  }

  float vsum = 0.0f;
  for (int it = 0; it < nit; ++it) {
    h2 R2[16], I2[16];
#pragma unroll
    for (int j = 0; j < 16; ++j) {
      const h2 pr = u2h(buf[j].x), pi = u2h(buf[j].y);
      R2[j] = UR2[j] * pr - UI2[j] * pi;
      I2[j] = UR2[j] * pi + UI2[j] * pr;
    }
    if (it + 1 < nit) {                        // prefetch next plane; hides
      const uint2* phn = psih + (size_t)(4 * j1 + it + 1) * 8192 + tid;
#pragma unroll
      for (int j = 0; j < 16; ++j) buf[j] = phn[j * 512];
    }
    if (it) __syncthreads();                   // B0: prev B4-reads drained
    inv_rp_core(R2, I2, sU, g, q, twru, twiu);
#pragma unroll
    for (int m = 0; m < 16; ++m) {
      const float rl = (float)R2[m].x, il = (float)I2[m].x;
      const float rh = (float)R2[m].y, ih = (float)I2[m].y;
      vsum += fast_sqrtf(rl * rl + il * il) + fast_sqrtf(rh * rh + ih * ih);
    }
    if ((it & 3) == 3) {                       // one reduce per j2 group
      const float tot = block_reduce_sum<8>(vsum, red, tid);
      if (tid == 0) atomicAdd(&s2num[b * 15 + pb + (it >> 2)], tot);
      vsum = 0.0f;
    }
  }
}

// Phase B f32 fallback (r5, tier-2).
__global__ __launch_bounds__(NT) void k_scat_b(const float2* __restrict__ psi,
                                               const unsigned* __restrict__ Ubuf,
                                               float* __restrict__ s2num,
                                               const float2* __restrict__ twg) {
  __shared__ unsigned sU[SDIM * PITCH];
  __shared__ float red[16];
  const int tid = threadIdx.x;
  const int g = __builtin_amdgcn_readfirstlane(tid >> 7);
  const int q = tid & 127;
  float twr[16], twi[16];
  load_tw(twg, g, twr, twi);
  int t = blockIdx.x;
  const int l2 = t & 3; t >>= 2;
  const int pair = t % 15; t /= 15;
  const int l1 = t & 3;
  const int b = t >> 2;
  int j1 = 0, base = 0;
  if (pair >= 14)      { j1 = 4; base = 14; }
  else if (pair >= 12) { j1 = 3; base = 12; }
  else if (pair >= 9)  { j1 = 2; base = 9; }
  else if (pair >= 5)  { j1 = 1; base = 5; }
  const int j2 = j1 + 1 + (pair - base);
  float R[16], I[16];
  {
    const uint4* u4 = (const uint4*)Ubuf + (size_t)((b * 5 + j1) * 4 + l1) * 4096 + tid;
    uint4 ub[4];
#pragma unroll
    for (int i = 0; i < 4; ++i) ub[i] = u4[i * 1024];
    const unsigned* ubs = (const unsigned*)ub;
    const float4* p4 = (const float4*)psi + (size_t)(j2 * 4 + l2) * 8192 + tid;
#pragma unroll
    for (int i = 0; i < 8; ++i) {
      const float4 v = p4[i * 1024];
      float ur, ui;
      unpackbf(ubs[2 * i], ur, ui);
      R[2 * i] = ur * v.x - ui * v.y;      I[2 * i] = ur * v.y + ui * v.x;
      unpackbf(ubs[2 * i + 1], ur, ui);
      R[2 * i + 1] = ur * v.z - ui * v.w;  I[2 * i + 1] = ur * v.w + ui * v.z;
    }
  }
  inv_fft2<true>(R, I, sU, g, q, twr, twi);
  float vsum = 0.0f;
#pragma unroll
  for (int m = 0; m < 16; ++m) vsum += fast_sqrtf(R[m] * R[m] + I[m] * I[m]);
  const float tot = block_reduce_sum<16>(vsum, red, tid);
  if (tid == 0) atomicAdd(&s2num[b * 15 + pair], tot);
}

// Fallback (ws tiny): monolithic; correctness only.
__global__ __launch_bounds__(NT) void k_scat_mono(const float2* __restrict__ Xf,
                                                  const float2* __restrict__ psi,
                                                  float* __restrict__ s1num,
                                                  float* __restrict__ s2num,
                                                  const float2* __restrict__ twg) {
  __shared__ unsigned sU[SDIM * PITCH];
  __shared__ float red[16];
  const int tid = threadIdx.x;
  const int g = __builtin_amdgcn_readfirstlane(tid >> 7);
  const int q = tid & 127;
  float twr[16], twi[16];
  load_tw(twg, g, twr, twi);
  const int bid = blockIdx.x;
  float R[16], I[16];
  if (bid < 1280) {
    const int j1 = bid >> 8;
    const int b = (bid & 255) >> 2;
    const int l1 = bid & 3;
    const float4* x4 = (const float4*)Xf + (size_t)b * 8192 + tid;
    const float4* p4 = (const float4*)psi + (size_t)(j1 * 4 + l1) * 8192 + tid;
#pragma unroll
    for (int i = 0; i < 8; ++i) {
      const float4 x = x4[i * 1024], v = p4[i * 1024];
      R[2 * i]     = x.x * v.x - x.y * v.y;  I[2 * i]     = x.x * v.y + x.y * v.x;
      R[2 * i + 1] = x.z * v.z - x.w * v.w;  I[2 * i + 1] = x.z * v.w + x.w * v.z;
    }
    inv_fft2<true>(R, I, sU, g, q, twr, twi);
    float s1sum = 0.0f;
#pragma unroll
    for (int m = 0; m < 16; ++m) {
      const float a = fast_sqrtf(R[m] * R[m] + I[m] * I[m]);
      s1sum += a; R[m] = a; I[m] = 0.0f;
    }
    fwd_fft2(R, I, sU, g, q, twr, twi);
    float Ur[16], Ui[16];
#pragma unroll
    for (int k = 0; k < 16; ++k) { Ur[k] = R[k]; Ui[k] = I[k]; }
    {
      const float tot = block_reduce_sum<16>(s1sum, red, tid);
      if (tid == 0) atomicAdd(&s1num[b * 6 + j1], tot);
    }
    const int pb = (j1 * (11 - j1)) >> 1;
    int plane = (j1 + 1) * 4;
#pragma unroll 1
    for (int j2 = j1 + 1; j2 <= 5; ++j2) {
      float vsum = 0.0f;
#pragma unroll 1
      for (int l2 = 0; l2 < 4; ++l2) {
        const float4* q4 = (const float4*)psi + (size_t)plane * 8192 + tid;
#pragma unroll
        for (int i = 0; i < 8; ++i) {
          const float4 v = q4[i * 1024];
          R[2 * i]     = Ur[2 * i] * v.x - Ui[2 * i] * v.y;
          I[2 * i]     = Ur[2 * i] * v.y + Ui[2 * i] * v.x;
          R[2 * i + 1] = Ur[2 * i + 1] * v.z - Ui[2 * i + 1] * v.w;
          I[2 * i + 1] = Ur[2 * i + 1] * v.w + Ui[2 * i + 1] * v.z;
        }
        inv_fft2<false>(R, I, sU, g, q, twr, twi);
#pragma unroll
        for (int m = 0; m < 16; ++m) vsum += fast_sqrtf(R[m] * R[m] + I[m] * I[m]);
        ++plane;
      }
      const float tot = block_reduce_sum<16>(vsum, red, tid);
      if (tid == 0) atomicAdd(&s2num[b * 15 + pb + (j2 - j1 - 1)], tot);
    }
  } else {
    const int idx = bid - 1280;
    const int b = idx >> 2, l = idx & 3;
    const float4* x4 = (const float4*)Xf + (size_t)b * 8192 + tid;
    const float4* p4 = (const float4*)psi + (size_t)(20 + l) * 8192 + tid;
#pragma unroll
    for (int i = 0; i < 8; ++i) {
      const float4 x = x4[i * 1024], v = p4[i * 1024];
      R[2 * i]     = x.x * v.x - x.y * v.y;  I[2 * i]     = x.x * v.y + x.y * v.x;
      R[2 * i + 1] = x.z * v.z - x.w * v.w;  I[2 * i + 1] = x.z * v.w + x.w * v.z;
    }
    inv_fft2<true>(R, I, sU, g, q, twr, twi);
    float s = 0.0f;
#pragma unroll
    for (int m = 0; m < 16; ++m) s += fast_sqrtf(R[m] * R[m] + I[m] * I[m]);
    const float tot = block_reduce_sum<16>(s, red, tid);
    if (tid == 0) atomicAdd(&s1num[b * 6 + 5], tot);
  }
}

__global__ __launch_bounds__(64) void k_final(const float* __restrict__ s0,
                                              const float* __restrict__ s1num,
                                              const float* __restrict__ s2num,
                                              const float* __restrict__ w1,
                                              const float* __restrict__ b1,
                                              const float* __restrict__ w2,
                                              const float* __restrict__ b2,
                                              const float* __restrict__ w3,
                                              const float* __restrict__ b3,
                                              float* __restrict__ out,
                                              float s2scale) {
  const int b = threadIdx.x;
  if (b >= 64) return;
  float x[22];
  x[0] = s0[b];
#pragma unroll
  for (int j = 0; j < 6; ++j) x[1 + j] = s1num[b * 6 + j] * (1.0f / (4.0f * 16384.0f));
#pragma unroll
  for (int p = 0; p < 15; ++p) x[7 + p] = s2num[b * 15 + p] * s2scale;
  float h1[16];
#pragma unroll
  for (int o = 0; o < 16; ++o) {
    float t = b1[o];
    for (int i = 0; i < 22; ++i) t += x[i] * w1[i * 16 + o];
    h1[o] = fmaxf(t, 0.0f);
  }
  float h2a[16];
#pragma unroll
  for (int o = 0; o < 16; ++o) {
    float t = b2[o];
    for (int i = 0; i < 16; ++i) t += h1[i] * w2[i * 16 + o];
    h2a[o] = fmaxf(t, 0.0f);
  }
  float t = b3[0];
#pragma unroll
  for (int i = 0; i < 16; ++i) t += h2a[i] * w3[i];
  out[b] = 1.0f / (1.0f + expf(-t));
}

extern "C" void kernel_launch(void* const* d_in, const int* in_sizes, int n_in,
                              void* d_out, int out_size, void* d_ws, size_t ws_size,
                              hipStream_t stream) {
  (void)in_sizes; (void)n_in; (void)out_size;
  const float* image  = (const float*)d_in[0];
  const float* mags   = (const float*)d_in[1];
  const float* phases = (const float*)d_in[2];
  const float* w1 = (const float*)d_in[3];
  const float* b1 = (const float*)d_in[4];
  const float* w2 = (const float*)d_in[5];
  const float* b2 = (const float*)d_in[6];
  const float* w3 = (const float*)d_in[7];
  const float* b3 = (const float*)d_in[8];
  float* out = (float*)d_out;

  char* ws = (char*)d_ws;
  float2* psi = (float2*)ws;                       // 3,145,728 B
  float2* Xf  = (float2*)(ws + 3145728);           // 8,388,608 B
  float*  s0  = (float*)(ws + 11534336);           // 64
  float*  s1n = s0 + 64;                           // 384
  float*  s2n = s1n + 384;                         // 960
  float2* twg = (float2*)(s2n + 960);              // 128 float2 (1024 B)
  uint2*  twgh = (uint2*)((char*)twg + 1024);      // 128 uint2 (1024 B)
  unsigned* Ubuf = (unsigned*)(ws + 11542528);     // 83,886,080 B
  uint2*  psih = (uint2*)(ws + 95428608);          // 1,310,720 B (20 planes)
  const size_t need_r5 = 11542528ull + 83886080ull;          // 95,428,608
  const size_t need_h2 = need_r5 + 1310720ull;               // 96,739,328

  hipMemsetAsync(s1n, 0, (384 + 960) * sizeof(float), stream);
  if (ws_size >= need_h2) {
    k_psi<<<dim3(2176), dim3(256), 0, stream>>>(mags, phases, psi, twg, psih, twgh);
    k_img_fft<<<dim3(64), dim3(NT), 0, stream>>>(image, Xf, s0, twg);
    k_scat_a<<<dim3(1536), dim3(NT), 0, stream>>>(Xf, psi, s1n, Ubuf, twg);
    k_scat_b_rpm<<<dim3(1280), dim3(512), 0, stream>>>(psih, Ubuf, s2n, twgh);
    k_final<<<dim3(1), dim3(64), 0, stream>>>(s0, s1n, s2n, w1, b1, w2, b2, w3, b3, out,
                                              1.0f / (16.0f * 16384.0f * PSIH_SCALE));
  } else if (ws_size >= need_r5) {
    k_psi<<<dim3(1536), dim3(256), 0, stream>>>(mags, phases, psi, twg, psih, twgh);
    k_img_fft<<<dim3(64), dim3(NT), 0, stream>>>(image, Xf, s0, twg);
    k_scat_a<<<dim3(1536), dim3(NT), 0, stream>>>(Xf, psi, s1n, Ubuf, twg);
    k_scat_b<<<dim3(15360), dim3(NT), 0, stream>>>(psi, Ubuf, s2n, twg);
    k_final<<<dim3(1), dim3(64), 0, stream>>>(s0, s1n, s2n, w1, b1, w2, b2, w3, b3, out,
                                              1.0f / (16.0f * 16384.0f));
  } else {
    k_psi<<<dim3(1536), dim3(256), 0, stream>>>(mags, phases, psi, twg, psih, twgh);
    k_img_fft<<<dim3(64), dim3(NT), 0, stream>>>(image, Xf, s0, twg);
    k_scat_mono<<<dim3(1536), dim3(NT), 0, stream>>>(Xf, psi, s1n, s2n, twg);
    k_final<<<dim3(1), dim3(64), 0, stream>>>(s0, s1n, s2n, w1, b1, w2, b2, w3, b3, out,
                                              1.0f / (16.0f * 16384.0f));
  }
}

// Round 10
// 440.712 us; speedup vs baseline: 1.3464x; 1.0137x over previous
//
#include <hip/hip_runtime.h>
#include <math.h>

// Scattering net: four-step register FFT.
//
// Round-21: ROW-PAIR f16 k_scat_a. r20 killed k_scat_b's HBM traffic (296->46
// MB) but time barely moved -> it is barrier/LDS-latency bound, not memory
// bound. Next biggest item: k_scat_a (~70us, still f32 r5-structure). Port it
// to the verified row-pair f16 machinery: 512 thr, 66KB (2 blocks/CU),
// inv_rp_core (r19/r20 verified) + new fwd_rp_core (mirror; the transpose is
// self-symmetric: same strip reads + perm selectors serve both directions).
// X.psi cmul in f32 (x16 scale for f16 range; s1 /16 in k_final; u1 /16 into
// fwd so U is unscaled). U stored as f16 pairs (MORE mantissa than old bf16),
// k_scat_b_rpm loader becomes 8x dwordx4 + 2 perms/slot. f32 tier-2 kept.

#define SDIM 128
#define PLANE 16384
#define PITCH 129
#define NT 1024
#define TWO_PI 6.28318530717958647692f
#define PSIH_SCALE 16.0f
#define A_SCALE 16.0f

typedef _Float16 h2 __attribute__((ext_vector_type(2)));

constexpr float W16R[8] = {1.f, 0.9238795325f, 0.7071067812f, 0.3826834324f,
                           0.f, -0.3826834324f, -0.7071067812f, -0.9238795325f};
constexpr float W16I[8] = {0.f, -0.3826834324f, -0.7071067812f, -0.9238795325f,
                           -1.f, -0.9238795325f, -0.7071067812f, -0.3826834324f};

__device__ __forceinline__ float fast_sqrtf(float x) { return __builtin_amdgcn_sqrtf(x); }

// ---- packed bf16 complex <-> fp32 pair (tier-2 f32 path) ----
__device__ __forceinline__ unsigned packbf(float re, float im) {
  const unsigned r = __float_as_uint(re) + 0x8000u;
  const unsigned i = __float_as_uint(im) + 0x8000u;
  return __builtin_amdgcn_perm(r, i, 0x07060302u);
}
__device__ __forceinline__ void unpackbf(unsigned u, float& re, float& im) {
  re = __uint_as_float(u & 0xFFFF0000u);
  im = __uint_as_float(u << 16);
}

// ---- h2 helpers ----
union UHU { unsigned u; h2 h; };
__device__ __forceinline__ h2 u2h(unsigned u) { UHU x; x.u = u; return x.h; }
__device__ __forceinline__ unsigned h2u(h2 h) { UHU x; x.h = h; return x.u; }
__device__ __forceinline__ h2 bch2(float f) { const _Float16 h = (_Float16)f; h2 v = {h, h}; return v; }
__device__ __forceinline__ h2 mkh2(float a, float b) { h2 v = {(_Float16)a, (_Float16)b}; return v; }

#define SEL_LO 0x05040100u
#define SEL_HI 0x07060302u

// storage-polymorphic LDS access (f32 cores)
__device__ __forceinline__ void stC(float2* s, int idx, float re, float im) { s[idx] = make_float2(re, im); }
__device__ __forceinline__ void ldC(const float2* s, int idx, float& re, float& im) { const float2 v = s[idx]; re = v.x; im = v.y; }
__device__ __forceinline__ void stC(unsigned* s, int idx, float re, float im) { s[idx] = packbf(re, im); }
__device__ __forceinline__ void ldC(const unsigned* s, int idx, float& re, float& im) { unpackbf(s[idx], re, im); }

// wave-uniform twiddle tables -> SGPRs.
__device__ __forceinline__ void load_tw(const float2* __restrict__ twg, int g,
                                        float* twr, float* twi) {
#pragma unroll
  for (int k = 1; k < 16; ++k) {
    const float2 w = twg[16 * g + k];
    twr[k] = __uint_as_float(__builtin_amdgcn_readfirstlane(__float_as_uint(w.x)));
    twi[k] = __uint_as_float(__builtin_amdgcn_readfirstlane(__float_as_uint(w.y)));
  }
}
__device__ __forceinline__ void load_twh(const uint2* __restrict__ twgh, int g,
                                         unsigned* twru, unsigned* twiu) {
#pragma unroll
  for (int k = 1; k < 16; ++k) {
    const uint2 w = twgh[16 * g + k];
    twru[k] = (unsigned)__builtin_amdgcn_readfirstlane((int)w.x);
    twiu[k] = (unsigned)__builtin_amdgcn_readfirstlane((int)w.y);
  }
}

// ---------------- f32 FFT core (r5, known-good; tier-2) ----------------
template<bool INV>
__device__ __forceinline__ void bfly(float& ar, float& ai, float& br, float& bi, const int idx) {
  float tr, ti;
  if (idx == 0) { tr = br; ti = bi; }
  else if (idx == 4) {
    if (INV) { tr = -bi; ti = br; } else { tr = bi; ti = -br; }
  } else {
    const float wr = W16R[idx];
    const float wi = INV ? -W16I[idx] : W16I[idx];
    tr = br * wr - bi * wi;
    ti = br * wi + bi * wr;
  }
  br = ar - tr; bi = ai - ti;
  ar = ar + tr; ai = ai + ti;
}

#define CSWAP(re, im, a, b) { float _t = re[a]; re[a]=re[b]; re[b]=_t; _t = im[a]; im[a]=im[b]; im[b]=_t; }

template<bool INV>
__device__ __forceinline__ void dft16(float* re, float* im) {
  CSWAP(re, im, 1, 8) CSWAP(re, im, 2, 4) CSWAP(re, im, 3, 12)
  CSWAP(re, im, 5, 10) CSWAP(re, im, 7, 14) CSWAP(re, im, 11, 13)
#pragma unroll
  for (int ls = 1; ls <= 4; ++ls) {
    const int len = 1 << ls, half = len >> 1, tstep = 16 >> ls;
#pragma unroll
    for (int blk = 0; blk < 16; blk += len)
#pragma unroll
      for (int j = 0; j < half; ++j)
        bfly<INV>(re[blk + j], im[blk + j], re[blk + j + half], im[blk + j + half], j * tstep);
  }
}

template<bool INV>
__device__ __forceinline__ void dft8(float* re, float* im) {
  CSWAP(re, im, 1, 4) CSWAP(re, im, 3, 6)
#pragma unroll
  for (int ls = 1; ls <= 3; ++ls) {
    const int len = 1 << ls, half = len >> 1, tstep = 8 >> ls;
#pragma unroll
    for (int blk = 0; blk < 8; blk += len)
#pragma unroll
      for (int j = 0; j < half; ++j)
        bfly<INV>(re[blk + j], im[blk + j], re[blk + j + half], im[blk + j + half], j * tstep * 2);
  }
}

__device__ __forceinline__ void twmul_fwd(float* R, float* I, const float* twr, const float* twi) {
#pragma unroll
  for (int k = 1; k < 16; ++k) {
    const float r = R[k] * twr[k] - I[k] * twi[k];
    I[k] = R[k] * twi[k] + I[k] * twr[k]; R[k] = r;
  }
}
__device__ __forceinline__ void twmul_inv(float* R, float* I, const float* twr, const float* twi) {
#pragma unroll
  for (int k = 1; k < 16; ++k) {
    const float r = R[k] * twr[k] + I[k] * twi[k];
    I[k] = I[k] * twr[k] - R[k] * twi[k]; R[k] = r;
  }
}

template<typename S>
__device__ __forceinline__ void fwd_fft2(float* R, float* I, S* sC,
                                         int g, int q, const float* twr, const float* twi) {
  const int rb = q * PITCH;
  dft16<false>(R, I);
  twmul_fwd(R, I, twr, twi);
  __syncthreads();                             // B0
#pragma unroll
  for (int k = 0; k < 16; ++k) stC(sC, rb + 8 * k + g, R[k], I[k]);
  __syncthreads();                             // B1
#pragma unroll
  for (int t = 0; t < 8; ++t) {
    ldC(sC, rb + 16 * g + t, R[t], I[t]);
    ldC(sC, rb + 16 * g + 8 + t, R[8 + t], I[8 + t]);
  }
  dft8<false>(R, I); dft8<false>(R + 8, I + 8);
#pragma unroll
  for (int k2 = 0; k2 < 8; ++k2) {
    stC(sC, rb + 16 * g + k2, R[k2], I[k2]);
    stC(sC, rb + 16 * g + 8 + k2, R[8 + k2], I[8 + k2]);
  }
  __syncthreads();                             // B2
#pragma unroll
  for (int m = 0; m < 16; ++m) ldC(sC, (g + 8 * m) * PITCH + q, R[m], I[m]);
  dft16<false>(R, I);
  twmul_fwd(R, I, twr, twi);
#pragma unroll
  for (int k = 0; k < 16; ++k) stC(sC, (8 * k + g) * PITCH + q, R[k], I[k]);
  __syncthreads();                             // B3
#pragma unroll
  for (int u = 0; u < 8; ++u) {
    const int bp = (16 * g + 2 * u) * PITCH + q;
    ldC(sC, bp, R[2 * u], I[2 * u]);
    ldC(sC, bp + PITCH, R[2 * u + 1], I[2 * u + 1]);
  }
  dft8<false>(R, I); dft8<false>(R + 8, I + 8);
}

template<bool FIRST, typename S>
__device__ __forceinline__ void inv_fft2(float* R, float* I, S* sC,
                                         int g, int q, const float* twr, const float* twi) {
  const int rb = q * PITCH;
  dft8<true>(R, I); dft8<true>(R + 8, I + 8);
  if constexpr (!FIRST) __syncthreads();       // B0
#pragma unroll
  for (int t = 0; t < 16; ++t) stC(sC, rb + 16 * g + t, R[t], I[t]);
  __syncthreads();                             // B1
#pragma unroll
  for (int k = 0; k < 16; ++k) ldC(sC, rb + 8 * k + g, R[k], I[k]);
  twmul_inv(R, I, twr, twi);
  dft16<true>(R, I);
#pragma unroll
  for (int m = 0; m < 16; ++m) stC(sC, rb + g + 8 * m, R[m], I[m]);
  __syncthreads();                             // B2
#pragma unroll
  for (int u = 0; u < 8; ++u) {
    const int bp = (16 * g + 2 * u) * PITCH + q;
    ldC(sC, bp, R[2 * u], I[2 * u]);
    ldC(sC, bp + PITCH, R[2 * u + 1], I[2 * u + 1]);
  }
  dft8<true>(R, I); dft8<true>(R + 8, I + 8);
#pragma unroll
  for (int u = 0; u < 8; ++u) {
    const int bp = (16 * g + 2 * u) * PITCH + q;
    stC(sC, bp, R[2 * u], I[2 * u]);
    stC(sC, bp + PITCH, R[2 * u + 1], I[2 * u + 1]);
  }
  __syncthreads();                             // B3
#pragma unroll
  for (int k = 0; k < 16; ++k) ldC(sC, (8 * k + g) * PITCH + q, R[k], I[k]);
  twmul_inv(R, I, twr, twi);
  dft16<true>(R, I);
}

// ---------------- h2 FFT core ----------------
template<bool INV>
__device__ __forceinline__ void bfly_h(h2& ar, h2& ai, h2& br, h2& bi, const int idx) {
  h2 tr, ti;
  if (idx == 0) { tr = br; ti = bi; }
  else if (idx == 4) {
    if (INV) { tr = -bi; ti = br; } else { tr = bi; ti = -br; }
  } else {
    const h2 wr = bch2(W16R[idx]);
    const h2 wi = bch2(INV ? -W16I[idx] : W16I[idx]);
    tr = br * wr - bi * wi;
    ti = br * wi + bi * wr;
  }
  br = ar - tr; bi = ai - ti;
  ar = ar + tr; ai = ai + ti;
}

#define HSWAP(re, im, a, b) { h2 _t = re[a]; re[a]=re[b]; re[b]=_t; _t = im[a]; im[a]=im[b]; im[b]=_t; }

template<bool INV>
__device__ __forceinline__ void dft16h(h2* re, h2* im) {
  HSWAP(re, im, 1, 8) HSWAP(re, im, 2, 4) HSWAP(re, im, 3, 12)
  HSWAP(re, im, 5, 10) HSWAP(re, im, 7, 14) HSWAP(re, im, 11, 13)
#pragma unroll
  for (int ls = 1; ls <= 4; ++ls) {
    const int len = 1 << ls, half = len >> 1, tstep = 16 >> ls;
#pragma unroll
    for (int blk = 0; blk < 16; blk += len)
#pragma unroll
      for (int j = 0; j < half; ++j)
        bfly_h<INV>(re[blk + j], im[blk + j], re[blk + j + half], im[blk + j + half], j * tstep);
  }
}

template<bool INV>
__device__ __forceinline__ void dft8h(h2* re, h2* im) {
  HSWAP(re, im, 1, 4) HSWAP(re, im, 3, 6)
#pragma unroll
  for (int ls = 1; ls <= 3; ++ls) {
    const int len = 1 << ls, half = len >> 1, tstep = 8 >> ls;
#pragma unroll
    for (int blk = 0; blk < 8; blk += len)
#pragma unroll
      for (int j = 0; j < half; ++j)
        bfly_h<INV>(re[blk + j], im[blk + j], re[blk + j + half], im[blk + j + half], j * tstep * 2);
  }
}

__device__ __forceinline__ void twmul_inv_h(h2* R, h2* I, const unsigned* twru, const unsigned* twiu) {
#pragma unroll
  for (int k = 1; k < 16; ++k) {
    const h2 wr = u2h(twru[k]), wi = u2h(twiu[k]);
    const h2 r = R[k] * wr + I[k] * wi;
    I[k] = I[k] * wr - R[k] * wi;
    R[k] = r;
  }
}
__device__ __forceinline__ void twmul_fwd_h(h2* R, h2* I, const unsigned* twru, const unsigned* twiu) {
#pragma unroll
  for (int k = 1; k < 16; ++k) {
    const h2 wr = u2h(twru[k]), wi = u2h(twiu[k]);
    const h2 r = R[k] * wr - I[k] * wi;
    I[k] = R[k] * wi + I[k] * wr;
    R[k] = r;
  }
}

// Row-pair dual-line inverse fft2 (r19/r20 verified). 4 barriers.
// In: slot j <-> spectral row-pos 16g+j, halves = col-pos (q, q+64).
// Out: slot m <-> spatial (rows q|q+64 halves, col g+8m).
__device__ __forceinline__ void inv_rp_core(h2* R2, h2* I2, uint2* sU,
                                            int g, int q,
                                            const unsigned* twru, const unsigned* twiu) {
  const int sb = q * PITCH;
  dft8h<true>(R2, I2); dft8h<true>(R2 + 8, I2 + 8);
#pragma unroll
  for (int s = 0; s < 16; ++s) sU[sb + 16 * g + s] = make_uint2(h2u(R2[s]), h2u(I2[s]));
  __syncthreads();                             // B1
#pragma unroll
  for (int k = 0; k < 16; ++k) { const uint2 v = sU[sb + 8 * k + g]; R2[k] = u2h(v.x); I2[k] = u2h(v.y); }
  twmul_inv_h(R2, I2, twru, twiu);
  dft16h<true>(R2, I2);
#pragma unroll
  for (int m = 0; m < 16; ++m) sU[sb + g + 8 * m] = make_uint2(h2u(R2[m]), h2u(I2[m]));  // same cells
  __syncthreads();                             // B2
  {
    const int s_base = (16 * g) & 63;
    const unsigned sel = (g < 4) ? SEL_LO : SEL_HI;
#pragma unroll
    for (int j = 0; j < 16; ++j) {
      const int cb = (s_base + j) * PITCH;
      const uint2 vA = sU[cb + q];
      const uint2 vB = sU[cb + q + 64];
      R2[j] = u2h(__builtin_amdgcn_perm(vB.x, vA.x, sel));
      I2[j] = u2h(__builtin_amdgcn_perm(vB.y, vA.y, sel));
    }
  }
  dft8h<true>(R2, I2); dft8h<true>(R2 + 8, I2 + 8);
  __syncthreads();                             // B3
#pragma unroll
  for (int s = 0; s < 16; ++s) sU[sb + 16 * g + s] = make_uint2(h2u(R2[s]), h2u(I2[s]));
  __syncthreads();                             // B4
#pragma unroll
  for (int k = 0; k < 16; ++k) { const uint2 v = sU[sb + 8 * k + g]; R2[k] = u2h(v.x); I2[k] = u2h(v.y); }
  twmul_inv_h(R2, I2, twru, twiu);
  dft16h<true>(R2, I2);
}

// Row-pair dual-line FORWARD fft2 (mirror). 4 barriers.
// In: slot m <-> spatial (rows q|q+64 halves, col g+8m).
// Out: slot j <-> spectral row-pos 16g+j, halves = col-pos (q, q+64).
// Entry: safe to write own strip cells {8k+g} without a barrier IF the
// previous LDS phase was inv_rp_core's final own-strip read (cells 8k+g).
__device__ __forceinline__ void fwd_rp_core(h2* R2, h2* I2, uint2* sU,
                                            int g, int q,
                                            const unsigned* twru, const unsigned* twiu) {
  const int sb = q * PITCH;
  // pass 1: row-pair lines, elements = cols g+8m
  dft16h<false>(R2, I2);
  twmul_fwd_h(R2, I2, twru, twiu);
#pragma unroll
  for (int k = 0; k < 16; ++k) sU[sb + 8 * k + g] = make_uint2(h2u(R2[k]), h2u(I2[k]));
  __syncthreads();                             // B1
#pragma unroll
  for (int t = 0; t < 16; ++t) { const uint2 v = sU[sb + 16 * g + t]; R2[t] = u2h(v.x); I2[t] = u2h(v.y); }
  dft8h<false>(R2, I2); dft8h<false>(R2 + 8, I2 + 8);
  // slot t <-> spectral col-pos 16g+t of rows (q, q+64); write same cells
#pragma unroll
  for (int t = 0; t < 16; ++t) sU[sb + 16 * g + t] = make_uint2(h2u(R2[t]), h2u(I2[t]));
  __syncthreads();                             // B2: all strips ready
  // transpose + re-pair: rows->cols. Strip su holds row-pair (su, su+64);
  // slot u = row g+8u (lo), slot u+8 = row g+8u+64 (hi); halves = colpos q,q+64.
  {
#pragma unroll
    for (int u = 0; u < 8; ++u) {
      const int cb = (g + 8 * u) * PITCH;
      const uint2 vA = sU[cb + q];
      const uint2 vB = sU[cb + q + 64];
      R2[u]     = u2h(__builtin_amdgcn_perm(vB.x, vA.x, SEL_LO));
      I2[u]     = u2h(__builtin_amdgcn_perm(vB.y, vA.y, SEL_LO));
      R2[u + 8] = u2h(__builtin_amdgcn_perm(vB.x, vA.x, SEL_HI));
      I2[u + 8] = u2h(__builtin_amdgcn_perm(vB.y, vA.y, SEL_HI));
    }
  }
  // pass 2: col-pos-pair lines (q, q+64), elements = rows g+8m
  dft16h<false>(R2, I2);
  twmul_fwd_h(R2, I2, twru, twiu);
  __syncthreads();                             // B3: transpose reads drained
#pragma unroll
  for (int k = 0; k < 16; ++k) sU[sb + 8 * k + g] = make_uint2(h2u(R2[k]), h2u(I2[k]));
  __syncthreads();                             // B4
#pragma unroll
  for (int t = 0; t < 16; ++t) { const uint2 v = sU[sb + 16 * g + t]; R2[t] = u2h(v.x); I2[t] = u2h(v.y); }
  dft8h<false>(R2, I2); dft8h<false>(R2 + 8, I2 + 8);
}

template<int NW>
__device__ __forceinline__ float block_reduce_sum(float v, float* red, int tid) {
#pragma unroll
  for (int o = 32; o > 0; o >>= 1) v += __shfl_down(v, o);
  __syncthreads();
  if ((tid & 63) == 0) red[tid >> 6] = v;
  __syncthreads();
  float t = 0.0f;
  if (tid == 0) {
#pragma unroll
    for (int w = 0; w < NW; ++w) t += red[w];
  }
  return t;
}

// psi f32 granules (r5) + psih row-pair h2 cells for planes 4..23.
__global__ __launch_bounds__(256) void k_psi(const float* __restrict__ mags,
                                             const float* __restrict__ phases,
                                             float2* __restrict__ psi,
                                             float2* __restrict__ twg,
                                             uint2* __restrict__ psih,
                                             uint2* __restrict__ twgh) {
  if (blockIdx.x == 0 && threadIdx.x < 128) {
    const int gg = threadIdx.x >> 4, k = threadIdx.x & 15;
    float sn, cs;
    __sincosf(-TWO_PI * (float)(gg * k) * (1.0f / 128.0f), &sn, &cs);
    twg[threadIdx.x] = make_float2(cs, sn);
    twgh[threadIdx.x] = make_uint2(h2u(bch2(cs)), h2u(bch2(sn)));
  }
  const int gid = blockIdx.x * 256 + threadIdx.x;
  if (gid < 24 * PLANE) {                              // f32 psi (r5 granules)
    const int p = gid >> 14;
    const int rem = gid & (PLANE - 1);
    const int e = rem & 1;
    const int tt = (rem >> 1) & 1023;
    const int i = rem >> 11;
    const int j = 2 * i + e;
    const int g = tt >> 7, q = tt & 127;
    const int pr = 16 * g + j, pc = q;
    const int kr = (pr >> 3) + 16 * (pr & 7);
    const int kc = (pc >> 3) + 16 * (pc & 7);
    const int src = (p << 14) + kr * SDIM + kc;
    const float m = mags[src] * (1.0f / 16384.0f);
    float sn, cs;
    __sincosf(phases[src], &sn, &cs);
    psi[gid] = make_float2(m * cs, m * sn);
  } else if (gid < 24 * PLANE + 20 * 8192) {           // row-pair h2 psih
    const int c = gid - 24 * PLANE;
    const int pidx = c >> 13;
    const int rem = c & 8191;
    const int j = rem >> 9;
    const int t512 = rem & 511;
    const int g = t512 >> 6, q = t512 & 63;
    const int row = 16 * g + j;
    const int plane = pidx + 4;
    const int kr = (row >> 3) + 16 * (row & 7);
    const int kc0 = (q >> 3) + 16 * (q & 7);
    const int q1 = q + 64;
    const int kc1 = (q1 >> 3) + 16 * (q1 & 7);
    const int src0 = (plane << 14) + kr * SDIM + kc0;
    const int src1 = (plane << 14) + kr * SDIM + kc1;
    const float scl = PSIH_SCALE / 16384.0f;
    const float m0 = mags[src0] * scl;
    const float m1 = mags[src1] * scl;
    float sn0, cs0, sn1, cs1;
    __sincosf(phases[src0], &sn0, &cs0);
    __sincosf(phases[src1], &sn1, &cs1);
    psih[c] = make_uint2(h2u(mkh2(m0 * cs0, m1 * cs1)), h2u(mkh2(m0 * sn0, m1 * sn1)));
  }
}

// fp32 LDS; Xf granule layout; ~5 us.
__global__ __launch_bounds__(NT) void k_img_fft(const float* __restrict__ img,
                                                float2* __restrict__ Xf,
                                                float* __restrict__ s0,
                                                const float2* __restrict__ twg) {
  __shared__ float2 sC[SDIM * PITCH];
  __shared__ float red[16];
  const int tid = threadIdx.x, b = blockIdx.x;
  const int g = __builtin_amdgcn_readfirstlane(tid >> 7);
  const int q = tid & 127;
  float twr[16], twi[16];
  load_tw(twg, g, twr, twi);
  const float* ip = img + b * PLANE;
  float sum = 0.0f;
#pragma unroll
  for (int kk = 0; kk < 16; ++kk) {
    const int e = tid + kk * NT;
    const float v = ip[e];
    sC[(e >> 7) * PITCH + (e & 127)] = make_float2(v, 0.0f);
    sum += v;
  }
  const float tot = block_reduce_sum<16>(sum, red, tid);
  if (tid == 0) s0[b] = tot * (1.0f / 16384.0f);
  __syncthreads();
  float R[16], I[16];
#pragma unroll
  for (int m = 0; m < 16; ++m) { R[m] = sC[q * PITCH + g + 8 * m].x; I[m] = 0.0f; }
  fwd_fft2(R, I, sC, g, q, twr, twi);
  float4* x4 = (float4*)Xf + (size_t)b * 8192 + tid;
#pragma unroll
  for (int i = 0; i < 8; ++i)
    x4[i * 1024] = make_float4(R[2 * i], I[2 * i], R[2 * i + 1], I[2 * i + 1]);
}

// Phase A row-pair h2: 1536 blocks x 512 thr, 66KB -> 2 blocks/CU.
// bid<1280: (j1,b,l1): u1=|ifft|(x16), s1; U=fwd(u1/16) -> Ubuf f16-pair uint4.
// bid>=1280: j=5 inverse + s1 only.
__global__ __launch_bounds__(512, 4) void k_scat_a_rp(const float2* __restrict__ Xf,
                                                      const float2* __restrict__ psi,
                                                      float* __restrict__ s1num,
                                                      unsigned* __restrict__ Ubuf,
                                                      const uint2* __restrict__ twgh) {
  __shared__ uint2 sU[64 * PITCH];             // 66,048 B
  __shared__ float red[8];
  const int tid = threadIdx.x;
  const int g = __builtin_amdgcn_readfirstlane(tid >> 6);
  const int q = tid & 63;
  unsigned twru[16], twiu[16];
  load_twh(twgh, g, twru, twiu);
  const int bid = blockIdx.x;

  int plane, b, sidx, grp = -1;
  if (bid < 1280) {
    const int j1 = bid >> 8;
    b = (bid & 255) >> 2;
    const int l1 = bid & 3;
    plane = j1 * 4 + l1;
    sidx = b * 6 + j1;
    grp = (b * 5 + j1) * 4 + l1;
  } else {
    const int idx = bid - 1280;
    b = idx >> 2;
    plane = 20 + (idx & 3);
    sidx = b * 6 + 5;
  }

  h2 R2[16], I2[16];
  {
    const int t0 = g * 128 + q;
    const float4* xL = (const float4*)Xf + (size_t)b * 8192 + t0;
    const float4* pL = (const float4*)psi + (size_t)plane * 8192 + t0;
#pragma unroll
    for (int i = 0; i < 8; ++i) {
      const float4 xa = xL[i * 1024],      va = pL[i * 1024];
      const float4 xb = xL[i * 1024 + 64], vb = pL[i * 1024 + 64];
      const float reL0 = xa.x * va.x - xa.y * va.y, imL0 = xa.x * va.y + xa.y * va.x;
      const float reH0 = xb.x * vb.x - xb.y * vb.y, imH0 = xb.x * vb.y + xb.y * vb.x;
      const float reL1 = xa.z * va.z - xa.w * va.w, imL1 = xa.z * va.w + xa.w * va.z;
      const float reH1 = xb.z * vb.z - xb.w * vb.w, imH1 = xb.z * vb.w + xb.w * vb.z;
      R2[2 * i]     = mkh2(reL0 * A_SCALE, reH0 * A_SCALE);
      I2[2 * i]     = mkh2(imL0 * A_SCALE, imH0 * A_SCALE);
      R2[2 * i + 1] = mkh2(reL1 * A_SCALE, reH1 * A_SCALE);
      I2[2 * i + 1] = mkh2(imL1 * A_SCALE, imH1 * A_SCALE);
    }
  }
  inv_rp_core(R2, I2, sU, g, q, twru, twiu);

  float s1sum = 0.0f;
  if (grp >= 0) {
#pragma unroll
    for (int m = 0; m < 16; ++m) {
      const float rl = (float)R2[m].x, il = (float)I2[m].x;
      const float rh = (float)R2[m].y, ih = (float)I2[m].y;
      const float aL = fast_sqrtf(rl * rl + il * il);
      const float aH = fast_sqrtf(rh * rh + ih * ih);
      s1sum += aL + aH;
      R2[m] = mkh2(aL * (1.0f / A_SCALE), aH * (1.0f / A_SCALE));
      I2[m] = bch2(0.0f);
    }
    fwd_rp_core(R2, I2, sU, g, q, twru, twiu);
    // store U as f16-pairs: uint4{cL(2i), cH(2i), cL(2i+1), cH(2i+1)}
    uint4* o4 = (uint4*)Ubuf + (size_t)grp * 4096 + tid;
#pragma unroll
    for (int i = 0; i < 8; ++i) {
      uint4 ob;
      ob.x = __builtin_amdgcn_perm(h2u(I2[2 * i]),     h2u(R2[2 * i]),     SEL_LO);
      ob.y = __builtin_amdgcn_perm(h2u(I2[2 * i]),     h2u(R2[2 * i]),     SEL_HI);
      ob.z = __builtin_amdgcn_perm(h2u(I2[2 * i + 1]), h2u(R2[2 * i + 1]), SEL_LO);
      ob.w = __builtin_amdgcn_perm(h2u(I2[2 * i + 1]), h2u(R2[2 * i + 1]), SEL_HI);
      o4[i * 512] = ob;
    }
  } else {
#pragma unroll
    for (int m = 0; m < 16; ++m) {
      const float rl = (float)R2[m].x, il = (float)I2[m].x;
      const float rh = (float)R2[m].y, ih = (float)I2[m].y;
      s1sum += fast_sqrtf(rl * rl + il * il) + fast_sqrtf(rh * rh + ih * ih);
    }
  }
  const float tot = block_reduce_sum<8>(s1sum, red, tid);
  if (tid == 0) atomicAdd(&s1num[sidx], tot);
}

// Phase A f32 (tier-2; r5 structure, bf16 granule Ubuf).
__global__ __launch_bounds__(NT) void k_scat_a(const float2* __restrict__ Xf,
                                               const float2* __restrict__ psi,
                                               float* __restrict__ s1num,
                                               unsigned* __restrict__ Ubuf,
                                               const float2* __restrict__ twg) {
  __shared__ unsigned sU[SDIM * PITCH];
  __shared__ float red[16];
  const int tid = threadIdx.x;
  const int g = __builtin_amdgcn_readfirstlane(tid >> 7);
  const int q = tid & 127;
  float twr[16], twi[16];
  load_tw(twg, g, twr, twi);
  const int bid = blockIdx.x;
  float R[16], I[16];

  if (bid < 1280) {
    const int j1 = bid >> 8;
    const int b = (bid & 255) >> 2;
    const int l1 = bid & 3;
    const float4* x4 = (const float4*)Xf + (size_t)b * 8192 + tid;
    const float4* p4 = (const float4*)psi + (size_t)(j1 * 4 + l1) * 8192 + tid;
#pragma unroll
    for (int i = 0; i < 8; ++i) {
      const float4 x = x4[i * 1024], v = p4[i * 1024];
      R[2 * i]     = x.x * v.x - x.y * v.y;  I[2 * i]     = x.x * v.y + x.y * v.x;
      R[2 * i + 1] = x.z * v.z - x.w * v.w;  I[2 * i + 1] = x.z * v.w + x.w * v.z;
    }
    inv_fft2<true>(R, I, sU, g, q, twr, twi);
    float s1sum = 0.0f;
#pragma unroll
    for (int m = 0; m < 16; ++m) {
      const float a = fast_sqrtf(R[m] * R[m] + I[m] * I[m]);
      s1sum += a; R[m] = a; I[m] = 0.0f;
    }
    fwd_fft2(R, I, sU, g, q, twr, twi);
    uint4 ob[4];
    unsigned* obs = (unsigned*)ob;
#pragma unroll
    for (int j = 0; j < 16; ++j) obs[j] = packbf(R[j], I[j]);
    uint4* o4 = (uint4*)Ubuf + (size_t)((b * 5 + j1) * 4 + l1) * 4096 + tid;
#pragma unroll
    for (int i = 0; i < 4; ++i) o4[i * 1024] = ob[i];
    const float tot = block_reduce_sum<16>(s1sum, red, tid);
    if (tid == 0) atomicAdd(&s1num[b * 6 + j1], tot);
  } else {
    const int idx = bid - 1280;
    const int b = idx >> 2, l = idx & 3;
    const float4* x4 = (const float4*)Xf + (size_t)b * 8192 + tid;
    const float4* p4 = (const float4*)psi + (size_t)(20 + l) * 8192 + tid;
#pragma unroll
    for (int i = 0; i < 8; ++i) {
      const float4 x = x4[i * 1024], v = p4[i * 1024];
      R[2 * i]     = x.x * v.x - x.y * v.y;  I[2 * i]     = x.x * v.y + x.y * v.x;
      R[2 * i + 1] = x.z * v.z - x.w * v.w;  I[2 * i + 1] = x.z * v.w + x.w * v.z;
    }
    inv_fft2<true>(R, I, sU, g, q, twr, twi);
    float s = 0.0f;
#pragma unroll
    for (int m = 0; m < 16; ++m) s += fast_sqrtf(R[m] * R[m] + I[m] * I[m]);
    const float tot = block_reduce_sum<16>(s, red, tid);
    if (tid == 0) atomicAdd(&s1num[b * 6 + 5], tot);
  }
}

// Phase B multi-ifft row-pair h2 (r20 structure; f16-pair U loader).
__global__ __launch_bounds__(512, 4) void k_scat_b_rpm(const uint2* __restrict__ psih,
                                                       const unsigned* __restrict__ Ubuf,
                                                       float* __restrict__ s2num,
                                                       const uint2* __restrict__ twgh) {
  __shared__ uint2 sU[64 * PITCH];             // 66,048 B
  __shared__ float red[8];
  const int tid = threadIdx.x;
  const int g = __builtin_amdgcn_readfirstlane(tid >> 6);
  const int q = tid & 63;
  unsigned twru[16], twiu[16];
  load_twh(twgh, g, twru, twiu);
  const int bid = blockIdx.x;
  const int j1 = bid >> 8;                     // heavy j1=0 first
  const int b = (bid & 255) >> 2;
  const int l1 = bid & 3;
  const int pb = (j1 * (11 - j1)) >> 1;
  const int nit = (5 - j1) * 4;

  // U-slice once: f16-pair uint4 granules.
  h2 UR2[16], UI2[16];
  {
    const uint4* u4 = (const uint4*)Ubuf + (size_t)((b * 5 + j1) * 4 + l1) * 4096 + tid;
#pragma unroll
    for (int i = 0; i < 8; ++i) {
      const uint4 v = u4[i * 512];
      UR2[2 * i]     = u2h(__builtin_amdgcn_perm(v.y, v.x, SEL_LO));
      UI2[2 * i]     = u2h(__builtin_amdgcn_perm(v.y, v.x, SEL_HI));
      UR2[2 * i + 1] = u2h(__builtin_amdgcn_perm(v.w, v.z, SEL_LO));
      UI2[2 * i + 1] = u2h(__builtin_amdgcn_perm(v.w, v.z, SEL_HI));
    }
  }

  uint2 buf[16];
  {
    const uint2* ph = psih + (size_t)(4 * j1) * 8192 + tid;
#pragma unroll
    for (int j = 0; j < 16; ++j) buf[j] = ph[j * 512];
  }

  float vsum = 0.0f;
  for (int it = 0; it < nit; ++it) {
    h2 R2[16], I2[16];
#pragma unroll
    for (int j = 0; j < 16; ++j) {
      const h2 pr = u2h(buf[j].x), pi = u2h(buf[j].y);
      R2[j] = UR2[j] * pr - UI2[j] * pi;
      I2[j] = UR2[j] * pi + UI2[j] * pr;
    }
    if (it + 1 < nit) {
      const uint2* phn = psih + (size_t)(4 * j1 + it + 1) * 8192 + tid;
#pragma unroll
      for (int j = 0; j < 16; ++j) buf[j] = phn[j * 512];
    }
    if (it) __syncthreads();                   // B0: prev B4-reads drained
    inv_rp_core(R2, I2, sU, g, q, twru, twiu);
#pragma unroll
    for (int m = 0; m < 16; ++m) {
      const float rl = (float)R2[m].x, il = (float)I2[m].x;
      const float rh = (float)R2[m].y, ih = (float)I2[m].y;
      vsum += fast_sqrtf(rl * rl + il * il) + fast_sqrtf(rh * rh + ih * ih);
    }
    if ((it & 3) == 3) {
      const float tot = block_reduce_sum<8>(vsum, red, tid);
      if (tid == 0) atomicAdd(&s2num[b * 15 + pb + (it >> 2)], tot);
      vsum = 0.0f;
    }
  }
}

// Phase B f32 fallback (tier-2; bf16 granule Ubuf).
__global__ __launch_bounds__(NT) void k_scat_b(const float2* __restrict__ psi,
                                               const unsigned* __restrict__ Ubuf,
                                               float* __restrict__ s2num,
                                               const float2* __restrict__ twg) {
  __shared__ unsigned sU[SDIM * PITCH];
  __shared__ float red[16];
  const int tid = threadIdx.x;
  const int g = __builtin_amdgcn_readfirstlane(tid >> 7);
  const int q = tid & 127;
  float twr[16], twi[16];
  load_tw(twg, g, twr, twi);
  int t = blockIdx.x;
  const int l2 = t & 3; t >>= 2;
  const int pair = t % 15; t /= 15;
  const int l1 = t & 3;
  const int b = t >> 2;
  int j1 = 0, base = 0;
  if (pair >= 14)      { j1 = 4; base = 14; }
  else if (pair >= 12) { j1 = 3; base = 12; }
  else if (pair >= 9)  { j1 = 2; base = 9; }
  else if (pair >= 5)  { j1 = 1; base = 5; }
  const int j2 = j1 + 1 + (pair - base);
  float R[16], I[16];
  {
    const uint4* u4 = (const uint4*)Ubuf + (size_t)((b * 5 + j1) * 4 + l1) * 4096 + tid;
    uint4 ub[4];
#pragma unroll
    for (int i = 0; i < 4; ++i) ub[i] = u4[i * 1024];
    const unsigned* ubs = (const unsigned*)ub;
    const float4* p4 = (const float4*)psi + (size_t)(j2 * 4 + l2) * 8192 + tid;
#pragma unroll
    for (int i = 0; i < 8; ++i) {
      const float4 v = p4[i * 1024];
      float ur, ui;
      unpackbf(ubs[2 * i], ur, ui);
      R[2 * i] = ur * v.x - ui * v.y;      I[2 * i] = ur * v.y + ui * v.x;
      unpackbf(ubs[2 * i + 1], ur, ui);
      R[2 * i + 1] = ur * v.z - ui * v.w;  I[2 * i + 1] = ur * v.w + ui * v.z;
    }
  }
  inv_fft2<true>(R, I, sU, g, q, twr, twi);
  float vsum = 0.0f;
#pragma unroll
  for (int m = 0; m < 16; ++m) vsum += fast_sqrtf(R[m] * R[m] + I[m] * I[m]);
  const float tot = block_reduce_sum<16>(vsum, red, tid);
  if (tid == 0) atomicAdd(&s2num[b * 15 + pair], tot);
}

// Fallback (ws tiny): monolithic; correctness only.
__global__ __launch_bounds__(NT) void k_scat_mono(const float2* __restrict__ Xf,
                                                  const float2* __restrict__ psi,
                                                  float* __restrict__ s1num,
                                                  float* __restrict__ s2num,
                                                  const float2* __restrict__ twg) {
  __shared__ unsigned sU[SDIM * PITCH];
  __shared__ float red[16];
  const int tid = threadIdx.x;
  const int g = __builtin_amdgcn_readfirstlane(tid >> 7);
  const int q = tid & 127;
  float twr[16], twi[16];
  load_tw(twg, g, twr, twi);
  const int bid = blockIdx.x;
  float R[16], I[16];
  if (bid < 1280) {
    const int j1 = bid >> 8;
    const int b = (bid & 255) >> 2;
    const int l1 = bid & 3;
    const float4* x4 = (const float4*)Xf + (size_t)b * 8192 + tid;
    const float4* p4 = (const float4*)psi + (size_t)(j1 * 4 + l1) * 8192 + tid;
#pragma unroll
    for (int i = 0; i < 8; ++i) {
      const float4 x = x4[i * 1024], v = p4[i * 1024];
      R[2 * i]     = x.x * v.x - x.y * v.y;  I[2 * i]     = x.x * v.y + x.y * v.x;
      R[2 * i + 1] = x.z * v.z - x.w * v.w;  I[2 * i + 1] = x.z * v.w + x.w * v.z;
    }
    inv_fft2<true>(R, I, sU, g, q, twr, twi);
    float s1sum = 0.0f;
#pragma unroll
    for (int m = 0; m < 16; ++m) {
      const float a = fast_sqrtf(R[m] * R[m] + I[m] * I[m]);
      s1sum += a; R[m] = a; I[m] = 0.0f;
    }
    fwd_fft2(R, I, sU, g, q, twr, twi);
    float Ur[16], Ui[16];
#pragma unroll
    for (int k = 0; k < 16; ++k) { Ur[k] = R[k]; Ui[k] = I[k]; }
    {
      const float tot = block_reduce_sum<16>(s1sum, red, tid);
      if (tid == 0) atomicAdd(&s1num[b * 6 + j1], tot);
    }
    const int pb = (j1 * (11 - j1)) >> 1;
    int plane = (j1 + 1) * 4;
#pragma unroll 1
    for (int j2 = j1 + 1; j2 <= 5; ++j2) {
      float vsum = 0.0f;
#pragma unroll 1
      for (int l2 = 0; l2 < 4; ++l2) {
        const float4* q4 = (const float4*)psi + (size_t)plane * 8192 + tid;
#pragma unroll
        for (int i = 0; i < 8; ++i) {
          const float4 v = q4[i * 1024];
          R[2 * i]     = Ur[2 * i] * v.x - Ui[2 * i] * v.y;
          I[2 * i]     = Ur[2 * i] * v.y + Ui[2 * i] * v.x;
          R[2 * i + 1] = Ur[2 * i + 1] * v.z - Ui[2 * i + 1] * v.w;
          I[2 * i + 1] = Ur[2 * i + 1] * v.w + Ui[2 * i + 1] * v.z;
        }
        inv_fft2<false>(R, I, sU, g, q, twr, twi);
#pragma unroll
        for (int m = 0; m < 16; ++m) vsum += fast_sqrtf(R[m] * R[m] + I[m] * I[m]);
        ++plane;
      }
      const float tot = block_reduce_sum<16>(vsum, red, tid);
      if (tid == 0) atomicAdd(&s2num[b * 15 + pb + (j2 - j1 - 1)], tot);
    }
  } else {
    const int idx = bid - 1280;
    const int b = idx >> 2, l = idx & 3;
    const float4* x4 = (const float4*)Xf + (size_t)b * 8192 + tid;
    const float4* p4 = (const float4*)psi + (size_t)(20 + l) * 8192 + tid;
#pragma unroll
    for (int i = 0; i < 8; ++i) {
      const float4 x = x4[i * 1024], v = p4[i * 1024];
      R[2 * i]     = x.x * v.x - x.y * v.y;  I[2 * i]     = x.x * v.y + x.y * v.x;
      R[2 * i + 1] = x.z * v.z - x.w * v.w;  I[2 * i + 1] = x.z * v.w + x.w * v.z;
    }
    inv_fft2<true>(R, I, sU, g, q, twr, twi);
    float s = 0.0f;
#pragma unroll
    for (int m = 0; m < 16; ++m) s += fast_sqrtf(R[m] * R[m] + I[m] * I[m]);
    const float tot = block_reduce_sum<16>(s, red, tid);
    if (tid == 0) atomicAdd(&s1num[b * 6 + 5], tot);
  }
}

__global__ __launch_bounds__(64) void k_final(const float* __restrict__ s0,
                                              const float* __restrict__ s1num,
                                              const float* __restrict__ s2num,
                                              const float* __restrict__ w1,
                                              const float* __restrict__ b1,
                                              const float* __restrict__ w2,
                                              const float* __restrict__ b2,
                                              const float* __restrict__ w3,
                                              const float* __restrict__ b3,
                                              float* __restrict__ out,
                                              float s1scale, float s2scale) {
  const int b = threadIdx.x;
  if (b >= 64) return;
  float x[22];
  x[0] = s0[b];
#pragma unroll
  for (int j = 0; j < 6; ++j) x[1 + j] = s1num[b * 6 + j] * s1scale;
#pragma unroll
  for (int p = 0; p < 15; ++p) x[7 + p] = s2num[b * 15 + p] * s2scale;
  float h1[16];
#pragma unroll
  for (int o = 0; o < 16; ++o) {
    float t = b1[o];
    for (int i = 0; i < 22; ++i) t += x[i] * w1[i * 16 + o];
    h1[o] = fmaxf(t, 0.0f);
  }
  float h2a[16];
#pragma unroll
  for (int o = 0; o < 16; ++o) {
    float t = b2[o];
    for (int i = 0; i < 16; ++i) t += h1[i] * w2[i * 16 + o];
    h2a[o] = fmaxf(t, 0.0f);
  }
  float t = b3[0];
#pragma unroll
  for (int i = 0; i < 16; ++i) t += h2a[i] * w3[i];
  out[b] = 1.0f / (1.0f + expf(-t));
}

extern "C" void kernel_launch(void* const* d_in, const int* in_sizes, int n_in,
                              void* d_out, int out_size, void* d_ws, size_t ws_size,
                              hipStream_t stream) {
  (void)in_sizes; (void)n_in; (void)out_size;
  const float* image  = (const float*)d_in[0];
  const float* mags   = (const float*)d_in[1];
  const float* phases = (const float*)d_in[2];
  const float* w1 = (const float*)d_in[3];
  const float* b1 = (const float*)d_in[4];
  const float* w2 = (const float*)d_in[5];
  const float* b2 = (const float*)d_in[6];
  const float* w3 = (const float*)d_in[7];
  const float* b3 = (const float*)d_in[8];
  float* out = (float*)d_out;

  char* ws = (char*)d_ws;
  float2* psi = (float2*)ws;                       // 3,145,728 B
  float2* Xf  = (float2*)(ws + 3145728);           // 8,388,608 B
  float*  s0  = (float*)(ws + 11534336);           // 64
  float*  s1n = s0 + 64;                           // 384
  float*  s2n = s1n + 384;                         // 960
  float2* twg = (float2*)(s2n + 960);              // 128 float2 (1024 B)
  uint2*  twgh = (uint2*)((char*)twg + 1024);      // 128 uint2 (1024 B)
  unsigned* Ubuf = (unsigned*)(ws + 11542528);     // 83,886,080 B
  uint2*  psih = (uint2*)(ws + 95428608);          // 1,310,720 B (20 planes)
  const size_t need_r5 = 11542528ull + 83886080ull;          // 95,428,608
  const size_t need_h2 = need_r5 + 1310720ull;               // 96,739,328

  hipMemsetAsync(s1n, 0, (384 + 960) * sizeof(float), stream);
  if (ws_size >= need_h2) {
    k_psi<<<dim3(2176), dim3(256), 0, stream>>>(mags, phases, psi, twg, psih, twgh);
    k_img_fft<<<dim3(64), dim3(NT), 0, stream>>>(image, Xf, s0, twg);
    k_scat_a_rp<<<dim3(1536), dim3(512), 0, stream>>>(Xf, psi, s1n, Ubuf, twgh);
    k_scat_b_rpm<<<dim3(1280), dim3(512), 0, stream>>>(psih, Ubuf, s2n, twgh);
    k_final<<<dim3(1), dim3(64), 0, stream>>>(s0, s1n, s2n, w1, b1, w2, b2, w3, b3, out,
                                              1.0f / (4.0f * 16384.0f * A_SCALE),
                                              1.0f / (16.0f * 16384.0f * PSIH_SCALE));
  } else if (ws_size >= need_r5) {
    k_psi<<<dim3(1536), dim3(256), 0, stream>>>(mags, phases, psi, twg, psih, twgh);
    k_img_fft<<<dim3(64), dim3(NT), 0, stream>>>(image, Xf, s0, twg);
    k_scat_a<<<dim3(1536), dim3(NT), 0, stream>>>(Xf, psi, s1n, Ubuf, twg);
    k_scat_b<<<dim3(15360), dim3(NT), 0, stream>>>(psi, Ubuf, s2n, twg);
    k_final<<<dim3(1), dim3(64), 0, stream>>>(s0, s1n, s2n, w1, b1, w2, b2, w3, b3, out,
                                              1.0f / (4.0f * 16384.0f),
                                              1.0f / (16.0f * 16384.0f));
  } else {
    k_psi<<<dim3(1536), dim3(256), 0, stream>>>(mags, phases, psi, twg, psih, twgh);
    k_img_fft<<<dim3(64), dim3(NT), 0, stream>>>(image, Xf, s0, twg);
    k_scat_mono<<<dim3(1536), dim3(NT), 0, stream>>>(Xf, psi, s1n, s2n, twg);
    k_final<<<dim3(1), dim3(64), 0, stream>>>(s0, s1n, s2n, w1, b1, w2, b2, w3, b3, out,
                                              1.0f / (4.0f * 16384.0f),
                                              1.0f / (16.0f * 16384.0f));
  }
}

// Round 11
// 424.805 us; speedup vs baseline: 1.3968x; 1.0374x over previous
//
#include <hip/hip_runtime.h>
#include <math.h>

// Scattering net: four-step register FFT.
//
// Round-22: FUSE scat_a + scat_b. r21 showed scat_a smaller than modeled;
// scat_b is ~66% of its VALU-issue bound (4 waves/SIMD x ~1050 instr x 2cyc).
// The (b,j1,l1) block that PRODUCES U is exactly the one that CONSUMES it ->
// fuse: cmul(X.psi) -> inv -> s1 -> fwd -> U in 32 h2 regs -> r20 prefetched
// multi-ifft loop. U never touches HBM (saves 84MB W + 46MB F + one launch).
// Barrier audit: fwd's final own-strip reads (cells sb+16g+t, own thread) and
// the loop's first inv own-strip writes (same cells, same thread) need no
// barrier; the s1-reduce's barriers drain the rest; `if(it)` barrier kept
// between loop iterations (cross-thread cell reuse). Magnitude via h2
// square+fma then 2 cvt + 2 sqrt (saves ~3 VALU/slot). VGPR peak ~112.
// Tier-2 (f32 scat_a/scat_b via Ubuf) and mono fallback unchanged.

#define SDIM 128
#define PLANE 16384
#define PITCH 129
#define NT 1024
#define TWO_PI 6.28318530717958647692f
#define PSIH_SCALE 16.0f
#define A_SCALE 16.0f

typedef _Float16 h2 __attribute__((ext_vector_type(2)));

constexpr float W16R[8] = {1.f, 0.9238795325f, 0.7071067812f, 0.3826834324f,
                           0.f, -0.3826834324f, -0.7071067812f, -0.9238795325f};
constexpr float W16I[8] = {0.f, -0.3826834324f, -0.7071067812f, -0.9238795325f,
                           -1.f, -0.9238795325f, -0.7071067812f, -0.3826834324f};

__device__ __forceinline__ float fast_sqrtf(float x) { return __builtin_amdgcn_sqrtf(x); }

// ---- packed bf16 complex <-> fp32 pair (tier-2 f32 path) ----
__device__ __forceinline__ unsigned packbf(float re, float im) {
  const unsigned r = __float_as_uint(re) + 0x8000u;
  const unsigned i = __float_as_uint(im) + 0x8000u;
  return __builtin_amdgcn_perm(r, i, 0x07060302u);
}
__device__ __forceinline__ void unpackbf(unsigned u, float& re, float& im) {
  re = __uint_as_float(u & 0xFFFF0000u);
  im = __uint_as_float(u << 16);
}

// ---- h2 helpers ----
union UHU { unsigned u; h2 h; };
__device__ __forceinline__ h2 u2h(unsigned u) { UHU x; x.u = u; return x.h; }
__device__ __forceinline__ unsigned h2u(h2 h) { UHU x; x.h = h; return x.u; }
__device__ __forceinline__ h2 bch2(float f) { const _Float16 h = (_Float16)f; h2 v = {h, h}; return v; }
__device__ __forceinline__ h2 mkh2(float a, float b) { h2 v = {(_Float16)a, (_Float16)b}; return v; }

#define SEL_LO 0x05040100u
#define SEL_HI 0x07060302u

// storage-polymorphic LDS access (f32 cores)
__device__ __forceinline__ void stC(float2* s, int idx, float re, float im) { s[idx] = make_float2(re, im); }
__device__ __forceinline__ void ldC(const float2* s, int idx, float& re, float& im) { const float2 v = s[idx]; re = v.x; im = v.y; }
__device__ __forceinline__ void stC(unsigned* s, int idx, float re, float im) { s[idx] = packbf(re, im); }
__device__ __forceinline__ void ldC(const unsigned* s, int idx, float& re, float& im) { unpackbf(s[idx], re, im); }

// wave-uniform twiddle tables -> SGPRs.
__device__ __forceinline__ void load_tw(const float2* __restrict__ twg, int g,
                                        float* twr, float* twi) {
#pragma unroll
  for (int k = 1; k < 16; ++k) {
    const float2 w = twg[16 * g + k];
    twr[k] = __uint_as_float(__builtin_amdgcn_readfirstlane(__float_as_uint(w.x)));
    twi[k] = __uint_as_float(__builtin_amdgcn_readfirstlane(__float_as_uint(w.y)));
  }
}
__device__ __forceinline__ void load_twh(const uint2* __restrict__ twgh, int g,
                                         unsigned* twru, unsigned* twiu) {
#pragma unroll
  for (int k = 1; k < 16; ++k) {
    const uint2 w = twgh[16 * g + k];
    twru[k] = (unsigned)__builtin_amdgcn_readfirstlane((int)w.x);
    twiu[k] = (unsigned)__builtin_amdgcn_readfirstlane((int)w.y);
  }
}

// ---------------- f32 FFT core (r5, known-good; tier-2) ----------------
template<bool INV>
__device__ __forceinline__ void bfly(float& ar, float& ai, float& br, float& bi, const int idx) {
  float tr, ti;
  if (idx == 0) { tr = br; ti = bi; }
  else if (idx == 4) {
    if (INV) { tr = -bi; ti = br; } else { tr = bi; ti = -br; }
  } else {
    const float wr = W16R[idx];
    const float wi = INV ? -W16I[idx] : W16I[idx];
    tr = br * wr - bi * wi;
    ti = br * wi + bi * wr;
  }
  br = ar - tr; bi = ai - ti;
  ar = ar + tr; ai = ai + ti;
}

#define CSWAP(re, im, a, b) { float _t = re[a]; re[a]=re[b]; re[b]=_t; _t = im[a]; im[a]=im[b]; im[b]=_t; }

template<bool INV>
__device__ __forceinline__ void dft16(float* re, float* im) {
  CSWAP(re, im, 1, 8) CSWAP(re, im, 2, 4) CSWAP(re, im, 3, 12)
  CSWAP(re, im, 5, 10) CSWAP(re, im, 7, 14) CSWAP(re, im, 11, 13)
#pragma unroll
  for (int ls = 1; ls <= 4; ++ls) {
    const int len = 1 << ls, half = len >> 1, tstep = 16 >> ls;
#pragma unroll
    for (int blk = 0; blk < 16; blk += len)
#pragma unroll
      for (int j = 0; j < half; ++j)
        bfly<INV>(re[blk + j], im[blk + j], re[blk + j + half], im[blk + j + half], j * tstep);
  }
}

template<bool INV>
__device__ __forceinline__ void dft8(float* re, float* im) {
  CSWAP(re, im, 1, 4) CSWAP(re, im, 3, 6)
#pragma unroll
  for (int ls = 1; ls <= 3; ++ls) {
    const int len = 1 << ls, half = len >> 1, tstep = 8 >> ls;
#pragma unroll
    for (int blk = 0; blk < 8; blk += len)
#pragma unroll
      for (int j = 0; j < half; ++j)
        bfly<INV>(re[blk + j], im[blk + j], re[blk + j + half], im[blk + j + half], j * tstep * 2);
  }
}

__device__ __forceinline__ void twmul_fwd(float* R, float* I, const float* twr, const float* twi) {
#pragma unroll
  for (int k = 1; k < 16; ++k) {
    const float r = R[k] * twr[k] - I[k] * twi[k];
    I[k] = R[k] * twi[k] + I[k] * twr[k]; R[k] = r;
  }
}
__device__ __forceinline__ void twmul_inv(float* R, float* I, const float* twr, const float* twi) {
#pragma unroll
  for (int k = 1; k < 16; ++k) {
    const float r = R[k] * twr[k] + I[k] * twi[k];
    I[k] = I[k] * twr[k] - R[k] * twi[k]; R[k] = r;
  }
}

template<typename S>
__device__ __forceinline__ void fwd_fft2(float* R, float* I, S* sC,
                                         int g, int q, const float* twr, const float* twi) {
  const int rb = q * PITCH;
  dft16<false>(R, I);
  twmul_fwd(R, I, twr, twi);
  __syncthreads();                             // B0
#pragma unroll
  for (int k = 0; k < 16; ++k) stC(sC, rb + 8 * k + g, R[k], I[k]);
  __syncthreads();                             // B1
#pragma unroll
  for (int t = 0; t < 8; ++t) {
    ldC(sC, rb + 16 * g + t, R[t], I[t]);
    ldC(sC, rb + 16 * g + 8 + t, R[8 + t], I[8 + t]);
  }
  dft8<false>(R, I); dft8<false>(R + 8, I + 8);
#pragma unroll
  for (int k2 = 0; k2 < 8; ++k2) {
    stC(sC, rb + 16 * g + k2, R[k2], I[k2]);
    stC(sC, rb + 16 * g + 8 + k2, R[8 + k2], I[8 + k2]);
  }
  __syncthreads();                             // B2
#pragma unroll
  for (int m = 0; m < 16; ++m) ldC(sC, (g + 8 * m) * PITCH + q, R[m], I[m]);
  dft16<false>(R, I);
  twmul_fwd(R, I, twr, twi);
#pragma unroll
  for (int k = 0; k < 16; ++k) stC(sC, (8 * k + g) * PITCH + q, R[k], I[k]);
  __syncthreads();                             // B3
#pragma unroll
  for (int u = 0; u < 8; ++u) {
    const int bp = (16 * g + 2 * u) * PITCH + q;
    ldC(sC, bp, R[2 * u], I[2 * u]);
    ldC(sC, bp + PITCH, R[2 * u + 1], I[2 * u + 1]);
  }
  dft8<false>(R, I); dft8<false>(R + 8, I + 8);
}

template<bool FIRST, typename S>
__device__ __forceinline__ void inv_fft2(float* R, float* I, S* sC,
                                         int g, int q, const float* twr, const float* twi) {
  const int rb = q * PITCH;
  dft8<true>(R, I); dft8<true>(R + 8, I + 8);
  if constexpr (!FIRST) __syncthreads();       // B0
#pragma unroll
  for (int t = 0; t < 16; ++t) stC(sC, rb + 16 * g + t, R[t], I[t]);
  __syncthreads();                             // B1
#pragma unroll
  for (int k = 0; k < 16; ++k) ldC(sC, rb + 8 * k + g, R[k], I[k]);
  twmul_inv(R, I, twr, twi);
  dft16<true>(R, I);
#pragma unroll
  for (int m = 0; m < 16; ++m) stC(sC, rb + g + 8 * m, R[m], I[m]);
  __syncthreads();                             // B2
#pragma unroll
  for (int u = 0; u < 8; ++u) {
    const int bp = (16 * g + 2 * u) * PITCH + q;
    ldC(sC, bp, R[2 * u], I[2 * u]);
    ldC(sC, bp + PITCH, R[2 * u + 1], I[2 * u + 1]);
  }
  dft8<true>(R, I); dft8<true>(R + 8, I + 8);
#pragma unroll
  for (int u = 0; u < 8; ++u) {
    const int bp = (16 * g + 2 * u) * PITCH + q;
    stC(sC, bp, R[2 * u], I[2 * u]);
    stC(sC, bp + PITCH, R[2 * u + 1], I[2 * u + 1]);
  }
  __syncthreads();                             // B3
#pragma unroll
  for (int k = 0; k < 16; ++k) ldC(sC, (8 * k + g) * PITCH + q, R[k], I[k]);
  twmul_inv(R, I, twr, twi);
  dft16<true>(R, I);
}

// ---------------- h2 FFT core ----------------
template<bool INV>
__device__ __forceinline__ void bfly_h(h2& ar, h2& ai, h2& br, h2& bi, const int idx) {
  h2 tr, ti;
  if (idx == 0) { tr = br; ti = bi; }
  else if (idx == 4) {
    if (INV) { tr = -bi; ti = br; } else { tr = bi; ti = -br; }
  } else {
    const h2 wr = bch2(W16R[idx]);
    const h2 wi = bch2(INV ? -W16I[idx] : W16I[idx]);
    tr = br * wr - bi * wi;
    ti = br * wi + bi * wr;
  }
  br = ar - tr; bi = ai - ti;
  ar = ar + tr; ai = ai + ti;
}

#define HSWAP(re, im, a, b) { h2 _t = re[a]; re[a]=re[b]; re[b]=_t; _t = im[a]; im[a]=im[b]; im[b]=_t; }

template<bool INV>
__device__ __forceinline__ void dft16h(h2* re, h2* im) {
  HSWAP(re, im, 1, 8) HSWAP(re, im, 2, 4) HSWAP(re, im, 3, 12)
  HSWAP(re, im, 5, 10) HSWAP(re, im, 7, 14) HSWAP(re, im, 11, 13)
#pragma unroll
  for (int ls = 1; ls <= 4; ++ls) {
    const int len = 1 << ls, half = len >> 1, tstep = 16 >> ls;
#pragma unroll
    for (int blk = 0; blk < 16; blk += len)
#pragma unroll
      for (int j = 0; j < half; ++j)
        bfly_h<INV>(re[blk + j], im[blk + j], re[blk + j + half], im[blk + j + half], j * tstep);
  }
}

template<bool INV>
__device__ __forceinline__ void dft8h(h2* re, h2* im) {
  HSWAP(re, im, 1, 4) HSWAP(re, im, 3, 6)
#pragma unroll
  for (int ls = 1; ls <= 3; ++ls) {
    const int len = 1 << ls, half = len >> 1, tstep = 8 >> ls;
#pragma unroll
    for (int blk = 0; blk < 8; blk += len)
#pragma unroll
      for (int j = 0; j < half; ++j)
        bfly_h<INV>(re[blk + j], im[blk + j], re[blk + j + half], im[blk + j + half], j * tstep * 2);
  }
}

__device__ __forceinline__ void twmul_inv_h(h2* R, h2* I, const unsigned* twru, const unsigned* twiu) {
#pragma unroll
  for (int k = 1; k < 16; ++k) {
    const h2 wr = u2h(twru[k]), wi = u2h(twiu[k]);
    const h2 r = R[k] * wr + I[k] * wi;
    I[k] = I[k] * wr - R[k] * wi;
    R[k] = r;
  }
}
__device__ __forceinline__ void twmul_fwd_h(h2* R, h2* I, const unsigned* twru, const unsigned* twiu) {
#pragma unroll
  for (int k = 1; k < 16; ++k) {
    const h2 wr = u2h(twru[k]), wi = u2h(twiu[k]);
    const h2 r = R[k] * wr - I[k] * wi;
    I[k] = R[k] * wi + I[k] * wr;
    R[k] = r;
  }
}

// Row-pair dual-line inverse fft2 (r19/r20 verified). 4 barriers.
__device__ __forceinline__ void inv_rp_core(h2* R2, h2* I2, uint2* sU,
                                            int g, int q,
                                            const unsigned* twru, const unsigned* twiu) {
  const int sb = q * PITCH;
  dft8h<true>(R2, I2); dft8h<true>(R2 + 8, I2 + 8);
#pragma unroll
  for (int s = 0; s < 16; ++s) sU[sb + 16 * g + s] = make_uint2(h2u(R2[s]), h2u(I2[s]));
  __syncthreads();                             // B1
#pragma unroll
  for (int k = 0; k < 16; ++k) { const uint2 v = sU[sb + 8 * k + g]; R2[k] = u2h(v.x); I2[k] = u2h(v.y); }
  twmul_inv_h(R2, I2, twru, twiu);
  dft16h<true>(R2, I2);
#pragma unroll
  for (int m = 0; m < 16; ++m) sU[sb + g + 8 * m] = make_uint2(h2u(R2[m]), h2u(I2[m]));  // same cells
  __syncthreads();                             // B2
  {
    const int s_base = (16 * g) & 63;
    const unsigned sel = (g < 4) ? SEL_LO : SEL_HI;
#pragma unroll
    for (int j = 0; j < 16; ++j) {
      const int cb = (s_base + j) * PITCH;
      const uint2 vA = sU[cb + q];
      const uint2 vB = sU[cb + q + 64];
      R2[j] = u2h(__builtin_amdgcn_perm(vB.x, vA.x, sel));
      I2[j] = u2h(__builtin_amdgcn_perm(vB.y, vA.y, sel));
    }
  }
  dft8h<true>(R2, I2); dft8h<true>(R2 + 8, I2 + 8);
  __syncthreads();                             // B3
#pragma unroll
  for (int s = 0; s < 16; ++s) sU[sb + 16 * g + s] = make_uint2(h2u(R2[s]), h2u(I2[s]));
  __syncthreads();                             // B4
#pragma unroll
  for (int k = 0; k < 16; ++k) { const uint2 v = sU[sb + 8 * k + g]; R2[k] = u2h(v.x); I2[k] = u2h(v.y); }
  twmul_inv_h(R2, I2, twru, twiu);
  dft16h<true>(R2, I2);
}

// Row-pair dual-line FORWARD fft2 (r21 verified mirror). 4 barriers.
__device__ __forceinline__ void fwd_rp_core(h2* R2, h2* I2, uint2* sU,
                                            int g, int q,
                                            const unsigned* twru, const unsigned* twiu) {
  const int sb = q * PITCH;
  dft16h<false>(R2, I2);
  twmul_fwd_h(R2, I2, twru, twiu);
#pragma unroll
  for (int k = 0; k < 16; ++k) sU[sb + 8 * k + g] = make_uint2(h2u(R2[k]), h2u(I2[k]));
  __syncthreads();                             // B1
#pragma unroll
  for (int t = 0; t < 16; ++t) { const uint2 v = sU[sb + 16 * g + t]; R2[t] = u2h(v.x); I2[t] = u2h(v.y); }
  dft8h<false>(R2, I2); dft8h<false>(R2 + 8, I2 + 8);
#pragma unroll
  for (int t = 0; t < 16; ++t) sU[sb + 16 * g + t] = make_uint2(h2u(R2[t]), h2u(I2[t]));
  __syncthreads();                             // B2: all strips ready
  {
#pragma unroll
    for (int u = 0; u < 8; ++u) {
      const int cb = (g + 8 * u) * PITCH;
      const uint2 vA = sU[cb + q];
      const uint2 vB = sU[cb + q + 64];
      R2[u]     = u2h(__builtin_amdgcn_perm(vB.x, vA.x, SEL_LO));
      I2[u]     = u2h(__builtin_amdgcn_perm(vB.y, vA.y, SEL_LO));
      R2[u + 8] = u2h(__builtin_amdgcn_perm(vB.x, vA.x, SEL_HI));
      I2[u + 8] = u2h(__builtin_amdgcn_perm(vB.y, vA.y, SEL_HI));
    }
  }
  dft16h<false>(R2, I2);
  twmul_fwd_h(R2, I2, twru, twiu);
  __syncthreads();                             // B3: transpose reads drained
#pragma unroll
  for (int k = 0; k < 16; ++k) sU[sb + 8 * k + g] = make_uint2(h2u(R2[k]), h2u(I2[k]));
  __syncthreads();                             // B4
#pragma unroll
  for (int t = 0; t < 16; ++t) { const uint2 v = sU[sb + 16 * g + t]; R2[t] = u2h(v.x); I2[t] = u2h(v.y); }
  dft8h<false>(R2, I2); dft8h<false>(R2 + 8, I2 + 8);
}

template<int NW>
__device__ __forceinline__ float block_reduce_sum(float v, float* red, int tid) {
#pragma unroll
  for (int o = 32; o > 0; o >>= 1) v += __shfl_down(v, o);
  __syncthreads();
  if ((tid & 63) == 0) red[tid >> 6] = v;
  __syncthreads();
  float t = 0.0f;
  if (tid == 0) {
#pragma unroll
    for (int w = 0; w < NW; ++w) t += red[w];
  }
  return t;
}

// psi f32 granules (r5) + psih row-pair h2 cells for planes 4..23.
__global__ __launch_bounds__(256) void k_psi(const float* __restrict__ mags,
                                             const float* __restrict__ phases,
                                             float2* __restrict__ psi,
                                             float2* __restrict__ twg,
                                             uint2* __restrict__ psih,
                                             uint2* __restrict__ twgh) {
  if (blockIdx.x == 0 && threadIdx.x < 128) {
    const int gg = threadIdx.x >> 4, k = threadIdx.x & 15;
    float sn, cs;
    __sincosf(-TWO_PI * (float)(gg * k) * (1.0f / 128.0f), &sn, &cs);
    twg[threadIdx.x] = make_float2(cs, sn);
    twgh[threadIdx.x] = make_uint2(h2u(bch2(cs)), h2u(bch2(sn)));
  }
  const int gid = blockIdx.x * 256 + threadIdx.x;
  if (gid < 24 * PLANE) {                              // f32 psi (r5 granules)
    const int p = gid >> 14;
    const int rem = gid & (PLANE - 1);
    const int e = rem & 1;
    const int tt = (rem >> 1) & 1023;
    const int i = rem >> 11;
    const int j = 2 * i + e;
    const int g = tt >> 7, q = tt & 127;
    const int pr = 16 * g + j, pc = q;
    const int kr = (pr >> 3) + 16 * (pr & 7);
    const int kc = (pc >> 3) + 16 * (pc & 7);
    const int src = (p << 14) + kr * SDIM + kc;
    const float m = mags[src] * (1.0f / 16384.0f);
    float sn, cs;
    __sincosf(phases[src], &sn, &cs);
    psi[gid] = make_float2(m * cs, m * sn);
  } else if (gid < 24 * PLANE + 20 * 8192) {           // row-pair h2 psih
    const int c = gid - 24 * PLANE;
    const int pidx = c >> 13;
    const int rem = c & 8191;
    const int j = rem >> 9;
    const int t512 = rem & 511;
    const int g = t512 >> 6, q = t512 & 63;
    const int row = 16 * g + j;
    const int plane = pidx + 4;
    const int kr = (row >> 3) + 16 * (row & 7);
    const int kc0 = (q >> 3) + 16 * (q & 7);
    const int q1 = q + 64;
    const int kc1 = (q1 >> 3) + 16 * (q1 & 7);
    const int src0 = (plane << 14) + kr * SDIM + kc0;
    const int src1 = (plane << 14) + kr * SDIM + kc1;
    const float scl = PSIH_SCALE / 16384.0f;
    const float m0 = mags[src0] * scl;
    const float m1 = mags[src1] * scl;
    float sn0, cs0, sn1, cs1;
    __sincosf(phases[src0], &sn0, &cs0);
    __sincosf(phases[src1], &sn1, &cs1);
    psih[c] = make_uint2(h2u(mkh2(m0 * cs0, m1 * cs1)), h2u(mkh2(m0 * sn0, m1 * sn1)));
  }
}

// fp32 LDS; Xf granule layout; ~5 us.
__global__ __launch_bounds__(NT) void k_img_fft(const float* __restrict__ img,
                                                float2* __restrict__ Xf,
                                                float* __restrict__ s0,
                                                const float2* __restrict__ twg) {
  __shared__ float2 sC[SDIM * PITCH];
  __shared__ float red[16];
  const int tid = threadIdx.x, b = blockIdx.x;
  const int g = __builtin_amdgcn_readfirstlane(tid >> 7);
  const int q = tid & 127;
  float twr[16], twi[16];
  load_tw(twg, g, twr, twi);
  const float* ip = img + b * PLANE;
  float sum = 0.0f;
#pragma unroll
  for (int kk = 0; kk < 16; ++kk) {
    const int e = tid + kk * NT;
    const float v = ip[e];
    sC[(e >> 7) * PITCH + (e & 127)] = make_float2(v, 0.0f);
    sum += v;
  }
  const float tot = block_reduce_sum<16>(sum, red, tid);
  if (tid == 0) s0[b] = tot * (1.0f / 16384.0f);
  __syncthreads();
  float R[16], I[16];
#pragma unroll
  for (int m = 0; m < 16; ++m) { R[m] = sC[q * PITCH + g + 8 * m].x; I[m] = 0.0f; }
  fwd_fft2(R, I, sC, g, q, twr, twi);
  float4* x4 = (float4*)Xf + (size_t)b * 8192 + tid;
#pragma unroll
  for (int i = 0; i < 8; ++i)
    x4[i * 1024] = make_float4(R[2 * i], I[2 * i], R[2 * i + 1], I[2 * i + 1]);
}

// FUSED scattering: 1536 blocks x 512 thr, 66KB -> 2 blocks/CU.
// bid<1280 (j1=bid>>8, b, l1): cmul(X.psi) -> inv -> s1 -> fwd -> U in regs
// -> loop (5-j1)*4 psih planes with prefetch: cmul -> inv -> s2 per j2.
// bid>=1280: j=5 inverse + s1 only.
__global__ __launch_bounds__(512, 4) void k_scat_ab(const float2* __restrict__ Xf,
                                                    const float2* __restrict__ psi,
                                                    const uint2* __restrict__ psih,
                                                    float* __restrict__ s1num,
                                                    float* __restrict__ s2num,
                                                    const uint2* __restrict__ twgh) {
  __shared__ uint2 sU[64 * PITCH];             // 66,048 B
  __shared__ float red[8];
  const int tid = threadIdx.x;
  const int g = __builtin_amdgcn_readfirstlane(tid >> 6);
  const int q = tid & 63;
  unsigned twru[16], twiu[16];
  load_twh(twgh, g, twru, twiu);
  const int bid = blockIdx.x;

  int plane, b, sidx, j1 = -1;
  if (bid < 1280) {
    j1 = bid >> 8;                             // heavy j1=0 first
    b = (bid & 255) >> 2;
    const int l1 = bid & 3;
    plane = j1 * 4 + l1;
    sidx = b * 6 + j1;
  } else {
    const int idx = bid - 1280;
    b = idx >> 2;
    plane = 20 + (idx & 3);
    sidx = b * 6 + 5;
  }

  h2 R2[16], I2[16];
  {
    const int t0 = g * 128 + q;
    const float4* xL = (const float4*)Xf + (size_t)b * 8192 + t0;
    const float4* pL = (const float4*)psi + (size_t)plane * 8192 + t0;
#pragma unroll
    for (int i = 0; i < 8; ++i) {
      const float4 xa = xL[i * 1024],      va = pL[i * 1024];
      const float4 xb = xL[i * 1024 + 64], vb = pL[i * 1024 + 64];
      const float reL0 = xa.x * va.x - xa.y * va.y, imL0 = xa.x * va.y + xa.y * va.x;
      const float reH0 = xb.x * vb.x - xb.y * vb.y, imH0 = xb.x * vb.y + xb.y * vb.x;
      const float reL1 = xa.z * va.z - xa.w * va.w, imL1 = xa.z * va.w + xa.w * va.z;
      const float reH1 = xb.z * vb.z - xb.w * vb.w, imH1 = xb.z * vb.w + xb.w * vb.z;
      R2[2 * i]     = mkh2(reL0 * A_SCALE, reH0 * A_SCALE);
      I2[2 * i]     = mkh2(imL0 * A_SCALE, imH0 * A_SCALE);
      R2[2 * i + 1] = mkh2(reL1 * A_SCALE, reH1 * A_SCALE);
      I2[2 * i + 1] = mkh2(imL1 * A_SCALE, imH1 * A_SCALE);
    }
  }
  inv_rp_core(R2, I2, sU, g, q, twru, twiu);

  if (j1 < 0) {                                // j=5: s1 only
    float s1sum = 0.0f;
#pragma unroll
    for (int m = 0; m < 16; ++m) {
      const h2 sq = R2[m] * R2[m] + I2[m] * I2[m];
      s1sum += fast_sqrtf((float)sq.x) + fast_sqrtf((float)sq.y);
    }
    const float tot = block_reduce_sum<8>(s1sum, red, tid);
    if (tid == 0) atomicAdd(&s1num[sidx], tot);
    return;
  }

  float s1sum = 0.0f;
#pragma unroll
  for (int m = 0; m < 16; ++m) {
    const h2 sq = R2[m] * R2[m] + I2[m] * I2[m];
    const float aL = fast_sqrtf((float)sq.x);
    const float aH = fast_sqrtf((float)sq.y);
    s1sum += aL + aH;
    R2[m] = mkh2(aL * (1.0f / A_SCALE), aH * (1.0f / A_SCALE));
    I2[m] = bch2(0.0f);
  }
  fwd_rp_core(R2, I2, sU, g, q, twru, twiu);

  // U -> dedicated regs; prefetch first psih plane; s1 reduce (its barriers
  // also guarantee all fwd strip reads are globally done before loop writes).
  h2 UR2[16], UI2[16];
#pragma unroll
  for (int j = 0; j < 16; ++j) { UR2[j] = R2[j]; UI2[j] = I2[j]; }
  uint2 buf[16];
  {
    const uint2* ph = psih + (size_t)(4 * j1) * 8192 + tid;
#pragma unroll
    for (int j = 0; j < 16; ++j) buf[j] = ph[j * 512];
  }
  {
    const float tot = block_reduce_sum<8>(s1sum, red, tid);
    if (tid == 0) atomicAdd(&s1num[sidx], tot);
  }

  const int pb = (j1 * (11 - j1)) >> 1;
  const int nit = (5 - j1) * 4;
  float vsum = 0.0f;
  for (int it = 0; it < nit; ++it) {
#pragma unroll
    for (int j = 0; j < 16; ++j) {
      const h2 pr = u2h(buf[j].x), pi = u2h(buf[j].y);
      R2[j] = UR2[j] * pr - UI2[j] * pi;
      I2[j] = UR2[j] * pi + UI2[j] * pr;
    }
    if (it + 1 < nit) {                        // prefetch next plane
      const uint2* phn = psih + (size_t)(4 * j1 + it + 1) * 8192 + tid;
#pragma unroll
      for (int j = 0; j < 16; ++j) buf[j] = phn[j * 512];
    }
    __syncthreads();                           // prev strip reads drained
    inv_rp_core(R2, I2, sU, g, q, twru, twiu);
#pragma unroll
    for (int m = 0; m < 16; ++m) {
      const h2 sq = R2[m] * R2[m] + I2[m] * I2[m];
      vsum += fast_sqrtf((float)sq.x) + fast_sqrtf((float)sq.y);
    }
    if ((it & 3) == 3) {
      const float tot = block_reduce_sum<8>(vsum, red, tid);
      if (tid == 0) atomicAdd(&s2num[b * 15 + pb + (it >> 2)], tot);
      vsum = 0.0f;
    }
  }
}

// ---------------- tier-2 f32 kernels (r5 structure, Ubuf) ----------------
__global__ __launch_bounds__(NT) void k_scat_a(const float2* __restrict__ Xf,
                                               const float2* __restrict__ psi,
                                               float* __restrict__ s1num,
                                               unsigned* __restrict__ Ubuf,
                                               const float2* __restrict__ twg) {
  __shared__ unsigned sU[SDIM * PITCH];
  __shared__ float red[16];
  const int tid = threadIdx.x;
  const int g = __builtin_amdgcn_readfirstlane(tid >> 7);
  const int q = tid & 127;
  float twr[16], twi[16];
  load_tw(twg, g, twr, twi);
  const int bid = blockIdx.x;
  float R[16], I[16];

  if (bid < 1280) {
    const int j1 = bid >> 8;
    const int b = (bid & 255) >> 2;
    const int l1 = bid & 3;
    const float4* x4 = (const float4*)Xf + (size_t)b * 8192 + tid;
    const float4* p4 = (const float4*)psi + (size_t)(j1 * 4 + l1) * 8192 + tid;
#pragma unroll
    for (int i = 0; i < 8; ++i) {
      const float4 x = x4[i * 1024], v = p4[i * 1024];
      R[2 * i]     = x.x * v.x - x.y * v.y;  I[2 * i]     = x.x * v.y + x.y * v.x;
      R[2 * i + 1] = x.z * v.z - x.w * v.w;  I[2 * i + 1] = x.z * v.w + x.w * v.z;
    }
    inv_fft2<true>(R, I, sU, g, q, twr, twi);
    float s1sum = 0.0f;
#pragma unroll
    for (int m = 0; m < 16; ++m) {
      const float a = fast_sqrtf(R[m] * R[m] + I[m] * I[m]);
      s1sum += a; R[m] = a; I[m] = 0.0f;
    }
    fwd_fft2(R, I, sU, g, q, twr, twi);
    uint4 ob[4];
    unsigned* obs = (unsigned*)ob;
#pragma unroll
    for (int j = 0; j < 16; ++j) obs[j] = packbf(R[j], I[j]);
    uint4* o4 = (uint4*)Ubuf + (size_t)((b * 5 + j1) * 4 + l1) * 4096 + tid;
#pragma unroll
    for (int i = 0; i < 4; ++i) o4[i * 1024] = ob[i];
    const float tot = block_reduce_sum<16>(s1sum, red, tid);
    if (tid == 0) atomicAdd(&s1num[b * 6 + j1], tot);
  } else {
    const int idx = bid - 1280;
    const int b = idx >> 2, l = idx & 3;
    const float4* x4 = (const float4*)Xf + (size_t)b * 8192 + tid;
    const float4* p4 = (const float4*)psi + (size_t)(20 + l) * 8192 + tid;
#pragma unroll
    for (int i = 0; i < 8; ++i) {
      const float4 x = x4[i * 1024], v = p4[i * 1024];
      R[2 * i]     = x.x * v.x - x.y * v.y;  I[2 * i]     = x.x * v.y + x.y * v.x;
      R[2 * i + 1] = x.z * v.z - x.w * v.w;  I[2 * i + 1] = x.z * v.w + x.w * v.z;
    }
    inv_fft2<true>(R, I, sU, g, q, twr, twi);
    float s = 0.0f;
#pragma unroll
    for (int m = 0; m < 16; ++m) s += fast_sqrtf(R[m] * R[m] + I[m] * I[m]);
    const float tot = block_reduce_sum<16>(s, red, tid);
    if (tid == 0) atomicAdd(&s1num[b * 6 + 5], tot);
  }
}

__global__ __launch_bounds__(NT) void k_scat_b(const float2* __restrict__ psi,
                                               const unsigned* __restrict__ Ubuf,
                                               float* __restrict__ s2num,
                                               const float2* __restrict__ twg) {
  __shared__ unsigned sU[SDIM * PITCH];
  __shared__ float red[16];
  const int tid = threadIdx.x;
  const int g = __builtin_amdgcn_readfirstlane(tid >> 7);
  const int q = tid & 127;
  float twr[16], twi[16];
  load_tw(twg, g, twr, twi);
  int t = blockIdx.x;
  const int l2 = t & 3; t >>= 2;
  const int pair = t % 15; t /= 15;
  const int l1 = t & 3;
  const int b = t >> 2;
  int j1 = 0, base = 0;
  if (pair >= 14)      { j1 = 4; base = 14; }
  else if (pair >= 12) { j1 = 3; base = 12; }
  else if (pair >= 9)  { j1 = 2; base = 9; }
  else if (pair >= 5)  { j1 = 1; base = 5; }
  const int j2 = j1 + 1 + (pair - base);
  float R[16], I[16];
  {
    const uint4* u4 = (const uint4*)Ubuf + (size_t)((b * 5 + j1) * 4 + l1) * 4096 + tid;
    uint4 ub[4];
#pragma unroll
    for (int i = 0; i < 4; ++i) ub[i] = u4[i * 1024];
    const unsigned* ubs = (const unsigned*)ub;
    const float4* p4 = (const float4*)psi + (size_t)(j2 * 4 + l2) * 8192 + tid;
#pragma unroll
    for (int i = 0; i < 8; ++i) {
      const float4 v = p4[i * 1024];
      float ur, ui;
      unpackbf(ubs[2 * i], ur, ui);
      R[2 * i] = ur * v.x - ui * v.y;      I[2 * i] = ur * v.y + ui * v.x;
      unpackbf(ubs[2 * i + 1], ur, ui);
      R[2 * i + 1] = ur * v.z - ui * v.w;  I[2 * i + 1] = ur * v.w + ui * v.z;
    }
  }
  inv_fft2<true>(R, I, sU, g, q, twr, twi);
  float vsum = 0.0f;
#pragma unroll
  for (int m = 0; m < 16; ++m) vsum += fast_sqrtf(R[m] * R[m] + I[m] * I[m]);
  const float tot = block_reduce_sum<16>(vsum, red, tid);
  if (tid == 0) atomicAdd(&s2num[b * 15 + pair], tot);
}

// Fallback (ws tiny): monolithic; correctness only.
__global__ __launch_bounds__(NT) void k_scat_mono(const float2* __restrict__ Xf,
                                                  const float2* __restrict__ psi,
                                                  float* __restrict__ s1num,
                                                  float* __restrict__ s2num,
                                                  const float2* __restrict__ twg) {
  __shared__ unsigned sU[SDIM * PITCH];
  __shared__ float red[16];
  const int tid = threadIdx.x;
  const int g = __builtin_amdgcn_readfirstlane(tid >> 7);
  const int q = tid & 127;
  float twr[16], twi[16];
  load_tw(twg, g, twr, twi);
  const int bid = blockIdx.x;
  float R[16], I[16];
  if (bid < 1280) {
    const int j1 = bid >> 8;
    const int b = (bid & 255) >> 2;
    const int l1 = bid & 3;
    const float4* x4 = (const float4*)Xf + (size_t)b * 8192 + tid;
    const float4* p4 = (const float4*)psi + (size_t)(j1 * 4 + l1) * 8192 + tid;
#pragma unroll
    for (int i = 0; i < 8; ++i) {
      const float4 x = x4[i * 1024], v = p4[i * 1024];
      R[2 * i]     = x.x * v.x - x.y * v.y;  I[2 * i]     = x.x * v.y + x.y * v.x;
      R[2 * i + 1] = x.z * v.z - x.w * v.w;  I[2 * i + 1] = x.z * v.w + x.w * v.z;
    }
    inv_fft2<true>(R, I, sU, g, q, twr, twi);
    float s1sum = 0.0f;
#pragma unroll
    for (int m = 0; m < 16; ++m) {
      const float a = fast_sqrtf(R[m] * R[m] + I[m] * I[m]);
      s1sum += a; R[m] = a; I[m] = 0.0f;
    }
    fwd_fft2(R, I, sU, g, q, twr, twi);
    float Ur[16], Ui[16];
#pragma unroll
    for (int k = 0; k < 16; ++k) { Ur[k] = R[k]; Ui[k] = I[k]; }
    {
      const float tot = block_reduce_sum<16>(s1sum, red, tid);
      if (tid == 0) atomicAdd(&s1num[b * 6 + j1], tot);
    }
    const int pb = (j1 * (11 - j1)) >> 1;
    int plane = (j1 + 1) * 4;
#pragma unroll 1
    for (int j2 = j1 + 1; j2 <= 5; ++j2) {
      float vsum = 0.0f;
#pragma unroll 1
      for (int l2 = 0; l2 < 4; ++l2) {
        const float4* q4 = (const float4*)psi + (size_t)plane * 8192 + tid;
#pragma unroll
        for (int i = 0; i < 8; ++i) {
          const float4 v = q4[i * 1024];
          R[2 * i]     = Ur[2 * i] * v.x - Ui[2 * i] * v.y;
          I[2 * i]     = Ur[2 * i] * v.y + Ui[2 * i] * v.x;
          R[2 * i + 1] = Ur[2 * i + 1] * v.z - Ui[2 * i + 1] * v.w;
          I[2 * i + 1] = Ur[2 * i + 1] * v.w + Ui[2 * i + 1] * v.z;
        }
        inv_fft2<false>(R, I, sU, g, q, twr, twi);
#pragma unroll
        for (int m = 0; m < 16; ++m) vsum += fast_sqrtf(R[m] * R[m] + I[m] * I[m]);
        ++plane;
      }
      const float tot = block_reduce_sum<16>(vsum, red, tid);
      if (tid == 0) atomicAdd(&s2num[b * 15 + pb + (j2 - j1 - 1)], tot);
    }
  } else {
    const int idx = bid - 1280;
    const int b = idx >> 2, l = idx & 3;
    const float4* x4 = (const float4*)Xf + (size_t)b * 8192 + tid;
    const float4* p4 = (const float4*)psi + (size_t)(20 + l) * 8192 + tid;
#pragma unroll
    for (int i = 0; i < 8; ++i) {
      const float4 x = x4[i * 1024], v = p4[i * 1024];
      R[2 * i]     = x.x * v.x - x.y * v.y;  I[2 * i]     = x.x * v.y + x.y * v.x;
      R[2 * i + 1] = x.z * v.z - x.w * v.w;  I[2 * i + 1] = x.z * v.w + x.w * v.z;
    }
    inv_fft2<true>(R, I, sU, g, q, twr, twi);
    float s = 0.0f;
#pragma unroll
    for (int m = 0; m < 16; ++m) s += fast_sqrtf(R[m] * R[m] + I[m] * I[m]);
    const float tot = block_reduce_sum<16>(s, red, tid);
    if (tid == 0) atomicAdd(&s1num[b * 6 + 5], tot);
  }
}

__global__ __launch_bounds__(64) void k_final(const float* __restrict__ s0,
                                              const float* __restrict__ s1num,
                                              const float* __restrict__ s2num,
                                              const float* __restrict__ w1,
                                              const float* __restrict__ b1,
                                              const float* __restrict__ w2,
                                              const float* __restrict__ b2,
                                              const float* __restrict__ w3,
                                              const float* __restrict__ b3,
                                              float* __restrict__ out,
                                              float s1scale, float s2scale) {
  const int b = threadIdx.x;
  if (b >= 64) return;
  float x[22];
  x[0] = s0[b];
#pragma unroll
  for (int j = 0; j < 6; ++j) x[1 + j] = s1num[b * 6 + j] * s1scale;
#pragma unroll
  for (int p = 0; p < 15; ++p) x[7 + p] = s2num[b * 15 + p] * s2scale;
  float h1[16];
#pragma unroll
  for (int o = 0; o < 16; ++o) {
    float t = b1[o];
    for (int i = 0; i < 22; ++i) t += x[i] * w1[i * 16 + o];
    h1[o] = fmaxf(t, 0.0f);
  }
  float h2a[16];
#pragma unroll
  for (int o = 0; o < 16; ++o) {
    float t = b2[o];
    for (int i = 0; i < 16; ++i) t += h1[i] * w2[i * 16 + o];
    h2a[o] = fmaxf(t, 0.0f);
  }
  float t = b3[0];
#pragma unroll
  for (int i = 0; i < 16; ++i) t += h2a[i] * w3[i];
  out[b] = 1.0f / (1.0f + expf(-t));
}

extern "C" void kernel_launch(void* const* d_in, const int* in_sizes, int n_in,
                              void* d_out, int out_size, void* d_ws, size_t ws_size,
                              hipStream_t stream) {
  (void)in_sizes; (void)n_in; (void)out_size;
  const float* image  = (const float*)d_in[0];
  const float* mags   = (const float*)d_in[1];
  const float* phases = (const float*)d_in[2];
  const float* w1 = (const float*)d_in[3];
  const float* b1 = (const float*)d_in[4];
  const float* w2 = (const float*)d_in[5];
  const float* b2 = (const float*)d_in[6];
  const float* w3 = (const float*)d_in[7];
  const float* b3 = (const float*)d_in[8];
  float* out = (float*)d_out;

  char* ws = (char*)d_ws;
  float2* psi = (float2*)ws;                       // 3,145,728 B
  float2* Xf  = (float2*)(ws + 3145728);           // 8,388,608 B
  float*  s0  = (float*)(ws + 11534336);           // 64
  float*  s1n = s0 + 64;                           // 384
  float*  s2n = s1n + 384;                         // 960
  float2* twg = (float2*)(s2n + 960);              // 128 float2 (1024 B)
  uint2*  twgh = (uint2*)((char*)twg + 1024);      // 128 uint2 (1024 B)
  unsigned* Ubuf = (unsigned*)(ws + 11542528);     // 83,886,080 B (tier-2 only)
  uint2*  psih = (uint2*)(ws + 95428608);          // 1,310,720 B (20 planes)
  const size_t need_r5 = 11542528ull + 83886080ull;          // 95,428,608
  const size_t need_h2 = need_r5 + 1310720ull;               // 96,739,328

  hipMemsetAsync(s1n, 0, (384 + 960) * sizeof(float), stream);
  if (ws_size >= need_h2) {
    k_psi<<<dim3(2176), dim3(256), 0, stream>>>(mags, phases, psi, twg, psih, twgh);
    k_img_fft<<<dim3(64), dim3(NT), 0, stream>>>(image, Xf, s0, twg);
    k_scat_ab<<<dim3(1536), dim3(512), 0, stream>>>(Xf, psi, psih, s1n, s2n, twgh);
    k_final<<<dim3(1), dim3(64), 0, stream>>>(s0, s1n, s2n, w1, b1, w2, b2, w3, b3, out,
                                              1.0f / (4.0f * 16384.0f * A_SCALE),
                                              1.0f / (16.0f * 16384.0f * PSIH_SCALE));
  } else if (ws_size >= need_r5) {
    k_psi<<<dim3(1536), dim3(256), 0, stream>>>(mags, phases, psi, twg, psih, twgh);
    k_img_fft<<<dim3(64), dim3(NT), 0, stream>>>(image, Xf, s0, twg);
    k_scat_a<<<dim3(1536), dim3(NT), 0, stream>>>(Xf, psi, s1n, Ubuf, twg);
    k_scat_b<<<dim3(15360), dim3(NT), 0, stream>>>(psi, Ubuf, s2n, twg);
    k_final<<<dim3(1), dim3(64), 0, stream>>>(s0, s1n, s2n, w1, b1, w2, b2, w3, b3, out,
                                              1.0f / (4.0f * 16384.0f),
                                              1.0f / (16.0f * 16384.0f));
  } else {
    k_psi<<<dim3(1536), dim3(256), 0, stream>>>(mags, phases, psi, twg, psih, twgh);
    k_img_fft<<<dim3(64), dim3(NT), 0, stream>>>(image, Xf, s0, twg);
    k_scat_mono<<<dim3(1536), dim3(NT), 0, stream>>>(Xf, psi, s1n, s2n, twg);
    k_final<<<dim3(1), dim3(64), 0, stream>>>(s0, s1n, s2n, w1, b1, w2, b2, w3, b3, out,
                                              1.0f / (4.0f * 16384.0f),
                                              1.0f / (16.0f * 16384.0f));
  }
}

// Round 12
// 414.922 us; speedup vs baseline: 1.4301x; 1.0238x over previous
//
#include <hip/hip_runtime.h>
#include <math.h>

// Scattering net: four-step register FFT, row-pair f16 fused pipeline.
//
// Round-23: 3-DISPATCH PIPELINE. r22's fused scat_ab sits at ~79% VALU-issue
// (4 waves/SIMD); the cheap target is the ~88us OUTSIDE it: ~6 dispatch
// boundaries (~8-10us each) + psi f32 table nobody needs anymore. Changes:
// (1) psih extended to all 24 planes (1.5MB); scat_ab's first cmul runs in h2
//     (X cvt via mkh2/pkrtz; psih carries x16 = A_SCALE). f32 psi deleted.
// (2) k_pre merges psi+img+zeroing: blocks 0..191 fill psih (block 0 also
//     writes twgh + zeros s1/s2 -> memset dispatch gone); blocks 192..255 run
//     the image FFT with a self-contained LDS twiddle table (readfirstlane ->
//     SGPRs after the reduce barriers; reuses fwd_fft2 unchanged; no cross-
//     block dependency).
// (3) k_scat_ab: loader switch only; verified cores byte-identical.
// h2 tier needs only ~11.5MB ws; mono fallback kept.

#define SDIM 128
#define PLANE 16384
#define PITCH 129
#define NT 1024
#define TWO_PI 6.28318530717958647692f
#define PSIH_SCALE 16.0f
#define A_SCALE 16.0f

typedef _Float16 h2 __attribute__((ext_vector_type(2)));

constexpr float W16R[8] = {1.f, 0.9238795325f, 0.7071067812f, 0.3826834324f,
                           0.f, -0.3826834324f, -0.7071067812f, -0.9238795325f};
constexpr float W16I[8] = {0.f, -0.3826834324f, -0.7071067812f, -0.9238795325f,
                           -1.f, -0.9238795325f, -0.7071067812f, -0.3826834324f};

__device__ __forceinline__ float fast_sqrtf(float x) { return __builtin_amdgcn_sqrtf(x); }

// ---- h2 helpers ----
union UHU { unsigned u; h2 h; };
__device__ __forceinline__ h2 u2h(unsigned u) { UHU x; x.u = u; return x.h; }
__device__ __forceinline__ unsigned h2u(h2 h) { UHU x; x.h = h; return x.u; }
__device__ __forceinline__ h2 bch2(float f) { const _Float16 h = (_Float16)f; h2 v = {h, h}; return v; }
__device__ __forceinline__ h2 mkh2(float a, float b) { h2 v = {(_Float16)a, (_Float16)b}; return v; }

#define SEL_LO 0x05040100u
#define SEL_HI 0x07060302u

// wave-uniform twiddle tables -> SGPRs.
__device__ __forceinline__ void load_twh(const uint2* __restrict__ twgh, int g,
                                         unsigned* twru, unsigned* twiu) {
#pragma unroll
  for (int k = 1; k < 16; ++k) {
    const uint2 w = twgh[16 * g + k];
    twru[k] = (unsigned)__builtin_amdgcn_readfirstlane((int)w.x);
    twiu[k] = (unsigned)__builtin_amdgcn_readfirstlane((int)w.y);
  }
}

// ---------------- f32 FFT core (r5, known-good; img + mono) ----------------
template<bool INV>
__device__ __forceinline__ void bfly(float& ar, float& ai, float& br, float& bi, const int idx) {
  float tr, ti;
  if (idx == 0) { tr = br; ti = bi; }
  else if (idx == 4) {
    if (INV) { tr = -bi; ti = br; } else { tr = bi; ti = -br; }
  } else {
    const float wr = W16R[idx];
    const float wi = INV ? -W16I[idx] : W16I[idx];
    tr = br * wr - bi * wi;
    ti = br * wi + bi * wr;
  }
  br = ar - tr; bi = ai - ti;
  ar = ar + tr; ai = ai + ti;
}

#define CSWAP(re, im, a, b) { float _t = re[a]; re[a]=re[b]; re[b]=_t; _t = im[a]; im[a]=im[b]; im[b]=_t; }

template<bool INV>
__device__ __forceinline__ void dft16(float* re, float* im) {
  CSWAP(re, im, 1, 8) CSWAP(re, im, 2, 4) CSWAP(re, im, 3, 12)
  CSWAP(re, im, 5, 10) CSWAP(re, im, 7, 14) CSWAP(re, im, 11, 13)
#pragma unroll
  for (int ls = 1; ls <= 4; ++ls) {
    const int len = 1 << ls, half = len >> 1, tstep = 16 >> ls;
#pragma unroll
    for (int blk = 0; blk < 16; blk += len)
#pragma unroll
      for (int j = 0; j < half; ++j)
        bfly<INV>(re[blk + j], im[blk + j], re[blk + j + half], im[blk + j + half], j * tstep);
  }
}

template<bool INV>
__device__ __forceinline__ void dft8(float* re, float* im) {
  CSWAP(re, im, 1, 4) CSWAP(re, im, 3, 6)
#pragma unroll
  for (int ls = 1; ls <= 3; ++ls) {
    const int len = 1 << ls, half = len >> 1, tstep = 8 >> ls;
#pragma unroll
    for (int blk = 0; blk < 8; blk += len)
#pragma unroll
      for (int j = 0; j < half; ++j)
        bfly<INV>(re[blk + j], im[blk + j], re[blk + j + half], im[blk + j + half], j * tstep * 2);
  }
}

__device__ __forceinline__ void twmul_fwd(float* R, float* I, const float* twr, const float* twi) {
#pragma unroll
  for (int k = 1; k < 16; ++k) {
    const float r = R[k] * twr[k] - I[k] * twi[k];
    I[k] = R[k] * twi[k] + I[k] * twr[k]; R[k] = r;
  }
}
__device__ __forceinline__ void twmul_inv(float* R, float* I, const float* twr, const float* twi) {
#pragma unroll
  for (int k = 1; k < 16; ++k) {
    const float r = R[k] * twr[k] + I[k] * twi[k];
    I[k] = I[k] * twr[k] - R[k] * twi[k]; R[k] = r;
  }
}

template<typename S>
__device__ __forceinline__ void stC(S* s, int idx, float re, float im) { s[idx] = make_float2(re, im); }
__device__ __forceinline__ void ldC(const float2* s, int idx, float& re, float& im) { const float2 v = s[idx]; re = v.x; im = v.y; }

template<typename S>
__device__ __forceinline__ void fwd_fft2(float* R, float* I, S* sC,
                                         int g, int q, const float* twr, const float* twi) {
  const int rb = q * PITCH;
  dft16<false>(R, I);
  twmul_fwd(R, I, twr, twi);
  __syncthreads();                             // B0
#pragma unroll
  for (int k = 0; k < 16; ++k) stC(sC, rb + 8 * k + g, R[k], I[k]);
  __syncthreads();                             // B1
#pragma unroll
  for (int t = 0; t < 8; ++t) {
    ldC(sC, rb + 16 * g + t, R[t], I[t]);
    ldC(sC, rb + 16 * g + 8 + t, R[8 + t], I[8 + t]);
  }
  dft8<false>(R, I); dft8<false>(R + 8, I + 8);
#pragma unroll
  for (int k2 = 0; k2 < 8; ++k2) {
    stC(sC, rb + 16 * g + k2, R[k2], I[k2]);
    stC(sC, rb + 16 * g + 8 + k2, R[8 + k2], I[8 + k2]);
  }
  __syncthreads();                             // B2
#pragma unroll
  for (int m = 0; m < 16; ++m) ldC(sC, (g + 8 * m) * PITCH + q, R[m], I[m]);
  dft16<false>(R, I);
  twmul_fwd(R, I, twr, twi);
#pragma unroll
  for (int k = 0; k < 16; ++k) stC(sC, (8 * k + g) * PITCH + q, R[k], I[k]);
  __syncthreads();                             // B3
#pragma unroll
  for (int u = 0; u < 8; ++u) {
    const int bp = (16 * g + 2 * u) * PITCH + q;
    ldC(sC, bp, R[2 * u], I[2 * u]);
    ldC(sC, bp + PITCH, R[2 * u + 1], I[2 * u + 1]);
  }
  dft8<false>(R, I); dft8<false>(R + 8, I + 8);
}

template<bool FIRST, typename S>
__device__ __forceinline__ void inv_fft2(float* R, float* I, S* sC,
                                         int g, int q, const float* twr, const float* twi) {
  const int rb = q * PITCH;
  dft8<true>(R, I); dft8<true>(R + 8, I + 8);
  if constexpr (!FIRST) __syncthreads();       // B0
#pragma unroll
  for (int t = 0; t < 16; ++t) stC(sC, rb + 16 * g + t, R[t], I[t]);
  __syncthreads();                             // B1
#pragma unroll
  for (int k = 0; k < 16; ++k) ldC(sC, rb + 8 * k + g, R[k], I[k]);
  twmul_inv(R, I, twr, twi);
  dft16<true>(R, I);
#pragma unroll
  for (int m = 0; m < 16; ++m) stC(sC, rb + g + 8 * m, R[m], I[m]);
  __syncthreads();                             // B2
#pragma unroll
  for (int u = 0; u < 8; ++u) {
    const int bp = (16 * g + 2 * u) * PITCH + q;
    ldC(sC, bp, R[2 * u], I[2 * u]);
    ldC(sC, bp + PITCH, R[2 * u + 1], I[2 * u + 1]);
  }
  dft8<true>(R, I); dft8<true>(R + 8, I + 8);
#pragma unroll
  for (int u = 0; u < 8; ++u) {
    const int bp = (16 * g + 2 * u) * PITCH + q;
    stC(sC, bp, R[2 * u], I[2 * u]);
    stC(sC, bp + PITCH, R[2 * u + 1], I[2 * u + 1]);
  }
  __syncthreads();                             // B3
#pragma unroll
  for (int k = 0; k < 16; ++k) ldC(sC, (8 * k + g) * PITCH + q, R[k], I[k]);
  twmul_inv(R, I, twr, twi);
  dft16<true>(R, I);
}

// ---------------- h2 FFT core (verified r19-r22) ----------------
template<bool INV>
__device__ __forceinline__ void bfly_h(h2& ar, h2& ai, h2& br, h2& bi, const int idx) {
  h2 tr, ti;
  if (idx == 0) { tr = br; ti = bi; }
  else if (idx == 4) {
    if (INV) { tr = -bi; ti = br; } else { tr = bi; ti = -br; }
  } else {
    const h2 wr = bch2(W16R[idx]);
    const h2 wi = bch2(INV ? -W16I[idx] : W16I[idx]);
    tr = br * wr - bi * wi;
    ti = br * wi + bi * wr;
  }
  br = ar - tr; bi = ai - ti;
  ar = ar + tr; ai = ai + ti;
}

#define HSWAP(re, im, a, b) { h2 _t = re[a]; re[a]=re[b]; re[b]=_t; _t = im[a]; im[a]=im[b]; im[b]=_t; }

template<bool INV>
__device__ __forceinline__ void dft16h(h2* re, h2* im) {
  HSWAP(re, im, 1, 8) HSWAP(re, im, 2, 4) HSWAP(re, im, 3, 12)
  HSWAP(re, im, 5, 10) HSWAP(re, im, 7, 14) HSWAP(re, im, 11, 13)
#pragma unroll
  for (int ls = 1; ls <= 4; ++ls) {
    const int len = 1 << ls, half = len >> 1, tstep = 16 >> ls;
#pragma unroll
    for (int blk = 0; blk < 16; blk += len)
#pragma unroll
      for (int j = 0; j < half; ++j)
        bfly_h<INV>(re[blk + j], im[blk + j], re[blk + j + half], im[blk + j + half], j * tstep);
  }
}

template<bool INV>
__device__ __forceinline__ void dft8h(h2* re, h2* im) {
  HSWAP(re, im, 1, 4) HSWAP(re, im, 3, 6)
#pragma unroll
  for (int ls = 1; ls <= 3; ++ls) {
    const int len = 1 << ls, half = len >> 1, tstep = 8 >> ls;
#pragma unroll
    for (int blk = 0; blk < 8; blk += len)
#pragma unroll
      for (int j = 0; j < half; ++j)
        bfly_h<INV>(re[blk + j], im[blk + j], re[blk + j + half], im[blk + j + half], j * tstep * 2);
  }
}

__device__ __forceinline__ void twmul_inv_h(h2* R, h2* I, const unsigned* twru, const unsigned* twiu) {
#pragma unroll
  for (int k = 1; k < 16; ++k) {
    const h2 wr = u2h(twru[k]), wi = u2h(twiu[k]);
    const h2 r = R[k] * wr + I[k] * wi;
    I[k] = I[k] * wr - R[k] * wi;
    R[k] = r;
  }
}
__device__ __forceinline__ void twmul_fwd_h(h2* R, h2* I, const unsigned* twru, const unsigned* twiu) {
#pragma unroll
  for (int k = 1; k < 16; ++k) {
    const h2 wr = u2h(twru[k]), wi = u2h(twiu[k]);
    const h2 r = R[k] * wr - I[k] * wi;
    I[k] = R[k] * wi + I[k] * wr;
    R[k] = r;
  }
}

// Row-pair dual-line inverse fft2 (verified). 4 barriers.
__device__ __forceinline__ void inv_rp_core(h2* R2, h2* I2, uint2* sU,
                                            int g, int q,
                                            const unsigned* twru, const unsigned* twiu) {
  const int sb = q * PITCH;
  dft8h<true>(R2, I2); dft8h<true>(R2 + 8, I2 + 8);
#pragma unroll
  for (int s = 0; s < 16; ++s) sU[sb + 16 * g + s] = make_uint2(h2u(R2[s]), h2u(I2[s]));
  __syncthreads();                             // B1
#pragma unroll
  for (int k = 0; k < 16; ++k) { const uint2 v = sU[sb + 8 * k + g]; R2[k] = u2h(v.x); I2[k] = u2h(v.y); }
  twmul_inv_h(R2, I2, twru, twiu);
  dft16h<true>(R2, I2);
#pragma unroll
  for (int m = 0; m < 16; ++m) sU[sb + g + 8 * m] = make_uint2(h2u(R2[m]), h2u(I2[m]));  // same cells
  __syncthreads();                             // B2
  {
    const int s_base = (16 * g) & 63;
    const unsigned sel = (g < 4) ? SEL_LO : SEL_HI;
#pragma unroll
    for (int j = 0; j < 16; ++j) {
      const int cb = (s_base + j) * PITCH;
      const uint2 vA = sU[cb + q];
      const uint2 vB = sU[cb + q + 64];
      R2[j] = u2h(__builtin_amdgcn_perm(vB.x, vA.x, sel));
      I2[j] = u2h(__builtin_amdgcn_perm(vB.y, vA.y, sel));
    }
  }
  dft8h<true>(R2, I2); dft8h<true>(R2 + 8, I2 + 8);
  __syncthreads();                             // B3
#pragma unroll
  for (int s = 0; s < 16; ++s) sU[sb + 16 * g + s] = make_uint2(h2u(R2[s]), h2u(I2[s]));
  __syncthreads();                             // B4
#pragma unroll
  for (int k = 0; k < 16; ++k) { const uint2 v = sU[sb + 8 * k + g]; R2[k] = u2h(v.x); I2[k] = u2h(v.y); }
  twmul_inv_h(R2, I2, twru, twiu);
  dft16h<true>(R2, I2);
}

// Row-pair dual-line FORWARD fft2 (verified mirror). 4 barriers.
__device__ __forceinline__ void fwd_rp_core(h2* R2, h2* I2, uint2* sU,
                                            int g, int q,
                                            const unsigned* twru, const unsigned* twiu) {
  const int sb = q * PITCH;
  dft16h<false>(R2, I2);
  twmul_fwd_h(R2, I2, twru, twiu);
#pragma unroll
  for (int k = 0; k < 16; ++k) sU[sb + 8 * k + g] = make_uint2(h2u(R2[k]), h2u(I2[k]));
  __syncthreads();                             // B1
#pragma unroll
  for (int t = 0; t < 16; ++t) { const uint2 v = sU[sb + 16 * g + t]; R2[t] = u2h(v.x); I2[t] = u2h(v.y); }
  dft8h<false>(R2, I2); dft8h<false>(R2 + 8, I2 + 8);
#pragma unroll
  for (int t = 0; t < 16; ++t) sU[sb + 16 * g + t] = make_uint2(h2u(R2[t]), h2u(I2[t]));
  __syncthreads();                             // B2: all strips ready
  {
#pragma unroll
    for (int u = 0; u < 8; ++u) {
      const int cb = (g + 8 * u) * PITCH;
      const uint2 vA = sU[cb + q];
      const uint2 vB = sU[cb + q + 64];
      R2[u]     = u2h(__builtin_amdgcn_perm(vB.x, vA.x, SEL_LO));
      I2[u]     = u2h(__builtin_amdgcn_perm(vB.y, vA.y, SEL_LO));
      R2[u + 8] = u2h(__builtin_amdgcn_perm(vB.x, vA.x, SEL_HI));
      I2[u + 8] = u2h(__builtin_amdgcn_perm(vB.y, vA.y, SEL_HI));
    }
  }
  dft16h<false>(R2, I2);
  twmul_fwd_h(R2, I2, twru, twiu);
  __syncthreads();                             // B3: transpose reads drained
#pragma unroll
  for (int k = 0; k < 16; ++k) sU[sb + 8 * k + g] = make_uint2(h2u(R2[k]), h2u(I2[k]));
  __syncthreads();                             // B4
#pragma unroll
  for (int t = 0; t < 16; ++t) { const uint2 v = sU[sb + 16 * g + t]; R2[t] = u2h(v.x); I2[t] = u2h(v.y); }
  dft8h<false>(R2, I2); dft8h<false>(R2 + 8, I2 + 8);
}

template<int NW>
__device__ __forceinline__ float block_reduce_sum(float v, float* red, int tid) {
#pragma unroll
  for (int o = 32; o > 0; o >>= 1) v += __shfl_down(v, o);
  __syncthreads();
  if ((tid & 63) == 0) red[tid >> 6] = v;
  __syncthreads();
  float t = 0.0f;
  if (tid == 0) {
#pragma unroll
    for (int w = 0; w < NW; ++w) t += red[w];
  }
  return t;
}

// k_pre: 256 blocks x 1024 threads.
// bid<192: psih cells (24 planes x 8192), x16 scale. Block 0 also writes twgh
//          and zeros s1n..s2n (1344 floats).
// bid>=192: image FFT for b = bid-192, with self-contained LDS twiddle table
//           -> Xf granules + s0. (133KB LDS -> 1 block/CU; 256 blocks = 1 wave.)
__global__ __launch_bounds__(NT) void k_pre(const float* __restrict__ mags,
                                            const float* __restrict__ phases,
                                            const float* __restrict__ img,
                                            uint2* __restrict__ psih,
                                            uint2* __restrict__ twgh,
                                            float2* __restrict__ Xf,
                                            float* __restrict__ s0,
                                            float* __restrict__ s1n) {
  __shared__ float2 sC[SDIM * PITCH];
  __shared__ float2 sTw[128];
  __shared__ float red[16];
  const int bid = blockIdx.x, tid = threadIdx.x;

  if (bid < 192) {
    if (bid == 0) {
      if (tid < 128) {
        const int gg = tid >> 4, k = tid & 15;
        float sn, cs;
        __sincosf(-TWO_PI * (float)(gg * k) * (1.0f / 128.0f), &sn, &cs);
        twgh[tid] = make_uint2(h2u(bch2(cs)), h2u(bch2(sn)));
      }
      for (int t = tid; t < 1344; t += NT) s1n[t] = 0.0f;   // s1(384)+s2(960)
    }
    const int c = bid * NT + tid;              // < 24*8192
    const int pidx = c >> 13;                  // plane 0..23
    const int rem = c & 8191;
    const int j = rem >> 9;
    const int t512 = rem & 511;
    const int g = t512 >> 6, q = t512 & 63;
    const int row = 16 * g + j;
    const int kr = (row >> 3) + 16 * (row & 7);
    const int kc0 = (q >> 3) + 16 * (q & 7);
    const int q1 = q + 64;
    const int kc1 = (q1 >> 3) + 16 * (q1 & 7);
    const int src0 = (pidx << 14) + kr * SDIM + kc0;
    const int src1 = (pidx << 14) + kr * SDIM + kc1;
    const float scl = PSIH_SCALE / 16384.0f;
    const float m0 = mags[src0] * scl;
    const float m1 = mags[src1] * scl;
    float sn0, cs0, sn1, cs1;
    __sincosf(phases[src0], &sn0, &cs0);
    __sincosf(phases[src1], &sn1, &cs1);
    psih[c] = make_uint2(h2u(mkh2(m0 * cs0, m1 * cs1)), h2u(mkh2(m0 * sn0, m1 * sn1)));
    return;
  }

  // ---- image FFT ----
  const int b = bid - 192;
  const int g = __builtin_amdgcn_readfirstlane(tid >> 7);
  const int q = tid & 127;
  if (tid < 128) {                             // LDS twiddle table
    const int gg = tid >> 4, k = tid & 15;
    float sn, cs;
    __sincosf(-TWO_PI * (float)(gg * k) * (1.0f / 128.0f), &sn, &cs);
    sTw[tid] = make_float2(cs, sn);
  }
  const float* ip = img + b * PLANE;
  float sum = 0.0f;
#pragma unroll
  for (int kk = 0; kk < 16; ++kk) {
    const int e = tid + kk * NT;
    const float v = ip[e];
    sC[(e >> 7) * PITCH + (e & 127)] = make_float2(v, 0.0f);
    sum += v;
  }
  const float tot = block_reduce_sum<16>(sum, red, tid);  // barriers publish sC & sTw
  if (tid == 0) s0[b] = tot * (1.0f / 16384.0f);
  __syncthreads();
  float twr[16], twi[16];
#pragma unroll
  for (int k = 1; k < 16; ++k) {
    const float2 w = sTw[16 * g + k];
    twr[k] = __uint_as_float(__builtin_amdgcn_readfirstlane(__float_as_uint(w.x)));
    twi[k] = __uint_as_float(__builtin_amdgcn_readfirstlane(__float_as_uint(w.y)));
  }
  float R[16], I[16];
#pragma unroll
  for (int m = 0; m < 16; ++m) { R[m] = sC[q * PITCH + g + 8 * m].x; I[m] = 0.0f; }
  fwd_fft2(R, I, sC, g, q, twr, twi);
  float4* x4 = (float4*)Xf + (size_t)b * 8192 + tid;
#pragma unroll
  for (int i = 0; i < 8; ++i)
    x4[i * 1024] = make_float4(R[2 * i], I[2 * i], R[2 * i + 1], I[2 * i + 1]);
}

// FUSED scattering: 1536 blocks x 512 thr, 66KB -> 2 blocks/CU.
// bid<1280 (j1=bid>>8, b, l1): h2-cmul(X.psih) -> inv -> s1 -> fwd -> U in
// regs -> loop (5-j1)*4 psih planes (index 4j1+4+it) with prefetch.
// bid>=1280: j=5 inverse + s1 only.
__global__ __launch_bounds__(512, 4) void k_scat_ab(const float2* __restrict__ Xf,
                                                    const uint2* __restrict__ psih,
                                                    float* __restrict__ s1num,
                                                    float* __restrict__ s2num,
                                                    const uint2* __restrict__ twgh) {
  __shared__ uint2 sU[64 * PITCH];             // 66,048 B
  __shared__ float red[8];
  const int tid = threadIdx.x;
  const int g = __builtin_amdgcn_readfirstlane(tid >> 6);
  const int q = tid & 63;
  unsigned twru[16], twiu[16];
  load_twh(twgh, g, twru, twiu);
  const int bid = blockIdx.x;

  int plane, b, sidx, j1 = -1;
  if (bid < 1280) {
    j1 = bid >> 8;                             // heavy j1=0 first
    b = (bid & 255) >> 2;
    const int l1 = bid & 3;
    plane = j1 * 4 + l1;
    sidx = b * 6 + j1;
  } else {
    const int idx = bid - 1280;
    b = idx >> 2;
    plane = 20 + (idx & 3);
    sidx = b * 6 + 5;
  }

  h2 R2[16], I2[16];
  {
    const int t0 = g * 128 + q;
    const float4* xL = (const float4*)Xf + (size_t)b * 8192 + t0;
    const uint2* ph = psih + (size_t)plane * 8192 + tid;
#pragma unroll
    for (int i = 0; i < 8; ++i) {
      const float4 xa = xL[i * 1024];
      const float4 xb = xL[i * 1024 + 64];
      const h2 XR0 = mkh2(xa.x, xb.x), XI0 = mkh2(xa.y, xb.y);
      const h2 XR1 = mkh2(xa.z, xb.z), XI1 = mkh2(xa.w, xb.w);
      const uint2 p0 = ph[(2 * i) * 512];
      const uint2 p1 = ph[(2 * i + 1) * 512];
      const h2 PR0 = u2h(p0.x), PI0 = u2h(p0.y);
      const h2 PR1 = u2h(p1.x), PI1 = u2h(p1.y);
      R2[2 * i]     = XR0 * PR0 - XI0 * PI0;
      I2[2 * i]     = XR0 * PI0 + XI0 * PR0;
      R2[2 * i + 1] = XR1 * PR1 - XI1 * PI1;
      I2[2 * i + 1] = XR1 * PI1 + XI1 * PR1;
    }
  }
  inv_rp_core(R2, I2, sU, g, q, twru, twiu);

  if (j1 < 0) {                                // j=5: s1 only
    float s1sum = 0.0f;
#pragma unroll
    for (int m = 0; m < 16; ++m) {
      const h2 sq = R2[m] * R2[m] + I2[m] * I2[m];
      s1sum += fast_sqrtf((float)sq.x) + fast_sqrtf((float)sq.y);
    }
    const float tot = block_reduce_sum<8>(s1sum, red, tid);
    if (tid == 0) atomicAdd(&s1num[sidx], tot);
    return;
  }

  float s1sum = 0.0f;
#pragma unroll
  for (int m = 0; m < 16; ++m) {
    const h2 sq = R2[m] * R2[m] + I2[m] * I2[m];
    const float aL = fast_sqrtf((float)sq.x);
    const float aH = fast_sqrtf((float)sq.y);
    s1sum += aL + aH;
    R2[m] = mkh2(aL * (1.0f / A_SCALE), aH * (1.0f / A_SCALE));
    I2[m] = bch2(0.0f);
  }
  fwd_rp_core(R2, I2, sU, g, q, twru, twiu);

  h2 UR2[16], UI2[16];
#pragma unroll
  for (int j = 0; j < 16; ++j) { UR2[j] = R2[j]; UI2[j] = I2[j]; }
  uint2 buf[16];
  {
    const uint2* ph = psih + (size_t)(4 * j1 + 4) * 8192 + tid;
#pragma unroll
    for (int j = 0; j < 16; ++j) buf[j] = ph[j * 512];
  }
  {
    const float tot = block_reduce_sum<8>(s1sum, red, tid);
    if (tid == 0) atomicAdd(&s1num[sidx], tot);
  }

  const int pb = (j1 * (11 - j1)) >> 1;
  const int nit = (5 - j1) * 4;
  float vsum = 0.0f;
  for (int it = 0; it < nit; ++it) {
#pragma unroll
    for (int j = 0; j < 16; ++j) {
      const h2 pr = u2h(buf[j].x), pi = u2h(buf[j].y);
      R2[j] = UR2[j] * pr - UI2[j] * pi;
      I2[j] = UR2[j] * pi + UI2[j] * pr;
    }
    if (it + 1 < nit) {                        // prefetch next plane
      const uint2* phn = psih + (size_t)(4 * j1 + 4 + it + 1) * 8192 + tid;
#pragma unroll
      for (int j = 0; j < 16; ++j) buf[j] = phn[j * 512];
    }
    __syncthreads();                           // prev strip reads drained
    inv_rp_core(R2, I2, sU, g, q, twru, twiu);
#pragma unroll
    for (int m = 0; m < 16; ++m) {
      const h2 sq = R2[m] * R2[m] + I2[m] * I2[m];
      vsum += fast_sqrtf((float)sq.x) + fast_sqrtf((float)sq.y);
    }
    if ((it & 3) == 3) {
      const float tot = block_reduce_sum<8>(vsum, red, tid);
      if (tid == 0) atomicAdd(&s2num[b * 15 + pb + (it >> 2)], tot);
      vsum = 0.0f;
    }
  }
}

// ---------------- fallback tier (tiny ws): f32 psi + mono ----------------
__global__ __launch_bounds__(256) void k_psi_f32(const float* __restrict__ mags,
                                                 const float* __restrict__ phases,
                                                 float2* __restrict__ psi,
                                                 float2* __restrict__ twg) {
  if (blockIdx.x == 0 && threadIdx.x < 128) {
    const int gg = threadIdx.x >> 4, k = threadIdx.x & 15;
    float sn, cs;
    __sincosf(-TWO_PI * (float)(gg * k) * (1.0f / 128.0f), &sn, &cs);
    twg[threadIdx.x] = make_float2(cs, sn);
  }
  const int gid = blockIdx.x * 256 + threadIdx.x;      // < 24*16384
  const int p = gid >> 14;
  const int rem = gid & (PLANE - 1);
  const int e = rem & 1;
  const int tt = (rem >> 1) & 1023;
  const int i = rem >> 11;
  const int j = 2 * i + e;
  const int g = tt >> 7, q = tt & 127;
  const int pr = 16 * g + j, pc = q;
  const int kr = (pr >> 3) + 16 * (pr & 7);
  const int kc = (pc >> 3) + 16 * (pc & 7);
  const int src = (p << 14) + kr * SDIM + kc;
  const float m = mags[src] * (1.0f / 16384.0f);
  float sn, cs;
  __sincosf(phases[src], &sn, &cs);
  psi[gid] = make_float2(m * cs, m * sn);
}

__device__ __forceinline__ void load_tw(const float2* __restrict__ twg, int g,
                                        float* twr, float* twi) {
#pragma unroll
  for (int k = 1; k < 16; ++k) {
    const float2 w = twg[16 * g + k];
    twr[k] = __uint_as_float(__builtin_amdgcn_readfirstlane(__float_as_uint(w.x)));
    twi[k] = __uint_as_float(__builtin_amdgcn_readfirstlane(__float_as_uint(w.y)));
  }
}

__global__ __launch_bounds__(NT) void k_img_fft(const float* __restrict__ img,
                                                float2* __restrict__ Xf,
                                                float* __restrict__ s0,
                                                const float2* __restrict__ twg) {
  __shared__ float2 sC[SDIM * PITCH];
  __shared__ float red[16];
  const int tid = threadIdx.x, b = blockIdx.x;
  const int g = __builtin_amdgcn_readfirstlane(tid >> 7);
  const int q = tid & 127;
  float twr[16], twi[16];
  load_tw(twg, g, twr, twi);
  const float* ip = img + b * PLANE;
  float sum = 0.0f;
#pragma unroll
  for (int kk = 0; kk < 16; ++kk) {
    const int e = tid + kk * NT;
    const float v = ip[e];
    sC[(e >> 7) * PITCH + (e & 127)] = make_float2(v, 0.0f);
    sum += v;
  }
  const float tot = block_reduce_sum<16>(sum, red, tid);
  if (tid == 0) s0[b] = tot * (1.0f / 16384.0f);
  __syncthreads();
  float R[16], I[16];
#pragma unroll
  for (int m = 0; m < 16; ++m) { R[m] = sC[q * PITCH + g + 8 * m].x; I[m] = 0.0f; }
  fwd_fft2(R, I, sC, g, q, twr, twi);
  float4* x4 = (float4*)Xf + (size_t)b * 8192 + tid;
#pragma unroll
  for (int i = 0; i < 8; ++i)
    x4[i * 1024] = make_float4(R[2 * i], I[2 * i], R[2 * i + 1], I[2 * i + 1]);
}

__global__ __launch_bounds__(NT) void k_scat_mono(const float2* __restrict__ Xf,
                                                  const float2* __restrict__ psi,
                                                  float* __restrict__ s1num,
                                                  float* __restrict__ s2num,
                                                  const float2* __restrict__ twg) {
  __shared__ float2 sU[SDIM * PITCH];
  __shared__ float red[16];
  const int tid = threadIdx.x;
  const int g = __builtin_amdgcn_readfirstlane(tid >> 7);
  const int q = tid & 127;
  float twr[16], twi[16];
  load_tw(twg, g, twr, twi);
  const int bid = blockIdx.x;
  float R[16], I[16];
  if (bid < 1280) {
    const int j1 = bid >> 8;
    const int b = (bid & 255) >> 2;
    const int l1 = bid & 3;
    const float4* x4 = (const float4*)Xf + (size_t)b * 8192 + tid;
    const float4* p4 = (const float4*)psi + (size_t)(j1 * 4 + l1) * 8192 + tid;
#pragma unroll
    for (int i = 0; i < 8; ++i) {
      const float4 x = x4[i * 1024], v = p4[i * 1024];
      R[2 * i]     = x.x * v.x - x.y * v.y;  I[2 * i]     = x.x * v.y + x.y * v.x;
      R[2 * i + 1] = x.z * v.z - x.w * v.w;  I[2 * i + 1] = x.z * v.w + x.w * v.z;
    }
    inv_fft2<true>(R, I, sU, g, q, twr, twi);
    float s1sum = 0.0f;
#pragma unroll
    for (int m = 0; m < 16; ++m) {
      const float a = fast_sqrtf(R[m] * R[m] + I[m] * I[m]);
      s1sum += a; R[m] = a; I[m] = 0.0f;
    }
    fwd_fft2(R, I, sU, g, q, twr, twi);
    float Ur[16], Ui[16];
#pragma unroll
    for (int k = 0; k < 16; ++k) { Ur[k] = R[k]; Ui[k] = I[k]; }
    {
      const float tot = block_reduce_sum<16>(s1sum, red, tid);
      if (tid == 0) atomicAdd(&s1num[b * 6 + j1], tot);
    }
    const int pb = (j1 * (11 - j1)) >> 1;
    int plane = (j1 + 1) * 4;
#pragma unroll 1
    for (int j2 = j1 + 1; j2 <= 5; ++j2) {
      float vsum = 0.0f;
#pragma unroll 1
      for (int l2 = 0; l2 < 4; ++l2) {
        const float4* q4 = (const float4*)psi + (size_t)plane * 8192 + tid;
#pragma unroll
        for (int i = 0; i < 8; ++i) {
          const float4 v = q4[i * 1024];
          R[2 * i]     = Ur[2 * i] * v.x - Ui[2 * i] * v.y;
          I[2 * i]     = Ur[2 * i] * v.y + Ui[2 * i] * v.x;
          R[2 * i + 1] = Ur[2 * i + 1] * v.z - Ui[2 * i + 1] * v.w;
          I[2 * i + 1] = Ur[2 * i + 1] * v.w + Ui[2 * i + 1] * v.z;
        }
        inv_fft2<false>(R, I, sU, g, q, twr, twi);
#pragma unroll
        for (int m = 0; m < 16; ++m) vsum += fast_sqrtf(R[m] * R[m] + I[m] * I[m]);
        ++plane;
      }
      const float tot = block_reduce_sum<16>(vsum, red, tid);
      if (tid == 0) atomicAdd(&s2num[b * 15 + pb + (j2 - j1 - 1)], tot);
    }
  } else {
    const int idx = bid - 1280;
    const int b = idx >> 2, l = idx & 3;
    const float4* x4 = (const float4*)Xf + (size_t)b * 8192 + tid;
    const float4* p4 = (const float4*)psi + (size_t)(20 + l) * 8192 + tid;
#pragma unroll
    for (int i = 0; i < 8; ++i) {
      const float4 x = x4[i * 1024], v = p4[i * 1024];
      R[2 * i]     = x.x * v.x - x.y * v.y;  I[2 * i]     = x.x * v.y + x.y * v.x;
      R[2 * i + 1] = x.z * v.z - x.w * v.w;  I[2 * i + 1] = x.z * v.w + x.w * v.z;
    }
    inv_fft2<true>(R, I, sU, g, q, twr, twi);
    float s = 0.0f;
#pragma unroll
    for (int m = 0; m < 16; ++m) s += fast_sqrtf(R[m] * R[m] + I[m] * I[m]);
    const float tot = block_reduce_sum<16>(s, red, tid);
    if (tid == 0) atomicAdd(&s1num[b * 6 + 5], tot);
  }
}

__global__ __launch_bounds__(64) void k_final(const float* __restrict__ s0,
                                              const float* __restrict__ s1num,
                                              const float* __restrict__ s2num,
                                              const float* __restrict__ w1,
                                              const float* __restrict__ b1,
                                              const float* __restrict__ w2,
                                              const float* __restrict__ b2,
                                              const float* __restrict__ w3,
                                              const float* __restrict__ b3,
                                              float* __restrict__ out,
                                              float s1scale, float s2scale) {
  const int b = threadIdx.x;
  if (b >= 64) return;
  float x[22];
  x[0] = s0[b];
#pragma unroll
  for (int j = 0; j < 6; ++j) x[1 + j] = s1num[b * 6 + j] * s1scale;
#pragma unroll
  for (int p = 0; p < 15; ++p) x[7 + p] = s2num[b * 15 + p] * s2scale;
  float h1[16];
#pragma unroll
  for (int o = 0; o < 16; ++o) {
    float t = b1[o];
    for (int i = 0; i < 22; ++i) t += x[i] * w1[i * 16 + o];
    h1[o] = fmaxf(t, 0.0f);
  }
  float h2a[16];
#pragma unroll
  for (int o = 0; o < 16; ++o) {
    float t = b2[o];
    for (int i = 0; i < 16; ++i) t += h1[i] * w2[i * 16 + o];
    h2a[o] = fmaxf(t, 0.0f);
  }
  float t = b3[0];
#pragma unroll
  for (int i = 0; i < 16; ++i) t += h2a[i] * w3[i];
  out[b] = 1.0f / (1.0f + expf(-t));
}

extern "C" void kernel_launch(void* const* d_in, const int* in_sizes, int n_in,
                              void* d_out, int out_size, void* d_ws, size_t ws_size,
                              hipStream_t stream) {
  (void)in_sizes; (void)n_in; (void)out_size;
  const float* image  = (const float*)d_in[0];
  const float* mags   = (const float*)d_in[1];
  const float* phases = (const float*)d_in[2];
  const float* w1 = (const float*)d_in[3];
  const float* b1 = (const float*)d_in[4];
  const float* w2 = (const float*)d_in[5];
  const float* b2 = (const float*)d_in[6];
  const float* w3 = (const float*)d_in[7];
  const float* b3 = (const float*)d_in[8];
  float* out = (float*)d_out;

  char* ws = (char*)d_ws;
  // h2 tier: psih (24 planes) at ws+0 (1,572,864 B; fits the old psi region)
  uint2*  psih = (uint2*)ws;
  float2* psi  = (float2*)ws;                      // fallback tier only (3.1MB)
  float2* Xf  = (float2*)(ws + 3145728);           // 8,388,608 B
  float*  s0  = (float*)(ws + 11534336);           // 64
  float*  s1n = s0 + 64;                           // 384 (+960 s2 contiguous)
  float*  s2n = s1n + 384;                         // 960
  float2* twg = (float2*)(s2n + 960);              // 128 float2 (1024 B)
  uint2*  twgh = (uint2*)((char*)twg + 1024);      // 128 uint2 (1024 B)
  const size_t need_h2 = 11534336ull + (64 + 1344) * 4 + 2048;   // ~11.54 MB

  if (ws_size >= need_h2) {
    k_pre<<<dim3(256), dim3(NT), 0, stream>>>(mags, phases, image, psih, twgh,
                                              Xf, s0, s1n);
    k_scat_ab<<<dim3(1536), dim3(512), 0, stream>>>(Xf, psih, s1n, s2n, twgh);
    k_final<<<dim3(1), dim3(64), 0, stream>>>(s0, s1n, s2n, w1, b1, w2, b2, w3, b3, out,
                                              1.0f / (4.0f * 16384.0f * A_SCALE),
                                              1.0f / (16.0f * 16384.0f * PSIH_SCALE));
  } else {
    hipMemsetAsync(s1n, 0, (384 + 960) * sizeof(float), stream);
    k_psi_f32<<<dim3(1536), dim3(256), 0, stream>>>(mags, phases, psi, twg);
    k_img_fft<<<dim3(64), dim3(NT), 0, stream>>>(image, Xf, s0, twg);
    k_scat_mono<<<dim3(1536), dim3(NT), 0, stream>>>(Xf, psi, s1n, s2n, twg);
    k_final<<<dim3(1), dim3(64), 0, stream>>>(s0, s1n, s2n, w1, b1, w2, b2, w3, b3, out,
                                              1.0f / (4.0f * 16384.0f),
                                              1.0f / (16.0f * 16384.0f));
  }
}